// Round 5
// baseline (2159.019 us; speedup 1.0000x reference)
//
#include <hip/hip_runtime.h>

// GraphNet forward, fp32 compute / bf16 edge-hidden rows.
// Round 5: random 128B reads of the 205MB e_h array hit the DRAM random-
// sector wall (~300 GB/s, measured r3/r4: occupancy 2x -> +4%). Escape:
// never touch a big array randomly. Fused edge-MLP + coarse radix partition
// (sequential attr reads, bucket-run writes), then per-bucket fully
// sequential aggregation into a 512x65 fp32 LDS tile. Directions run
// sequentially, reusing one 211MB partition buffer (ws ~290MB, r2-proven).

typedef unsigned int uint;
typedef unsigned short ushort;

#define KSHIFT 9
#define KR 512          // nodes per coarse bucket
#define KMAX 200        // max buckets (N=100000 -> 196)
#define PST 33          // dwords per partitioned row: 32 bf16-pair + node-local

#define LDF4(p) (*reinterpret_cast<const float4*>(p))

__device__ __forceinline__ void load16(const float* __restrict__ p, float* v) {
  float4 a = LDF4(p), b = LDF4(p + 4), c = LDF4(p + 8), d = LDF4(p + 12);
  v[0]=a.x; v[1]=a.y; v[2]=a.z; v[3]=a.w;
  v[4]=b.x; v[5]=b.y; v[6]=b.z; v[7]=b.w;
  v[8]=c.x; v[9]=c.y; v[10]=c.z; v[11]=c.w;
  v[12]=d.x; v[13]=d.y; v[14]=d.z; v[15]=d.w;
}

__device__ __forceinline__ ushort f2bf(float f) {
  uint u = __float_as_uint(f);
  u += 0x7FFFu + ((u >> 16) & 1u);
  return (ushort)(u >> 16);
}
__device__ __forceinline__ uint pack2(float a, float b) {
  return (uint)f2bf(a) | ((uint)f2bf(b) << 16);
}

// ---- fold uniform-u contributions into per-layer init vectors
__global__ void precompute_kernel(const float* __restrict__ u,
                                  const float* __restrict__ W_eb,
                                  const float* __restrict__ b_eb,
                                  const float* __restrict__ W_nb,
                                  const float* __restrict__ b_nb,
                                  float* __restrict__ eb_init,
                                  float* __restrict__ nb_init) {
  int j = threadIdx.x;  // 64 threads
  float ae = b_eb[j], an = b_nb[j];
  for (int k = 0; k < 64; ++k) {
    float uk = u[k];
    ae = fmaf(uk, W_eb[(48 + k) * 64 + j], ae);
    an = fmaf(uk, W_nb[(80 + k) * 64 + j], an);
  }
  eb_init[j] = ae;
  nb_init[j] = an;
}

// ---- coarse-bucket histogram, both directions
__global__ __launch_bounds__(256) void bcount_kernel(
    const int* __restrict__ receivers, const int* __restrict__ senders,
    uint* __restrict__ bcnt_r, uint* __restrict__ bcnt_s, int E, int K) {
  __shared__ uint hr[KMAX], hs[KMAX];
  int t = threadIdx.x;
  for (int i = t; i < K; i += 256) { hr[i] = 0; hs[i] = 0; }
  __syncthreads();
  int stride = gridDim.x * 256;
  for (int e = blockIdx.x * 256 + t; e < E; e += stride) {
    atomicAdd(&hr[receivers[e] >> KSHIFT], 1u);
    atomicAdd(&hs[senders[e] >> KSHIFT], 1u);
  }
  __syncthreads();
  for (int i = t; i < K; i += 256) {
    if (hr[i]) atomicAdd(&bcnt_r[i], hr[i]);
    if (hs[i]) atomicAdd(&bcnt_s[i], hs[i]);
  }
}

// ---- exclusive scan of both bucket-count arrays (single block)
__global__ __launch_bounds__(256) void bscan_kernel(
    const uint* __restrict__ bcnt_r, const uint* __restrict__ bcnt_s,
    uint* __restrict__ start_r, uint* __restrict__ start_s,
    uint* __restrict__ cur_r, uint* __restrict__ cur_s, int E, int K) {
  __shared__ uint ts[256];
  int t = threadIdx.x;
  #pragma unroll
  for (int pass = 0; pass < 2; ++pass) {
    const uint* cnt = pass ? bcnt_s : bcnt_r;
    uint* start = pass ? start_s : start_r;
    uint* cur = pass ? cur_s : cur_r;
    uint own = (t < K) ? cnt[t] : 0;
    ts[t] = own;
    __syncthreads();
    for (int off = 1; off < 256; off <<= 1) {
      uint a = (t >= off) ? ts[t - off] : 0;
      __syncthreads();
      ts[t] += a;
      __syncthreads();
    }
    if (t < K) { start[t] = ts[t] - own; cur[t] = ts[t] - own; }
    if (t == 0) start[K] = (uint)E;
    __syncthreads();
  }
}

// ---- fused edge-MLP + coarse partition (one direction per launch).
// Sequential attr reads; x random (6.4MB, L2-hot). Rows staged in LDS by
// bucket -> bucket-run coalesced global writes.
__global__ __launch_bounds__(512) void epart_kernel(
    const float* __restrict__ edge_attr, const float* __restrict__ x,
    const int* __restrict__ senders, const int* __restrict__ receivers,
    const float* __restrict__ W_eb, const float* __restrict__ eb_init,
    uint* __restrict__ gcur, uint* __restrict__ part, int E, int K, int dir) {
  __shared__ uint stageR[512 * PST];  // 67.6 KB (stride 33: conflict-free)
  __shared__ uint stageN[512];
  __shared__ uint gpos[512];
  __shared__ uint hist[KMAX], lstart[KMAX], curL[KMAX], gbase[KMAX];
  __shared__ uint ts[256];
  int t = threadIdx.x;
  int base = blockIdx.x * 512;
  int cact = min(512, E - base);
  for (int i = t; i < K; i += 512) hist[i] = 0;
  __syncthreads();
  bool val = t < cact;
  int e = base + t;
  int r = 0, s = 0;
  if (val) { r = receivers[e]; s = senders[e]; }
  int key = dir ? s : r;
  uint row[32];
  if (val) {
    float v[48];
    load16(edge_attr + (size_t)e * 16, v);
    load16(x + (size_t)r * 16, v + 16);
    load16(x + (size_t)s * 16, v + 32);
    #pragma unroll
    for (int c = 0; c < 4; ++c) {
      float acc[16];
      #pragma unroll
      for (int j = 0; j < 16; ++j) acc[j] = eb_init[c * 16 + j];
      #pragma unroll
      for (int i2 = 0; i2 < 48; ++i2) {
        const float* Wrow = W_eb + i2 * 64 + c * 16;
        #pragma unroll
        for (int j = 0; j < 16; ++j) acc[j] = fmaf(v[i2], Wrow[j], acc[j]);
      }
      #pragma unroll
      for (int j = 0; j < 8; ++j)
        row[c * 8 + j] =
            pack2(fmaxf(acc[2 * j], 0.f), fmaxf(acc[2 * j + 1], 0.f));
    }
    atomicAdd(&hist[key >> KSHIFT], 1u);
  }
  __syncthreads();
  // scan K bins with the first 256 threads (all threads hit the syncs)
  uint own = 0;
  if (t < 256) { own = (t < K) ? hist[t] : 0; ts[t] = own; }
  __syncthreads();
  for (int off = 1; off < 256; off <<= 1) {
    uint a = 0;
    if (t < 256 && t >= off) a = ts[t - off];
    __syncthreads();
    if (t < 256) ts[t] += a;
    __syncthreads();
  }
  if (t < 256 && t < K) {
    uint ls = ts[t] - own;
    lstart[t] = ls;
    curL[t] = ls;
    if (own) gbase[t] = atomicAdd(&gcur[t], own);
  }
  __syncthreads();
  if (val) {
    int k = key >> KSHIFT;
    uint sl = atomicAdd(&curL[k], 1u);
    gpos[sl] = gbase[k] + (sl - lstart[k]);
    stageN[sl] = (uint)(key & (KR - 1));
    #pragma unroll
    for (int j = 0; j < 32; ++j) stageR[sl * PST + j] = row[j];
  }
  __syncthreads();
  int u2 = t >> 5, l = t & 31;
  for (int s2 = u2; s2 < cact; s2 += 16) {
    size_t gb = (size_t)gpos[s2] * PST;
    part[gb + l] = stageR[s2 * PST + l];
    if (l == 0) part[gb + 32] = stageN[s2];
  }
}

// ---- per-bucket aggregation: fully sequential reads of the partition,
// fp32 accumulate in a 512x65 LDS tile (132 KB), coalesced output.
__global__ __launch_bounds__(512) void paggr_kernel(
    const uint* __restrict__ part, const uint* __restrict__ start,
    float* __restrict__ sum, uint* __restrict__ cnt, int N) {
  __shared__ float acc[KR * 65];  // 133120 B
  __shared__ uint cntL[KR];
  int b = blockIdx.x, t = threadIdx.x;
  for (int i = t; i < KR * 65; i += 512) acc[i] = 0.f;
  for (int i = t; i < KR; i += 512) cntL[i] = 0;
  __syncthreads();
  int beg = (int)start[b], end = (int)start[b + 1];
  int u = t >> 5, l = t & 31;
  int pos = beg + u;
  for (; pos + 48 < end; pos += 64) {
    size_t p0 = (size_t)pos * PST, p1 = (size_t)(pos + 16) * PST;
    size_t p2 = (size_t)(pos + 32) * PST, p3 = (size_t)(pos + 48) * PST;
    uint w0 = part[p0 + l], n0 = part[p0 + 32];
    uint w1 = part[p1 + l], n1 = part[p1 + 32];
    uint w2 = part[p2 + l], n2 = part[p2 + 32];
    uint w3 = part[p3 + l], n3 = part[p3 + 32];
    atomicAdd(&acc[n0 * 65 + 2 * l],     __uint_as_float(w0 << 16));
    atomicAdd(&acc[n0 * 65 + 2 * l + 1], __uint_as_float(w0 & 0xFFFF0000u));
    atomicAdd(&acc[n1 * 65 + 2 * l],     __uint_as_float(w1 << 16));
    atomicAdd(&acc[n1 * 65 + 2 * l + 1], __uint_as_float(w1 & 0xFFFF0000u));
    atomicAdd(&acc[n2 * 65 + 2 * l],     __uint_as_float(w2 << 16));
    atomicAdd(&acc[n2 * 65 + 2 * l + 1], __uint_as_float(w2 & 0xFFFF0000u));
    atomicAdd(&acc[n3 * 65 + 2 * l],     __uint_as_float(w3 << 16));
    atomicAdd(&acc[n3 * 65 + 2 * l + 1], __uint_as_float(w3 & 0xFFFF0000u));
    if (l == 0) {
      atomicAdd(&cntL[n0], 1u); atomicAdd(&cntL[n1], 1u);
      atomicAdd(&cntL[n2], 1u); atomicAdd(&cntL[n3], 1u);
    }
  }
  for (; pos < end; pos += 16) {
    size_t p = (size_t)pos * PST;
    uint w = part[p + l], n = part[p + 32];
    atomicAdd(&acc[n * 65 + 2 * l],     __uint_as_float(w << 16));
    atomicAdd(&acc[n * 65 + 2 * l + 1], __uint_as_float(w & 0xFFFF0000u));
    if (l == 0) atomicAdd(&cntL[n], 1u);
  }
  __syncthreads();
  int nb = b * KR;
  for (int i = t; i < KR * 64; i += 512) {
    int node = nb + (i >> 6);
    if (node < N)
      sum[(size_t)node * 64 + (i & 63)] = acc[(i >> 6) * 65 + (i & 63)];
  }
  for (int i = t; i < KR; i += 512)
    if (nb + i < N) cnt[nb + i] = cntL[i];
}

// ---- node block
__global__ __launch_bounds__(256, 4) void node_kernel(
    const float* __restrict__ x, const float* __restrict__ sum_recv,
    const float* __restrict__ W_nb, const float* __restrict__ nb_init,
    float* __restrict__ n_h, int N) {
  int n = blockIdx.x * 256 + threadIdx.x;
  if (n >= N) return;
  float v[80];
  const float* ar = sum_recv + (size_t)n * 64;
  load16(ar, v); load16(ar + 16, v + 16); load16(ar + 32, v + 32);
  load16(ar + 48, v + 48);
  load16(x + (size_t)n * 16, v + 64);
  float* out = n_h + (size_t)n * 64;
  #pragma unroll
  for (int c = 0; c < 4; ++c) {
    float acc[16];
    #pragma unroll
    for (int j = 0; j < 16; ++j) acc[j] = nb_init[c * 16 + j];
    #pragma unroll
    for (int i = 0; i < 80; ++i) {
      const float* Wrow = W_nb + i * 64 + c * 16;
      #pragma unroll
      for (int j = 0; j < 16; ++j) acc[j] = fmaf(v[i], Wrow[j], acc[j]);
    }
    #pragma unroll
    for (int j = 0; j < 16; j += 4) {
      float4 tq = {fmaxf(acc[j], 0.f), fmaxf(acc[j + 1], 0.f),
                   fmaxf(acc[j + 2], 0.f), fmaxf(acc[j + 3], 0.f)};
      *reinterpret_cast<float4*>(out + c * 16 + j) = tq;
    }
  }
}

// ---- column sums of sum_recv (= sum of all e_h) and n_h
__global__ __launch_bounds__(256) void reduce_kernel(
    const float* __restrict__ sum_recv, const float* __restrict__ n_h,
    float* __restrict__ e_sum, float* __restrict__ n_sum, int N) {
  __shared__ float ls[128];
  if (threadIdx.x < 128) ls[threadIdx.x] = 0.f;
  __syncthreads();
  int g = threadIdx.x & 15;
  int tid = blockIdx.x * blockDim.x + threadIdx.x;
  int row0 = tid >> 4;
  int rstride = (gridDim.x * blockDim.x) >> 4;
  float pe[4] = {0, 0, 0, 0}, pn[4] = {0, 0, 0, 0};
  for (int r = row0; r < N; r += rstride) {
    float4 a = LDF4(sum_recv + (size_t)r * 64 + g * 4);
    float4 b = LDF4(n_h + (size_t)r * 64 + g * 4);
    pe[0] += a.x; pe[1] += a.y; pe[2] += a.z; pe[3] += a.w;
    pn[0] += b.x; pn[1] += b.y; pn[2] += b.z; pn[3] += b.w;
  }
  #pragma unroll
  for (int i = 0; i < 4; ++i) {
    atomicAdd(&ls[g * 4 + i], pe[i]);
    atomicAdd(&ls[64 + g * 4 + i], pn[i]);
  }
  __syncthreads();
  if (threadIdx.x < 64) {
    atomicAdd(&e_sum[threadIdx.x], ls[threadIdx.x]);
    atomicAdd(&n_sum[threadIdx.x], ls[64 + threadIdx.x]);
  }
}

// ---- global block + fold u2 into d1_init
__global__ void global_kernel(const float* __restrict__ u,
                              const float* __restrict__ e_sum,
                              const float* __restrict__ n_sum,
                              const float* __restrict__ W_gb,
                              const float* __restrict__ b_gb,
                              const float* __restrict__ W_d1,
                              const float* __restrict__ b_d1,
                              float* __restrict__ d1_init, float Ef, float Nf) {
  __shared__ float gin[192];
  __shared__ float u2s[64];
  int j = threadIdx.x;  // 64 threads
  gin[j] = e_sum[j] / Ef;
  gin[64 + j] = n_sum[j] / Nf;
  gin[128 + j] = u[j];
  __syncthreads();
  float a = b_gb[j];
  for (int k = 0; k < 192; ++k) a = fmaf(gin[k], W_gb[k * 64 + j], a);
  u2s[j] = fmaxf(a, 0.f);
  __syncthreads();
  float d = b_d1[j];
  for (int k = 0; k < 64; ++k) d = fmaf(u2s[k], W_d1[(192 + k) * 64 + j], d);
  d1_init[j] = d;
}

// ---- decoder
__global__ __launch_bounds__(256, 2) void decoder_kernel(
    const float* __restrict__ sum_recv, const float* __restrict__ sum_sent,
    const uint* __restrict__ cnt_r, const uint* __restrict__ cnt_s,
    const float* __restrict__ n_h, const float* __restrict__ W_d1,
    const float* __restrict__ d1_init, const float* __restrict__ W_d2,
    const float* __restrict__ b_d2, float* __restrict__ out, int N) {
  int n = blockIdx.x * 256 + threadIdx.x;
  if (n >= N) return;
  float acc[64];
  #pragma unroll
  for (int j = 0; j < 64; ++j) acc[j] = d1_init[j];
  float v[16];
  float invr = 1.0f / fmaxf((float)cnt_r[n], 1.0f);
  const float* pr = sum_recv + (size_t)n * 64;
  #pragma unroll
  for (int c = 0; c < 4; ++c) {
    load16(pr + c * 16, v);
    #pragma unroll
    for (int i = 0; i < 16; ++i) v[i] *= invr;
    #pragma unroll
    for (int i = 0; i < 16; ++i) {
      const float* Wrow = W_d1 + (c * 16 + i) * 64;
      #pragma unroll
      for (int j = 0; j < 64; ++j) acc[j] = fmaf(v[i], Wrow[j], acc[j]);
    }
  }
  float invs = 1.0f / fmaxf((float)cnt_s[n], 1.0f);
  const float* ps = sum_sent + (size_t)n * 64;
  #pragma unroll
  for (int c = 0; c < 4; ++c) {
    load16(ps + c * 16, v);
    #pragma unroll
    for (int i = 0; i < 16; ++i) v[i] *= invs;
    #pragma unroll
    for (int i = 0; i < 16; ++i) {
      const float* Wrow = W_d1 + (64 + c * 16 + i) * 64;
      #pragma unroll
      for (int j = 0; j < 64; ++j) acc[j] = fmaf(v[i], Wrow[j], acc[j]);
    }
  }
  const float* pn = n_h + (size_t)n * 64;
  #pragma unroll
  for (int c = 0; c < 4; ++c) {
    load16(pn + c * 16, v);
    #pragma unroll
    for (int i = 0; i < 16; ++i) {
      const float* Wrow = W_d1 + (128 + c * 16 + i) * 64;
      #pragma unroll
      for (int j = 0; j < 64; ++j) acc[j] = fmaf(v[i], Wrow[j], acc[j]);
    }
  }
  #pragma unroll
  for (int j = 0; j < 64; ++j) acc[j] = fmaxf(acc[j], 0.f);
  float* po = out + (size_t)n * 16;
  #pragma unroll
  for (int o = 0; o < 16; o += 4) {
    float4 tq;
    float* tp = &tq.x;
    #pragma unroll
    for (int q = 0; q < 4; ++q) {
      float a = b_d2[o + q];
      #pragma unroll
      for (int j = 0; j < 64; ++j) a = fmaf(acc[j], W_d2[j * 16 + o + q], a);
      tp[q] = a;
    }
    *reinterpret_cast<float4*>(po + o) = tq;
  }
}

extern "C" void kernel_launch(void* const* d_in, const int* in_sizes, int n_in,
                              void* d_out, int out_size, void* d_ws,
                              size_t ws_size, hipStream_t stream) {
  const float* x         = (const float*)d_in[0];
  const float* edge_attr = (const float*)d_in[1];
  const float* u         = (const float*)d_in[2];
  const int*   senders   = (const int*)d_in[3];
  const int*   receivers = (const int*)d_in[4];
  const float* W_eb = (const float*)d_in[7];
  const float* b_eb = (const float*)d_in[8];
  const float* W_nb = (const float*)d_in[9];
  const float* b_nb = (const float*)d_in[10];
  const float* W_gb = (const float*)d_in[11];
  const float* b_gb = (const float*)d_in[12];
  const float* W_d1 = (const float*)d_in[13];
  const float* b_d1 = (const float*)d_in[14];
  const float* W_d2 = (const float*)d_in[15];
  const float* b_d2 = (const float*)d_in[16];

  int N = in_sizes[0] / 16;
  int E = in_sizes[1] / 16;
  int K = (N + KR - 1) >> KSHIFT;  // 196 for N=100000

  char* w = (char*)d_ws;
  uint* part = (uint*)w;             w += (size_t)E * PST * 4;   // 211 MB
  float* sum_recv = (float*)w;       w += (size_t)N * 64 * 4;
  float* sum_sent = (float*)w;       w += (size_t)N * 64 * 4;
  float* n_h = (float*)w;            w += (size_t)N * 64 * 4;
  uint* cnt_r = (uint*)w;            w += (size_t)N * 4;
  uint* cnt_s = (uint*)w;            w += (size_t)N * 4;
  uint* start_r = (uint*)w;          w += (size_t)(K + 1) * 4;
  uint* start_s = (uint*)w;          w += (size_t)(K + 1) * 4;
  uint* cur_r = (uint*)w;            w += (size_t)K * 4;
  uint* cur_s = (uint*)w;            w += (size_t)K * 4;
  // zeroed region
  uint* bcnt_r = (uint*)w;           w += (size_t)KMAX * 4;
  uint* bcnt_s = (uint*)w;           w += (size_t)KMAX * 4;
  float* e_sum = (float*)w;          w += 64 * 4;
  float* n_sum = (float*)w;          w += 64 * 4;
  // small non-zeroed
  float* eb_init = (float*)w;        w += 64 * 4;
  float* nb_init = (float*)w;        w += 64 * 4;
  float* d1_init = (float*)w;        w += 64 * 4;

  size_t zero_bytes = (size_t)(2 * KMAX + 128) * 4;
  hipMemsetAsync(bcnt_r, 0, zero_bytes, stream);

  hipLaunchKernelGGL(precompute_kernel, dim3(1), dim3(64), 0, stream, u, W_eb,
                     b_eb, W_nb, b_nb, eb_init, nb_init);
  hipLaunchKernelGGL(bcount_kernel, dim3(64), dim3(256), 0, stream, receivers,
                     senders, bcnt_r, bcnt_s, E, K);
  hipLaunchKernelGGL(bscan_kernel, dim3(1), dim3(256), 0, stream, bcnt_r,
                     bcnt_s, start_r, start_s, cur_r, cur_s, E, K);
  // direction 0 (recv), then reuse `part` for direction 1 (send)
  hipLaunchKernelGGL(epart_kernel, dim3((E + 511) / 512), dim3(512), 0, stream,
                     edge_attr, x, senders, receivers, W_eb, eb_init, cur_r,
                     part, E, K, 0);
  hipLaunchKernelGGL(paggr_kernel, dim3(K), dim3(512), 0, stream, part,
                     start_r, sum_recv, cnt_r, N);
  hipLaunchKernelGGL(epart_kernel, dim3((E + 511) / 512), dim3(512), 0, stream,
                     edge_attr, x, senders, receivers, W_eb, eb_init, cur_s,
                     part, E, K, 1);
  hipLaunchKernelGGL(paggr_kernel, dim3(K), dim3(512), 0, stream, part,
                     start_s, sum_sent, cnt_s, N);
  hipLaunchKernelGGL(node_kernel, dim3((N + 255) / 256), dim3(256), 0, stream,
                     x, sum_recv, W_nb, nb_init, n_h, N);
  hipLaunchKernelGGL(reduce_kernel, dim3(256), dim3(256), 0, stream, sum_recv,
                     n_h, e_sum, n_sum, N);
  hipLaunchKernelGGL(global_kernel, dim3(1), dim3(64), 0, stream, u, e_sum,
                     n_sum, W_gb, b_gb, W_d1, b_d1, d1_init, (float)E,
                     (float)N);
  hipLaunchKernelGGL(decoder_kernel, dim3((N + 255) / 256), dim3(256), 0,
                     stream, sum_recv, sum_sent, cnt_r, cnt_s, n_h, W_d1,
                     d1_init, W_d2, b_d2, (float*)d_out, N);
}

// Round 6
// 770.005 us; speedup vs baseline: 2.8039x; 2.8039x over previous
//
#include <hip/hip_runtime.h>

// GraphNet forward, fp32 compute / bf16 edge-hidden storage.
// Round 6: r2 pipeline (best: 1084us) minus its one bad piece. Model from
// r3-r5: LDS f32 atomics ~3cy/lane -> 205M atomic-lanes = ~700us (the
// common cost of r3/r4 gather and r5 paggr). r2's register-accumulate
// gather is the only fast aggregation. Here: replace fill's 305us
// scattered-4B-HBM writes with LDS-staged distribute + per-bucket counting
// sort whose scattered writes live in an 8KB L2 window. Edge kernel runs
// right before the gathers so e_h stays L3-resident.

typedef unsigned int uint;
typedef unsigned short ushort;

#define BW 128          // nodes per bucket
#define BSHIFT 7
#define NBMAX 784       // max buckets (N=100000 -> 782)
#define DC 8192         // edges per distribute block
#define EMASK 0x1FFFFFu // 21 bits of edge id (E=1.6M < 2^21)

#define LDF4(p) (*reinterpret_cast<const float4*>(p))

__device__ __forceinline__ void load16(const float* __restrict__ p, float* v) {
  float4 a = LDF4(p), b = LDF4(p + 4), c = LDF4(p + 8), d = LDF4(p + 12);
  v[0]=a.x; v[1]=a.y; v[2]=a.z; v[3]=a.w;
  v[4]=b.x; v[5]=b.y; v[6]=b.z; v[7]=b.w;
  v[8]=c.x; v[9]=c.y; v[10]=c.z; v[11]=c.w;
  v[12]=d.x; v[13]=d.y; v[14]=d.z; v[15]=d.w;
}

__device__ __forceinline__ ushort f2bf(float f) {
  uint u = __float_as_uint(f);
  u += 0x7FFFu + ((u >> 16) & 1u);
  return (ushort)(u >> 16);
}
__device__ __forceinline__ float bf2f(ushort h) {
  return __uint_as_float((uint)h << 16);
}

// ---- fold uniform-u contributions into per-layer init vectors
__global__ void precompute_kernel(const float* __restrict__ u,
                                  const float* __restrict__ W_eb,
                                  const float* __restrict__ b_eb,
                                  const float* __restrict__ W_nb,
                                  const float* __restrict__ b_nb,
                                  float* __restrict__ eb_init,
                                  float* __restrict__ nb_init) {
  int j = threadIdx.x;  // 64 threads
  float ae = b_eb[j], an = b_nb[j];
  for (int k = 0; k < 64; ++k) {
    float uk = u[k];
    ae = fmaf(uk, W_eb[(48 + k) * 64 + j], ae);
    an = fmaf(uk, W_nb[(80 + k) * 64 + j], an);
  }
  eb_init[j] = ae;
  nb_init[j] = an;
}

// ---- bucket histogram for both directions (LDS hist -> global merge)
__global__ __launch_bounds__(256) void bcount_kernel(
    const int* __restrict__ receivers, const int* __restrict__ senders,
    uint* __restrict__ bcnt_r, uint* __restrict__ bcnt_s, int E, int NB) {
  __shared__ uint hr[NBMAX], hs[NBMAX];
  int t = threadIdx.x;
  for (int i = t; i < NB; i += 256) { hr[i] = 0; hs[i] = 0; }
  __syncthreads();
  int stride = gridDim.x * 256;
  for (int e = blockIdx.x * 256 + t; e < E; e += stride) {
    atomicAdd(&hr[receivers[e] >> BSHIFT], 1u);
    atomicAdd(&hs[senders[e] >> BSHIFT], 1u);
  }
  __syncthreads();
  for (int i = t; i < NB; i += 256) {
    if (hr[i]) atomicAdd(&bcnt_r[i], hr[i]);
    if (hs[i]) atomicAdd(&bcnt_s[i], hs[i]);
  }
}

// ---- exclusive scan of both bucket-count arrays (single block, 4/thread)
__global__ __launch_bounds__(256) void bscan_kernel(
    const uint* __restrict__ bcnt_r, const uint* __restrict__ bcnt_s,
    uint* __restrict__ start_r, uint* __restrict__ start_s,
    uint* __restrict__ cur_r, uint* __restrict__ cur_s, int E, int NB) {
  __shared__ uint ts[256];
  int t = threadIdx.x;
  #pragma unroll
  for (int pass = 0; pass < 2; ++pass) {
    const uint* cnt = pass ? bcnt_s : bcnt_r;
    uint* start = pass ? start_s : start_r;
    uint* cur = pass ? cur_s : cur_r;
    uint loc[4]; uint tsum = 0;
    #pragma unroll
    for (int q = 0; q < 4; ++q) {
      int i = t * 4 + q;
      loc[q] = (i < NB) ? cnt[i] : 0;
      tsum += loc[q];
    }
    ts[t] = tsum;
    __syncthreads();
    for (int off = 1; off < 256; off <<= 1) {
      uint a = (t >= off) ? ts[t - off] : 0;
      __syncthreads();
      ts[t] += a;
      __syncthreads();
    }
    uint run = ts[t] - tsum;
    #pragma unroll
    for (int q = 0; q < 4; ++q) {
      int i = t * 4 + q;
      if (i < NB) { start[i] = run; cur[i] = run; run += loc[q]; }
    }
    if (t == 0) start[NB] = (uint)E;
    __syncthreads();
  }
}

// ---- bucket-sort edge ids, both directions in one launch.
// entry = (node_local<<21)|edge_id; idsB holds the bucket for routing.
__global__ __launch_bounds__(256) void distribute_kernel(
    const int* __restrict__ receivers, const int* __restrict__ senders,
    uint* __restrict__ gcur_r, uint* __restrict__ gcur_s,
    uint* __restrict__ tmp_r, uint* __restrict__ tmp_s, int E, int NB) {
  __shared__ uint hist[NBMAX], lstart[NBMAX], cur[NBMAX], gbase[NBMAX];
  __shared__ uint ids[DC];
  __shared__ ushort idsB[DC];
  __shared__ uint ts[256];
  int dir = blockIdx.x & 1;
  const int* key = dir ? senders : receivers;
  uint* g_cursor = dir ? gcur_s : gcur_r;
  uint* tmp = dir ? tmp_s : tmp_r;
  int t = threadIdx.x;
  int base = (blockIdx.x >> 1) * DC;
  int cact = min(DC, E - base);
  for (int i = t; i < NB; i += 256) hist[i] = 0;
  __syncthreads();
  for (int k = 0; k < DC / 256; ++k) {
    int j = k * 256 + t;
    if (j < cact) atomicAdd(&hist[key[base + j] >> BSHIFT], 1u);
  }
  __syncthreads();
  {
    uint loc[4]; uint tsum = 0;
    #pragma unroll
    for (int q = 0; q < 4; ++q) {
      int i = t * 4 + q;
      loc[q] = (i < NB) ? hist[i] : 0;
      tsum += loc[q];
    }
    ts[t] = tsum;
    __syncthreads();
    for (int off = 1; off < 256; off <<= 1) {
      uint a = (t >= off) ? ts[t - off] : 0;
      __syncthreads();
      ts[t] += a;
      __syncthreads();
    }
    uint run = ts[t] - tsum;
    #pragma unroll
    for (int q = 0; q < 4; ++q) {
      int i = t * 4 + q;
      if (i < NB) { lstart[i] = run; cur[i] = run; run += loc[q]; }
    }
  }
  __syncthreads();
  for (int i = t; i < NB; i += 256)
    if (hist[i]) gbase[i] = atomicAdd(&g_cursor[i], hist[i]);
  for (int k = 0; k < DC / 256; ++k) {
    int j = k * 256 + t;
    if (j < cact) {
      int e = base + j;
      int kk = key[e];
      uint b = (uint)(kk >> BSHIFT);
      uint slot = atomicAdd(&cur[b], 1u);
      ids[slot] = ((uint)(kk & (BW - 1)) << 21) | (uint)e;
      idsB[slot] = (ushort)b;
    }
  }
  __syncthreads();
  for (int j = t; j < cact; j += 256) {
    uint b2 = idsB[j];
    tmp[gbase[b2] + ((uint)j - lstart[b2])] = ids[j];
  }
}

// ---- per-bucket counting sort to full per-node order.
// Scattered writes confined to the bucket's ~8KB output window (L2).
__global__ __launch_bounds__(256) void bucketsort_kernel(
    const uint* __restrict__ tmp_r, const uint* __restrict__ tmp_s,
    const uint* __restrict__ start_r, const uint* __restrict__ start_s,
    uint* __restrict__ eidx_r, uint* __restrict__ eidx_s,
    uint* __restrict__ row_ptr_r, uint* __restrict__ row_ptr_s,
    uint* __restrict__ cnt_r, uint* __restrict__ cnt_s, int N) {
  __shared__ uint hist[BW], pfx[BW], cur[BW];
  int d = blockIdx.x & 1;
  int b = blockIdx.x >> 1;
  const uint* tmp = d ? tmp_s : tmp_r;
  const uint* start = d ? start_s : start_r;
  uint* eidx = d ? eidx_s : eidx_r;
  uint* row_ptr = d ? row_ptr_s : row_ptr_r;
  uint* cnt = d ? cnt_s : cnt_r;
  int t = threadIdx.x;
  if (t < BW) hist[t] = 0;
  __syncthreads();
  int beg = (int)start[b], end = (int)start[b + 1];
  for (int i = beg + t; i < end; i += 256) atomicAdd(&hist[tmp[i] >> 21], 1u);
  __syncthreads();
  if (t < BW) pfx[t] = hist[t];
  __syncthreads();
  for (int off = 1; off < BW; off <<= 1) {
    uint a = 0;
    if (t < BW && t >= off) a = pfx[t - off];
    __syncthreads();
    if (t < BW) pfx[t] += a;
    __syncthreads();
  }
  if (t < BW) cur[t] = pfx[t] - hist[t];
  __syncthreads();
  for (int i = beg + t; i < end; i += 256) {
    uint v = tmp[i];
    uint nl = v >> 21;
    uint p = atomicAdd(&cur[nl], 1u);
    eidx[beg + p] = v & EMASK;
  }
  int nbase = b * BW;
  if (t < BW && nbase + t < N) {
    cnt[nbase + t] = hist[t];
    row_ptr[nbase + t] = (uint)beg + pfx[t] - hist[t];
  }
}

// ---- edge MLP: e_h = relu([ea, x_r, x_s]@W[0:48] + eb_init) -> bf16
__global__ __launch_bounds__(256, 4) void edge_kernel(
    const float* __restrict__ edge_attr, const float* __restrict__ x,
    const int* __restrict__ senders, const int* __restrict__ receivers,
    const float* __restrict__ W_eb, const float* __restrict__ eb_init,
    ushort* __restrict__ e_h, int E) {
  int e = blockIdx.x * 256 + threadIdx.x;
  if (e >= E) return;
  int r = receivers[e];
  int s = senders[e];
  float v[48];
  load16(edge_attr + (size_t)e * 16, v);
  load16(x + (size_t)r * 16, v + 16);
  load16(x + (size_t)s * 16, v + 32);
  uint4* dst = reinterpret_cast<uint4*>(e_h + (size_t)e * 64);
  #pragma unroll
  for (int c = 0; c < 4; ++c) {
    float acc[16];
    #pragma unroll
    for (int j = 0; j < 16; ++j) acc[j] = eb_init[c * 16 + j];
    #pragma unroll
    for (int i = 0; i < 48; ++i) {
      const float* Wrow = W_eb + i * 64 + c * 16;
      #pragma unroll
      for (int j = 0; j < 16; ++j) acc[j] = fmaf(v[i], Wrow[j], acc[j]);
    }
    union { ushort h[16]; uint4 q[2]; } pk;
    #pragma unroll
    for (int j = 0; j < 16; ++j) pk.h[j] = f2bf(fmaxf(acc[j], 0.f));
    dst[c * 2] = pk.q[0];
    dst[c * 2 + 1] = pk.q[1];
  }
}

// ---- gather: one wave per node; lane j accumulates column j in registers.
__global__ __launch_bounds__(256, 4) void gather_kernel(
    const ushort* __restrict__ e_h, const uint* __restrict__ row_ptr,
    const uint* __restrict__ cnt, const uint* __restrict__ eidx,
    float* __restrict__ out, int N) {
  int n = blockIdx.x * 4 + (threadIdx.x >> 6);
  if (n >= N) return;
  int lane = threadIdx.x & 63;
  int beg = (int)row_ptr[n], end = beg + (int)cnt[n];
  float a0 = 0, a1 = 0, a2 = 0, a3 = 0;
  int i = beg;
  for (; i + 4 <= end; i += 4) {
    int e0 = (int)eidx[i], e1 = (int)eidx[i + 1];
    int e2 = (int)eidx[i + 2], e3 = (int)eidx[i + 3];
    a0 += bf2f(e_h[(size_t)e0 * 64 + lane]);
    a1 += bf2f(e_h[(size_t)e1 * 64 + lane]);
    a2 += bf2f(e_h[(size_t)e2 * 64 + lane]);
    a3 += bf2f(e_h[(size_t)e3 * 64 + lane]);
  }
  for (; i < end; ++i) a0 += bf2f(e_h[(size_t)eidx[i] * 64 + lane]);
  out[(size_t)n * 64 + lane] = (a0 + a1) + (a2 + a3);
}

// ---- node block
__global__ __launch_bounds__(256, 4) void node_kernel(
    const float* __restrict__ x, const float* __restrict__ sum_recv,
    const float* __restrict__ W_nb, const float* __restrict__ nb_init,
    float* __restrict__ n_h, int N) {
  int n = blockIdx.x * 256 + threadIdx.x;
  if (n >= N) return;
  float v[80];
  const float* ar = sum_recv + (size_t)n * 64;
  load16(ar, v); load16(ar + 16, v + 16); load16(ar + 32, v + 32);
  load16(ar + 48, v + 48);
  load16(x + (size_t)n * 16, v + 64);
  float* out = n_h + (size_t)n * 64;
  #pragma unroll
  for (int c = 0; c < 4; ++c) {
    float acc[16];
    #pragma unroll
    for (int j = 0; j < 16; ++j) acc[j] = nb_init[c * 16 + j];
    #pragma unroll
    for (int i = 0; i < 80; ++i) {
      const float* Wrow = W_nb + i * 64 + c * 16;
      #pragma unroll
      for (int j = 0; j < 16; ++j) acc[j] = fmaf(v[i], Wrow[j], acc[j]);
    }
    #pragma unroll
    for (int j = 0; j < 16; j += 4) {
      float4 tq = {fmaxf(acc[j], 0.f), fmaxf(acc[j + 1], 0.f),
                   fmaxf(acc[j + 2], 0.f), fmaxf(acc[j + 3], 0.f)};
      *reinterpret_cast<float4*>(out + c * 16 + j) = tq;
    }
  }
}

// ---- column sums of sum_recv (= sum of all e_h) and n_h
__global__ __launch_bounds__(256) void reduce_kernel(
    const float* __restrict__ sum_recv, const float* __restrict__ n_h,
    float* __restrict__ e_sum, float* __restrict__ n_sum, int N) {
  __shared__ float ls[128];
  if (threadIdx.x < 128) ls[threadIdx.x] = 0.f;
  __syncthreads();
  int g = threadIdx.x & 15;
  int tid = blockIdx.x * blockDim.x + threadIdx.x;
  int row0 = tid >> 4;
  int rstride = (gridDim.x * blockDim.x) >> 4;
  float pe[4] = {0, 0, 0, 0}, pn[4] = {0, 0, 0, 0};
  for (int r = row0; r < N; r += rstride) {
    float4 a = LDF4(sum_recv + (size_t)r * 64 + g * 4);
    float4 b = LDF4(n_h + (size_t)r * 64 + g * 4);
    pe[0] += a.x; pe[1] += a.y; pe[2] += a.z; pe[3] += a.w;
    pn[0] += b.x; pn[1] += b.y; pn[2] += b.z; pn[3] += b.w;
  }
  #pragma unroll
  for (int i = 0; i < 4; ++i) {
    atomicAdd(&ls[g * 4 + i], pe[i]);
    atomicAdd(&ls[64 + g * 4 + i], pn[i]);
  }
  __syncthreads();
  if (threadIdx.x < 64) {
    atomicAdd(&e_sum[threadIdx.x], ls[threadIdx.x]);
    atomicAdd(&n_sum[threadIdx.x], ls[64 + threadIdx.x]);
  }
}

// ---- global block + fold u2 into d1_init
__global__ void global_kernel(const float* __restrict__ u,
                              const float* __restrict__ e_sum,
                              const float* __restrict__ n_sum,
                              const float* __restrict__ W_gb,
                              const float* __restrict__ b_gb,
                              const float* __restrict__ W_d1,
                              const float* __restrict__ b_d1,
                              float* __restrict__ d1_init, float Ef, float Nf) {
  __shared__ float gin[192];
  __shared__ float u2s[64];
  int j = threadIdx.x;  // 64 threads
  gin[j] = e_sum[j] / Ef;
  gin[64 + j] = n_sum[j] / Nf;
  gin[128 + j] = u[j];
  __syncthreads();
  float a = b_gb[j];
  for (int k = 0; k < 192; ++k) a = fmaf(gin[k], W_gb[k * 64 + j], a);
  u2s[j] = fmaxf(a, 0.f);
  __syncthreads();
  float d = b_d1[j];
  for (int k = 0; k < 64; ++k) d = fmaf(u2s[k], W_d1[(192 + k) * 64 + j], d);
  d1_init[j] = d;
}

// ---- decoder
__global__ __launch_bounds__(256, 2) void decoder_kernel(
    const float* __restrict__ sum_recv, const float* __restrict__ sum_sent,
    const uint* __restrict__ cnt_r, const uint* __restrict__ cnt_s,
    const float* __restrict__ n_h, const float* __restrict__ W_d1,
    const float* __restrict__ d1_init, const float* __restrict__ W_d2,
    const float* __restrict__ b_d2, float* __restrict__ out, int N) {
  int n = blockIdx.x * 256 + threadIdx.x;
  if (n >= N) return;
  float acc[64];
  #pragma unroll
  for (int j = 0; j < 64; ++j) acc[j] = d1_init[j];
  float v[16];
  float invr = 1.0f / fmaxf((float)cnt_r[n], 1.0f);
  const float* pr = sum_recv + (size_t)n * 64;
  #pragma unroll
  for (int c = 0; c < 4; ++c) {
    load16(pr + c * 16, v);
    #pragma unroll
    for (int i = 0; i < 16; ++i) v[i] *= invr;
    #pragma unroll
    for (int i = 0; i < 16; ++i) {
      const float* Wrow = W_d1 + (c * 16 + i) * 64;
      #pragma unroll
      for (int j = 0; j < 64; ++j) acc[j] = fmaf(v[i], Wrow[j], acc[j]);
    }
  }
  float invs = 1.0f / fmaxf((float)cnt_s[n], 1.0f);
  const float* ps = sum_sent + (size_t)n * 64;
  #pragma unroll
  for (int c = 0; c < 4; ++c) {
    load16(ps + c * 16, v);
    #pragma unroll
    for (int i = 0; i < 16; ++i) v[i] *= invs;
    #pragma unroll
    for (int i = 0; i < 16; ++i) {
      const float* Wrow = W_d1 + (64 + c * 16 + i) * 64;
      #pragma unroll
      for (int j = 0; j < 64; ++j) acc[j] = fmaf(v[i], Wrow[j], acc[j]);
    }
  }
  const float* pn = n_h + (size_t)n * 64;
  #pragma unroll
  for (int c = 0; c < 4; ++c) {
    load16(pn + c * 16, v);
    #pragma unroll
    for (int i = 0; i < 16; ++i) {
      const float* Wrow = W_d1 + (128 + c * 16 + i) * 64;
      #pragma unroll
      for (int j = 0; j < 64; ++j) acc[j] = fmaf(v[i], Wrow[j], acc[j]);
    }
  }
  #pragma unroll
  for (int j = 0; j < 64; ++j) acc[j] = fmaxf(acc[j], 0.f);
  float* po = out + (size_t)n * 16;
  #pragma unroll
  for (int o = 0; o < 16; o += 4) {
    float4 tq;
    float* tp = &tq.x;
    #pragma unroll
    for (int q = 0; q < 4; ++q) {
      float a = b_d2[o + q];
      #pragma unroll
      for (int j = 0; j < 64; ++j) a = fmaf(acc[j], W_d2[j * 16 + o + q], a);
      tp[q] = a;
    }
    *reinterpret_cast<float4*>(po + o) = tq;
  }
}

extern "C" void kernel_launch(void* const* d_in, const int* in_sizes, int n_in,
                              void* d_out, int out_size, void* d_ws,
                              size_t ws_size, hipStream_t stream) {
  const float* x         = (const float*)d_in[0];
  const float* edge_attr = (const float*)d_in[1];
  const float* u         = (const float*)d_in[2];
  const int*   senders   = (const int*)d_in[3];
  const int*   receivers = (const int*)d_in[4];
  const float* W_eb = (const float*)d_in[7];
  const float* b_eb = (const float*)d_in[8];
  const float* W_nb = (const float*)d_in[9];
  const float* b_nb = (const float*)d_in[10];
  const float* W_gb = (const float*)d_in[11];
  const float* b_gb = (const float*)d_in[12];
  const float* W_d1 = (const float*)d_in[13];
  const float* b_d1 = (const float*)d_in[14];
  const float* W_d2 = (const float*)d_in[15];
  const float* b_d2 = (const float*)d_in[16];

  int N = in_sizes[0] / 16;
  int E = in_sizes[1] / 16;
  int NB = (N + BW - 1) >> BSHIFT;  // 782 for N=100000
  int NDB = (E + DC - 1) / DC;      // distribute chunks per direction

  char* w = (char*)d_ws;
  ushort* e_h = (ushort*)w;          w += (size_t)E * 64 * 2;
  float* sum_recv = (float*)w;       w += (size_t)N * 64 * 4;
  float* sum_sent = (float*)w;       w += (size_t)N * 64 * 4;
  float* n_h = (float*)w;            w += (size_t)N * 64 * 4;
  uint* tmp_r = (uint*)w;            w += (size_t)E * 4;
  uint* tmp_s = (uint*)w;            w += (size_t)E * 4;
  uint* eidx_r = (uint*)w;           w += (size_t)E * 4;
  uint* eidx_s = (uint*)w;           w += (size_t)E * 4;
  uint* row_ptr_r = (uint*)w;        w += (size_t)N * 4;
  uint* row_ptr_s = (uint*)w;        w += (size_t)N * 4;
  uint* cnt_r = (uint*)w;            w += (size_t)N * 4;
  uint* cnt_s = (uint*)w;            w += (size_t)N * 4;
  uint* start_r = (uint*)w;          w += (size_t)(NB + 1) * 4;
  uint* start_s = (uint*)w;          w += (size_t)(NB + 1) * 4;
  uint* cur_r = (uint*)w;            w += (size_t)NB * 4;
  uint* cur_s = (uint*)w;            w += (size_t)NB * 4;
  // zeroed region
  uint* bcnt_r = (uint*)w;           w += (size_t)NBMAX * 4;
  uint* bcnt_s = (uint*)w;           w += (size_t)NBMAX * 4;
  float* e_sum = (float*)w;          w += 64 * 4;
  float* n_sum = (float*)w;          w += 64 * 4;
  // small non-zeroed
  float* eb_init = (float*)w;        w += 64 * 4;
  float* nb_init = (float*)w;        w += 64 * 4;
  float* d1_init = (float*)w;        w += 64 * 4;

  size_t zero_bytes = (size_t)(2 * NBMAX + 128) * 4;
  hipMemsetAsync(bcnt_r, 0, zero_bytes, stream);

  hipLaunchKernelGGL(precompute_kernel, dim3(1), dim3(64), 0, stream, u, W_eb,
                     b_eb, W_nb, b_nb, eb_init, nb_init);
  hipLaunchKernelGGL(bcount_kernel, dim3(64), dim3(256), 0, stream, receivers,
                     senders, bcnt_r, bcnt_s, E, NB);
  hipLaunchKernelGGL(bscan_kernel, dim3(1), dim3(256), 0, stream, bcnt_r,
                     bcnt_s, start_r, start_s, cur_r, cur_s, E, NB);
  hipLaunchKernelGGL(distribute_kernel, dim3(2 * NDB), dim3(256), 0, stream,
                     receivers, senders, cur_r, cur_s, tmp_r, tmp_s, E, NB);
  hipLaunchKernelGGL(bucketsort_kernel, dim3(2 * NB), dim3(256), 0, stream,
                     tmp_r, tmp_s, start_r, start_s, eidx_r, eidx_s, row_ptr_r,
                     row_ptr_s, cnt_r, cnt_s, N);
  // edge kernel last before gathers: e_h stays L3-resident
  hipLaunchKernelGGL(edge_kernel, dim3((E + 255) / 256), dim3(256), 0, stream,
                     edge_attr, x, senders, receivers, W_eb, eb_init, e_h, E);
  hipLaunchKernelGGL(gather_kernel, dim3((N + 3) / 4), dim3(256), 0, stream,
                     e_h, row_ptr_r, cnt_r, eidx_r, sum_recv, N);
  hipLaunchKernelGGL(gather_kernel, dim3((N + 3) / 4), dim3(256), 0, stream,
                     e_h, row_ptr_s, cnt_s, eidx_s, sum_sent, N);
  hipLaunchKernelGGL(node_kernel, dim3((N + 255) / 256), dim3(256), 0, stream,
                     x, sum_recv, W_nb, nb_init, n_h, N);
  hipLaunchKernelGGL(reduce_kernel, dim3(256), dim3(256), 0, stream, sum_recv,
                     n_h, e_sum, n_sum, N);
  hipLaunchKernelGGL(global_kernel, dim3(1), dim3(64), 0, stream, u, e_sum,
                     n_sum, W_gb, b_gb, W_d1, b_d1, d1_init, (float)E,
                     (float)N);
  hipLaunchKernelGGL(decoder_kernel, dim3((N + 255) / 256), dim3(256), 0,
                     stream, sum_recv, sum_sent, cnt_r, cnt_s, n_h, W_d1,
                     d1_init, W_d2, b_d2, (float*)d_out, N);
}

// Round 7
// 734.502 us; speedup vs baseline: 2.9394x; 1.0483x over previous
//
#include <hip/hip_runtime.h>

// GraphNet forward, fp32 compute / bf16 edge-hidden storage.
// Round 7: r6 pipeline (770us). Fixes:
//  - edge_kernel was VGPR-starved by __launch_bounds__(256,4) (VGPR=36 with
//    v[48] live => compiler re-loads; VALU 144us vs 62us FMA floor). Now
//    (256,2) + two 32-wide acc passes.
//  - x random 64B reads (6.4MB > 4MB per-XCD L2) refetched 180MB from L3.
//    Pre-convert x to bf16 (3.2MB, L2-resident); edge reads 16B/row.
//  - gather: half-wave pairing (uint loads, 2 cols/lane, 2 edges/wave-step,
//    shfl_xor(32) combine) halves issue count, doubles rows in flight.

typedef unsigned int uint;
typedef unsigned short ushort;

#define BW 128          // nodes per bucket
#define BSHIFT 7
#define NBMAX 784       // max buckets (N=100000 -> 782)
#define DC 8192         // edges per distribute block
#define EMASK 0x1FFFFFu // 21 bits of edge id (E=1.6M < 2^21)

#define LDF4(p) (*reinterpret_cast<const float4*>(p))

__device__ __forceinline__ void load16(const float* __restrict__ p, float* v) {
  float4 a = LDF4(p), b = LDF4(p + 4), c = LDF4(p + 8), d = LDF4(p + 12);
  v[0]=a.x; v[1]=a.y; v[2]=a.z; v[3]=a.w;
  v[4]=b.x; v[5]=b.y; v[6]=b.z; v[7]=b.w;
  v[8]=c.x; v[9]=c.y; v[10]=c.z; v[11]=c.w;
  v[12]=d.x; v[13]=d.y; v[14]=d.z; v[15]=d.w;
}

__device__ __forceinline__ ushort f2bf(float f) {
  uint u = __float_as_uint(f);
  u += 0x7FFFu + ((u >> 16) & 1u);
  return (ushort)(u >> 16);
}
__device__ __forceinline__ float bf2f(ushort h) {
  return __uint_as_float((uint)h << 16);
}

// ---- x -> bf16 table (3.2MB, per-XCD-L2-resident)
__global__ __launch_bounds__(256) void xconvert_kernel(
    const float* __restrict__ x, ushort* __restrict__ xb, int n16) {
  int i = blockIdx.x * 256 + threadIdx.x;
  if (i * 4 >= n16) return;
  float4 a = LDF4(x + i * 4);
  ushort4 o = {f2bf(a.x), f2bf(a.y), f2bf(a.z), f2bf(a.w)};
  *reinterpret_cast<ushort4*>(xb + i * 4) = o;
}

// ---- fold uniform-u contributions into per-layer init vectors
__global__ void precompute_kernel(const float* __restrict__ u,
                                  const float* __restrict__ W_eb,
                                  const float* __restrict__ b_eb,
                                  const float* __restrict__ W_nb,
                                  const float* __restrict__ b_nb,
                                  float* __restrict__ eb_init,
                                  float* __restrict__ nb_init) {
  int j = threadIdx.x;  // 64 threads
  float ae = b_eb[j], an = b_nb[j];
  for (int k = 0; k < 64; ++k) {
    float uk = u[k];
    ae = fmaf(uk, W_eb[(48 + k) * 64 + j], ae);
    an = fmaf(uk, W_nb[(80 + k) * 64 + j], an);
  }
  eb_init[j] = ae;
  nb_init[j] = an;
}

// ---- bucket histogram for both directions (LDS hist -> global merge)
__global__ __launch_bounds__(256) void bcount_kernel(
    const int* __restrict__ receivers, const int* __restrict__ senders,
    uint* __restrict__ bcnt_r, uint* __restrict__ bcnt_s, int E, int NB) {
  __shared__ uint hr[NBMAX], hs[NBMAX];
  int t = threadIdx.x;
  for (int i = t; i < NB; i += 256) { hr[i] = 0; hs[i] = 0; }
  __syncthreads();
  int stride = gridDim.x * 256;
  for (int e = blockIdx.x * 256 + t; e < E; e += stride) {
    atomicAdd(&hr[receivers[e] >> BSHIFT], 1u);
    atomicAdd(&hs[senders[e] >> BSHIFT], 1u);
  }
  __syncthreads();
  for (int i = t; i < NB; i += 256) {
    if (hr[i]) atomicAdd(&bcnt_r[i], hr[i]);
    if (hs[i]) atomicAdd(&bcnt_s[i], hs[i]);
  }
}

// ---- exclusive scan of both bucket-count arrays (single block, 4/thread)
__global__ __launch_bounds__(256) void bscan_kernel(
    const uint* __restrict__ bcnt_r, const uint* __restrict__ bcnt_s,
    uint* __restrict__ start_r, uint* __restrict__ start_s,
    uint* __restrict__ cur_r, uint* __restrict__ cur_s, int E, int NB) {
  __shared__ uint ts[256];
  int t = threadIdx.x;
  #pragma unroll
  for (int pass = 0; pass < 2; ++pass) {
    const uint* cnt = pass ? bcnt_s : bcnt_r;
    uint* start = pass ? start_s : start_r;
    uint* cur = pass ? cur_s : cur_r;
    uint loc[4]; uint tsum = 0;
    #pragma unroll
    for (int q = 0; q < 4; ++q) {
      int i = t * 4 + q;
      loc[q] = (i < NB) ? cnt[i] : 0;
      tsum += loc[q];
    }
    ts[t] = tsum;
    __syncthreads();
    for (int off = 1; off < 256; off <<= 1) {
      uint a = (t >= off) ? ts[t - off] : 0;
      __syncthreads();
      ts[t] += a;
      __syncthreads();
    }
    uint run = ts[t] - tsum;
    #pragma unroll
    for (int q = 0; q < 4; ++q) {
      int i = t * 4 + q;
      if (i < NB) { start[i] = run; cur[i] = run; run += loc[q]; }
    }
    if (t == 0) start[NB] = (uint)E;
    __syncthreads();
  }
}

// ---- bucket-sort edge ids, both directions in one launch.
__global__ __launch_bounds__(256) void distribute_kernel(
    const int* __restrict__ receivers, const int* __restrict__ senders,
    uint* __restrict__ gcur_r, uint* __restrict__ gcur_s,
    uint* __restrict__ tmp_r, uint* __restrict__ tmp_s, int E, int NB) {
  __shared__ uint hist[NBMAX], lstart[NBMAX], cur[NBMAX], gbase[NBMAX];
  __shared__ uint ids[DC];
  __shared__ ushort idsB[DC];
  __shared__ uint ts[256];
  int dir = blockIdx.x & 1;
  const int* key = dir ? senders : receivers;
  uint* g_cursor = dir ? gcur_s : gcur_r;
  uint* tmp = dir ? tmp_s : tmp_r;
  int t = threadIdx.x;
  int base = (blockIdx.x >> 1) * DC;
  int cact = min(DC, E - base);
  for (int i = t; i < NB; i += 256) hist[i] = 0;
  __syncthreads();
  for (int k = 0; k < DC / 256; ++k) {
    int j = k * 256 + t;
    if (j < cact) atomicAdd(&hist[key[base + j] >> BSHIFT], 1u);
  }
  __syncthreads();
  {
    uint loc[4]; uint tsum = 0;
    #pragma unroll
    for (int q = 0; q < 4; ++q) {
      int i = t * 4 + q;
      loc[q] = (i < NB) ? hist[i] : 0;
      tsum += loc[q];
    }
    ts[t] = tsum;
    __syncthreads();
    for (int off = 1; off < 256; off <<= 1) {
      uint a = (t >= off) ? ts[t - off] : 0;
      __syncthreads();
      ts[t] += a;
      __syncthreads();
    }
    uint run = ts[t] - tsum;
    #pragma unroll
    for (int q = 0; q < 4; ++q) {
      int i = t * 4 + q;
      if (i < NB) { lstart[i] = run; cur[i] = run; run += loc[q]; }
    }
  }
  __syncthreads();
  for (int i = t; i < NB; i += 256)
    if (hist[i]) gbase[i] = atomicAdd(&g_cursor[i], hist[i]);
  for (int k = 0; k < DC / 256; ++k) {
    int j = k * 256 + t;
    if (j < cact) {
      int e = base + j;
      int kk = key[e];
      uint b = (uint)(kk >> BSHIFT);
      uint slot = atomicAdd(&cur[b], 1u);
      ids[slot] = ((uint)(kk & (BW - 1)) << 21) | (uint)e;
      idsB[slot] = (ushort)b;
    }
  }
  __syncthreads();
  for (int j = t; j < cact; j += 256) {
    uint b2 = idsB[j];
    tmp[gbase[b2] + ((uint)j - lstart[b2])] = ids[j];
  }
}

// ---- per-bucket counting sort to full per-node order.
__global__ __launch_bounds__(256) void bucketsort_kernel(
    const uint* __restrict__ tmp_r, const uint* __restrict__ tmp_s,
    const uint* __restrict__ start_r, const uint* __restrict__ start_s,
    uint* __restrict__ eidx_r, uint* __restrict__ eidx_s,
    uint* __restrict__ row_ptr_r, uint* __restrict__ row_ptr_s,
    uint* __restrict__ cnt_r, uint* __restrict__ cnt_s, int N) {
  __shared__ uint hist[BW], pfx[BW], cur[BW];
  int d = blockIdx.x & 1;
  int b = blockIdx.x >> 1;
  const uint* tmp = d ? tmp_s : tmp_r;
  const uint* start = d ? start_s : start_r;
  uint* eidx = d ? eidx_s : eidx_r;
  uint* row_ptr = d ? row_ptr_s : row_ptr_r;
  uint* cnt = d ? cnt_s : cnt_r;
  int t = threadIdx.x;
  if (t < BW) hist[t] = 0;
  __syncthreads();
  int beg = (int)start[b], end = (int)start[b + 1];
  for (int i = beg + t; i < end; i += 256) atomicAdd(&hist[tmp[i] >> 21], 1u);
  __syncthreads();
  if (t < BW) pfx[t] = hist[t];
  __syncthreads();
  for (int off = 1; off < BW; off <<= 1) {
    uint a = 0;
    if (t < BW && t >= off) a = pfx[t - off];
    __syncthreads();
    if (t < BW) pfx[t] += a;
    __syncthreads();
  }
  if (t < BW) cur[t] = pfx[t] - hist[t];
  __syncthreads();
  for (int i = beg + t; i < end; i += 256) {
    uint v = tmp[i];
    uint nl = v >> 21;
    uint p = atomicAdd(&cur[nl], 1u);
    eidx[beg + p] = v & EMASK;
  }
  int nbase = b * BW;
  if (t < BW && nbase + t < N) {
    cnt[nbase + t] = hist[t];
    row_ptr[nbase + t] = (uint)beg + pfx[t] - hist[t];
  }
}

// ---- edge MLP: e_h = relu([ea, x_r, x_s]@W[0:48] + eb_init) -> bf16.
// v[48] loaded once; two 32-wide acc passes; x rows via bf16 table (16B).
__global__ __launch_bounds__(256, 2) void edge_kernel(
    const float* __restrict__ edge_attr, const ushort* __restrict__ xb,
    const int* __restrict__ senders, const int* __restrict__ receivers,
    const float* __restrict__ W_eb, const float* __restrict__ eb_init,
    ushort* __restrict__ e_h, int E) {
  int e = blockIdx.x * 256 + threadIdx.x;
  if (e >= E) return;
  int r = receivers[e];
  int s = senders[e];
  float v[48];
  load16(edge_attr + (size_t)e * 16, v);
  uint4 xr = *reinterpret_cast<const uint4*>(xb + (size_t)r * 16);
  uint4 xs = *reinterpret_cast<const uint4*>(xb + (size_t)s * 16);
  {
    const uint* pr = &xr.x;
    const uint* ps = &xs.x;
    #pragma unroll
    for (int k = 0; k < 4; ++k) {
      uint wr = pr[k], ws = ps[k];
      v[16 + 2 * k]     = __uint_as_float(wr << 16);
      v[16 + 2 * k + 1] = __uint_as_float(wr & 0xFFFF0000u);
      v[24 + 2 * k]     = __uint_as_float((wr >> 16) << 16);  // placeholder fix below
      v[32 + 2 * k]     = __uint_as_float(ws << 16);
      v[32 + 2 * k + 1] = __uint_as_float(ws & 0xFFFF0000u);
    }
  }
  // The ushort4-packed layout: xb row = 16 bf16 in 4 uints (2 per uint).
  // Redo unpack cleanly (8 uints needed for 16 values -> use two uint4 loads).
  uint4 xr2 = *reinterpret_cast<const uint4*>(xb + (size_t)r * 16 + 8);
  uint4 xs2 = *reinterpret_cast<const uint4*>(xb + (size_t)s * 16 + 8);
  {
    const uint* p0 = &xr.x; const uint* p1 = &xr2.x;
    const uint* q0 = &xs.x; const uint* q1 = &xs2.x;
    #pragma unroll
    for (int k = 0; k < 4; ++k) {
      v[16 + 2 * k]     = __uint_as_float(p0[k] << 16);
      v[16 + 2 * k + 1] = __uint_as_float(p0[k] & 0xFFFF0000u);
      v[24 + 2 * k]     = __uint_as_float(p1[k] << 16);
      v[24 + 2 * k + 1] = __uint_as_float(p1[k] & 0xFFFF0000u);
      v[32 + 2 * k]     = __uint_as_float(q0[k] << 16);
      v[32 + 2 * k + 1] = __uint_as_float(q0[k] & 0xFFFF0000u);
      v[40 + 2 * k]     = __uint_as_float(q1[k] << 16);
      v[40 + 2 * k + 1] = __uint_as_float(q1[k] & 0xFFFF0000u);
    }
  }
  uint4* dst = reinterpret_cast<uint4*>(e_h + (size_t)e * 64);
  #pragma unroll
  for (int h = 0; h < 2; ++h) {
    float acc[32];
    #pragma unroll
    for (int j = 0; j < 32; ++j) acc[j] = eb_init[h * 32 + j];
    #pragma unroll
    for (int i = 0; i < 48; ++i) {
      const float* Wrow = W_eb + i * 64 + h * 32;
      #pragma unroll
      for (int j = 0; j < 32; ++j) acc[j] = fmaf(v[i], Wrow[j], acc[j]);
    }
    union { ushort hh[32]; uint4 q[4]; } pk;
    #pragma unroll
    for (int j = 0; j < 32; ++j) pk.hh[j] = f2bf(fmaxf(acc[j], 0.f));
    #pragma unroll
    for (int q2 = 0; q2 < 4; ++q2) dst[h * 4 + q2] = pk.q[q2];
  }
}

// ---- gather: wave per node; half-waves take alternating edges; uint loads
// (2 cols/lane); combine via shfl_xor(32); float2 store from lanes 0-31.
__global__ __launch_bounds__(256, 4) void gather_kernel(
    const ushort* __restrict__ e_h, const uint* __restrict__ row_ptr,
    const uint* __restrict__ cnt, const uint* __restrict__ eidx,
    float* __restrict__ out, int N) {
  int n = blockIdx.x * 4 + (threadIdx.x >> 6);
  if (n >= N) return;
  const uint* eh32 = reinterpret_cast<const uint*>(e_h);
  int lane = threadIdx.x & 63;
  int half = lane >> 5;
  int l = lane & 31;
  int beg = (int)row_ptr[n], end = beg + (int)cnt[n];
  float a0 = 0, a1 = 0, b0 = 0, b1 = 0;
  int i = beg + half;
  for (; i + 2 < end; i += 4) {
    uint e0 = eidx[i], e1 = eidx[i + 2];
    uint w0 = eh32[(size_t)e0 * 32 + l];
    uint w1 = eh32[(size_t)e1 * 32 + l];
    a0 += __uint_as_float(w0 << 16);
    a1 += __uint_as_float(w0 & 0xFFFF0000u);
    b0 += __uint_as_float(w1 << 16);
    b1 += __uint_as_float(w1 & 0xFFFF0000u);
  }
  for (; i < end; i += 2) {
    uint w0 = eh32[(size_t)eidx[i] * 32 + l];
    a0 += __uint_as_float(w0 << 16);
    a1 += __uint_as_float(w0 & 0xFFFF0000u);
  }
  a0 += b0; a1 += b1;
  a0 += __shfl_xor(a0, 32);
  a1 += __shfl_xor(a1, 32);
  if (half == 0) {
    float2 t = {a0, a1};
    *reinterpret_cast<float2*>(out + (size_t)n * 64 + 2 * l) = t;
  }
}

// ---- node block: n_h = relu([sum_recv, x]@W_nb[0:80] + nb_init)
__global__ __launch_bounds__(256, 2) void node_kernel(
    const float* __restrict__ x, const float* __restrict__ sum_recv,
    const float* __restrict__ W_nb, const float* __restrict__ nb_init,
    float* __restrict__ n_h, int N) {
  int n = blockIdx.x * 256 + threadIdx.x;
  if (n >= N) return;
  float v[80];
  const float* ar = sum_recv + (size_t)n * 64;
  load16(ar, v); load16(ar + 16, v + 16); load16(ar + 32, v + 32);
  load16(ar + 48, v + 48);
  load16(x + (size_t)n * 16, v + 64);
  float* out = n_h + (size_t)n * 64;
  #pragma unroll
  for (int c = 0; c < 2; ++c) {
    float acc[32];
    #pragma unroll
    for (int j = 0; j < 32; ++j) acc[j] = nb_init[c * 32 + j];
    #pragma unroll
    for (int i = 0; i < 80; ++i) {
      const float* Wrow = W_nb + i * 64 + c * 32;
      #pragma unroll
      for (int j = 0; j < 32; ++j) acc[j] = fmaf(v[i], Wrow[j], acc[j]);
    }
    #pragma unroll
    for (int j = 0; j < 32; j += 4) {
      float4 tq = {fmaxf(acc[j], 0.f), fmaxf(acc[j + 1], 0.f),
                   fmaxf(acc[j + 2], 0.f), fmaxf(acc[j + 3], 0.f)};
      *reinterpret_cast<float4*>(out + c * 32 + j) = tq;
    }
  }
}

// ---- column sums of sum_recv (= sum of all e_h) and n_h
__global__ __launch_bounds__(256) void reduce_kernel(
    const float* __restrict__ sum_recv, const float* __restrict__ n_h,
    float* __restrict__ e_sum, float* __restrict__ n_sum, int N) {
  __shared__ float ls[128];
  if (threadIdx.x < 128) ls[threadIdx.x] = 0.f;
  __syncthreads();
  int g = threadIdx.x & 15;
  int tid = blockIdx.x * blockDim.x + threadIdx.x;
  int row0 = tid >> 4;
  int rstride = (gridDim.x * blockDim.x) >> 4;
  float pe[4] = {0, 0, 0, 0}, pn[4] = {0, 0, 0, 0};
  for (int r = row0; r < N; r += rstride) {
    float4 a = LDF4(sum_recv + (size_t)r * 64 + g * 4);
    float4 b = LDF4(n_h + (size_t)r * 64 + g * 4);
    pe[0] += a.x; pe[1] += a.y; pe[2] += a.z; pe[3] += a.w;
    pn[0] += b.x; pn[1] += b.y; pn[2] += b.z; pn[3] += b.w;
  }
  #pragma unroll
  for (int i = 0; i < 4; ++i) {
    atomicAdd(&ls[g * 4 + i], pe[i]);
    atomicAdd(&ls[64 + g * 4 + i], pn[i]);
  }
  __syncthreads();
  if (threadIdx.x < 64) {
    atomicAdd(&e_sum[threadIdx.x], ls[threadIdx.x]);
    atomicAdd(&n_sum[threadIdx.x], ls[64 + threadIdx.x]);
  }
}

// ---- global block + fold u2 into d1_init
__global__ void global_kernel(const float* __restrict__ u,
                              const float* __restrict__ e_sum,
                              const float* __restrict__ n_sum,
                              const float* __restrict__ W_gb,
                              const float* __restrict__ b_gb,
                              const float* __restrict__ W_d1,
                              const float* __restrict__ b_d1,
                              float* __restrict__ d1_init, float Ef, float Nf) {
  __shared__ float gin[192];
  __shared__ float u2s[64];
  int j = threadIdx.x;  // 64 threads
  gin[j] = e_sum[j] / Ef;
  gin[64 + j] = n_sum[j] / Nf;
  gin[128 + j] = u[j];
  __syncthreads();
  float a = b_gb[j];
  for (int k = 0; k < 192; ++k) a = fmaf(gin[k], W_gb[k * 64 + j], a);
  u2s[j] = fmaxf(a, 0.f);
  __syncthreads();
  float d = b_d1[j];
  for (int k = 0; k < 64; ++k) d = fmaf(u2s[k], W_d1[(192 + k) * 64 + j], d);
  d1_init[j] = d;
}

// ---- decoder
__global__ __launch_bounds__(256, 2) void decoder_kernel(
    const float* __restrict__ sum_recv, const float* __restrict__ sum_sent,
    const uint* __restrict__ cnt_r, const uint* __restrict__ cnt_s,
    const float* __restrict__ n_h, const float* __restrict__ W_d1,
    const float* __restrict__ d1_init, const float* __restrict__ W_d2,
    const float* __restrict__ b_d2, float* __restrict__ out, int N) {
  int n = blockIdx.x * 256 + threadIdx.x;
  if (n >= N) return;
  float acc[64];
  #pragma unroll
  for (int j = 0; j < 64; ++j) acc[j] = d1_init[j];
  float v[16];
  float invr = 1.0f / fmaxf((float)cnt_r[n], 1.0f);
  const float* pr = sum_recv + (size_t)n * 64;
  #pragma unroll
  for (int c = 0; c < 4; ++c) {
    load16(pr + c * 16, v);
    #pragma unroll
    for (int i = 0; i < 16; ++i) v[i] *= invr;
    #pragma unroll
    for (int i = 0; i < 16; ++i) {
      const float* Wrow = W_d1 + (c * 16 + i) * 64;
      #pragma unroll
      for (int j = 0; j < 64; ++j) acc[j] = fmaf(v[i], Wrow[j], acc[j]);
    }
  }
  float invs = 1.0f / fmaxf((float)cnt_s[n], 1.0f);
  const float* ps = sum_sent + (size_t)n * 64;
  #pragma unroll
  for (int c = 0; c < 4; ++c) {
    load16(ps + c * 16, v);
    #pragma unroll
    for (int i = 0; i < 16; ++i) v[i] *= invs;
    #pragma unroll
    for (int i = 0; i < 16; ++i) {
      const float* Wrow = W_d1 + (64 + c * 16 + i) * 64;
      #pragma unroll
      for (int j = 0; j < 64; ++j) acc[j] = fmaf(v[i], Wrow[j], acc[j]);
    }
  }
  const float* pn = n_h + (size_t)n * 64;
  #pragma unroll
  for (int c = 0; c < 4; ++c) {
    load16(pn + c * 16, v);
    #pragma unroll
    for (int i = 0; i < 16; ++i) {
      const float* Wrow = W_d1 + (128 + c * 16 + i) * 64;
      #pragma unroll
      for (int j = 0; j < 64; ++j) acc[j] = fmaf(v[i], Wrow[j], acc[j]);
    }
  }
  #pragma unroll
  for (int j = 0; j < 64; ++j) acc[j] = fmaxf(acc[j], 0.f);
  float* po = out + (size_t)n * 16;
  #pragma unroll
  for (int o = 0; o < 16; o += 4) {
    float4 tq;
    float* tp = &tq.x;
    #pragma unroll
    for (int q = 0; q < 4; ++q) {
      float a = b_d2[o + q];
      #pragma unroll
      for (int j = 0; j < 64; ++j) a = fmaf(acc[j], W_d2[j * 16 + o + q], a);
      tp[q] = a;
    }
    *reinterpret_cast<float4*>(po + o) = tq;
  }
}

extern "C" void kernel_launch(void* const* d_in, const int* in_sizes, int n_in,
                              void* d_out, int out_size, void* d_ws,
                              size_t ws_size, hipStream_t stream) {
  const float* x         = (const float*)d_in[0];
  const float* edge_attr = (const float*)d_in[1];
  const float* u         = (const float*)d_in[2];
  const int*   senders   = (const int*)d_in[3];
  const int*   receivers = (const int*)d_in[4];
  const float* W_eb = (const float*)d_in[7];
  const float* b_eb = (const float*)d_in[8];
  const float* W_nb = (const float*)d_in[9];
  const float* b_nb = (const float*)d_in[10];
  const float* W_gb = (const float*)d_in[11];
  const float* b_gb = (const float*)d_in[12];
  const float* W_d1 = (const float*)d_in[13];
  const float* b_d1 = (const float*)d_in[14];
  const float* W_d2 = (const float*)d_in[15];
  const float* b_d2 = (const float*)d_in[16];

  int N = in_sizes[0] / 16;
  int E = in_sizes[1] / 16;
  int NB = (N + BW - 1) >> BSHIFT;  // 782 for N=100000
  int NDB = (E + DC - 1) / DC;      // distribute chunks per direction

  char* w = (char*)d_ws;
  ushort* e_h = (ushort*)w;          w += (size_t)E * 64 * 2;
  float* sum_recv = (float*)w;       w += (size_t)N * 64 * 4;
  float* sum_sent = (float*)w;       w += (size_t)N * 64 * 4;
  float* n_h = (float*)w;            w += (size_t)N * 64 * 4;
  uint* tmp_r = (uint*)w;            w += (size_t)E * 4;
  uint* tmp_s = (uint*)w;            w += (size_t)E * 4;
  uint* eidx_r = (uint*)w;           w += (size_t)E * 4;
  uint* eidx_s = (uint*)w;           w += (size_t)E * 4;
  uint* row_ptr_r = (uint*)w;        w += (size_t)N * 4;
  uint* row_ptr_s = (uint*)w;        w += (size_t)N * 4;
  uint* cnt_r = (uint*)w;            w += (size_t)N * 4;
  uint* cnt_s = (uint*)w;            w += (size_t)N * 4;
  ushort* xb = (ushort*)w;           w += (size_t)N * 16 * 2;
  uint* start_r = (uint*)w;          w += (size_t)(NB + 1) * 4;
  uint* start_s = (uint*)w;          w += (size_t)(NB + 1) * 4;
  uint* cur_r = (uint*)w;            w += (size_t)NB * 4;
  uint* cur_s = (uint*)w;            w += (size_t)NB * 4;
  // zeroed region
  uint* bcnt_r = (uint*)w;           w += (size_t)NBMAX * 4;
  uint* bcnt_s = (uint*)w;           w += (size_t)NBMAX * 4;
  float* e_sum = (float*)w;          w += 64 * 4;
  float* n_sum = (float*)w;          w += 64 * 4;
  // small non-zeroed
  float* eb_init = (float*)w;        w += 64 * 4;
  float* nb_init = (float*)w;        w += 64 * 4;
  float* d1_init = (float*)w;        w += 64 * 4;

  size_t zero_bytes = (size_t)(2 * NBMAX + 128) * 4;
  hipMemsetAsync(bcnt_r, 0, zero_bytes, stream);

  hipLaunchKernelGGL(xconvert_kernel, dim3((N * 16 / 4 + 255) / 256), dim3(256),
                     0, stream, x, xb, N * 16);
  hipLaunchKernelGGL(precompute_kernel, dim3(1), dim3(64), 0, stream, u, W_eb,
                     b_eb, W_nb, b_nb, eb_init, nb_init);
  hipLaunchKernelGGL(bcount_kernel, dim3(64), dim3(256), 0, stream, receivers,
                     senders, bcnt_r, bcnt_s, E, NB);
  hipLaunchKernelGGL(bscan_kernel, dim3(1), dim3(256), 0, stream, bcnt_r,
                     bcnt_s, start_r, start_s, cur_r, cur_s, E, NB);
  hipLaunchKernelGGL(distribute_kernel, dim3(2 * NDB), dim3(256), 0, stream,
                     receivers, senders, cur_r, cur_s, tmp_r, tmp_s, E, NB);
  hipLaunchKernelGGL(bucketsort_kernel, dim3(2 * NB), dim3(256), 0, stream,
                     tmp_r, tmp_s, start_r, start_s, eidx_r, eidx_s, row_ptr_r,
                     row_ptr_s, cnt_r, cnt_s, N);
  // edge kernel last before gathers: e_h stays L3-resident
  hipLaunchKernelGGL(edge_kernel, dim3((E + 255) / 256), dim3(256), 0, stream,
                     edge_attr, xb, senders, receivers, W_eb, eb_init, e_h, E);
  hipLaunchKernelGGL(gather_kernel, dim3((N + 3) / 4), dim3(256), 0, stream,
                     e_h, row_ptr_r, cnt_r, eidx_r, sum_recv, N);
  hipLaunchKernelGGL(gather_kernel, dim3((N + 3) / 4), dim3(256), 0, stream,
                     e_h, row_ptr_s, cnt_s, eidx_s, sum_sent, N);
  hipLaunchKernelGGL(node_kernel, dim3((N + 255) / 256), dim3(256), 0, stream,
                     x, sum_recv, W_nb, nb_init, n_h, N);
  hipLaunchKernelGGL(reduce_kernel, dim3(256), dim3(256), 0, stream, sum_recv,
                     n_h, e_sum, n_sum, N);
  hipLaunchKernelGGL(global_kernel, dim3(1), dim3(64), 0, stream, u, e_sum,
                     n_sum, W_gb, b_gb, W_d1, b_d1, d1_init, (float)E,
                     (float)N);
  hipLaunchKernelGGL(decoder_kernel, dim3((N + 255) / 256), dim3(256), 0,
                     stream, sum_recv, sum_sent, cnt_r, cnt_s, n_h, W_d1,
                     d1_init, W_d2, b_d2, (float*)d_out, N);
}

// Round 8
// 725.219 us; speedup vs baseline: 2.9771x; 1.0128x over previous
//
#include <hip/hip_runtime.h>

// GraphNet forward, fp32 compute / bf16 edge-hidden storage.
// Round 8: edge_kernel was scratch-spilling (VGPR=44 with v[48] live;
// WRITE 307MB vs 205 ideal = +102MB scratch, FETCH +75MB re-read). Fix:
// all 8 input vector loads issued up front into named values, ONE 64-wide
// accumulator pass (live set ~110 VGPR <= (256,2) cap 256). Spilling acc
// across the FMA chain is now the expensive option, so the allocator won't.

typedef unsigned int uint;
typedef unsigned short ushort;

#define BW 128          // nodes per bucket
#define BSHIFT 7
#define NBMAX 784       // max buckets (N=100000 -> 782)
#define DC 8192         // edges per distribute block
#define EMASK 0x1FFFFFu // 21 bits of edge id (E=1.6M < 2^21)

#define LDF4(p) (*reinterpret_cast<const float4*>(p))

__device__ __forceinline__ void load16(const float* __restrict__ p, float* v) {
  float4 a = LDF4(p), b = LDF4(p + 4), c = LDF4(p + 8), d = LDF4(p + 12);
  v[0]=a.x; v[1]=a.y; v[2]=a.z; v[3]=a.w;
  v[4]=b.x; v[5]=b.y; v[6]=b.z; v[7]=b.w;
  v[8]=c.x; v[9]=c.y; v[10]=c.z; v[11]=c.w;
  v[12]=d.x; v[13]=d.y; v[14]=d.z; v[15]=d.w;
}

__device__ __forceinline__ ushort f2bf(float f) {
  uint u = __float_as_uint(f);
  u += 0x7FFFu + ((u >> 16) & 1u);
  return (ushort)(u >> 16);
}

// ---- x -> bf16 table (3.2MB, per-XCD-L2-resident)
__global__ __launch_bounds__(256) void xconvert_kernel(
    const float* __restrict__ x, ushort* __restrict__ xb, int n16) {
  int i = blockIdx.x * 256 + threadIdx.x;
  if (i * 4 >= n16) return;
  float4 a = LDF4(x + i * 4);
  ushort4 o = {f2bf(a.x), f2bf(a.y), f2bf(a.z), f2bf(a.w)};
  *reinterpret_cast<ushort4*>(xb + i * 4) = o;
}

// ---- fold uniform-u contributions into per-layer init vectors
__global__ void precompute_kernel(const float* __restrict__ u,
                                  const float* __restrict__ W_eb,
                                  const float* __restrict__ b_eb,
                                  const float* __restrict__ W_nb,
                                  const float* __restrict__ b_nb,
                                  float* __restrict__ eb_init,
                                  float* __restrict__ nb_init) {
  int j = threadIdx.x;  // 64 threads
  float ae = b_eb[j], an = b_nb[j];
  for (int k = 0; k < 64; ++k) {
    float uk = u[k];
    ae = fmaf(uk, W_eb[(48 + k) * 64 + j], ae);
    an = fmaf(uk, W_nb[(80 + k) * 64 + j], an);
  }
  eb_init[j] = ae;
  nb_init[j] = an;
}

// ---- bucket histogram for both directions (LDS hist -> global merge)
__global__ __launch_bounds__(256) void bcount_kernel(
    const int* __restrict__ receivers, const int* __restrict__ senders,
    uint* __restrict__ bcnt_r, uint* __restrict__ bcnt_s, int E, int NB) {
  __shared__ uint hr[NBMAX], hs[NBMAX];
  int t = threadIdx.x;
  for (int i = t; i < NB; i += 256) { hr[i] = 0; hs[i] = 0; }
  __syncthreads();
  int stride = gridDim.x * 256;
  for (int e = blockIdx.x * 256 + t; e < E; e += stride) {
    atomicAdd(&hr[receivers[e] >> BSHIFT], 1u);
    atomicAdd(&hs[senders[e] >> BSHIFT], 1u);
  }
  __syncthreads();
  for (int i = t; i < NB; i += 256) {
    if (hr[i]) atomicAdd(&bcnt_r[i], hr[i]);
    if (hs[i]) atomicAdd(&bcnt_s[i], hs[i]);
  }
}

// ---- exclusive scan of both bucket-count arrays (single block, 4/thread)
__global__ __launch_bounds__(256) void bscan_kernel(
    const uint* __restrict__ bcnt_r, const uint* __restrict__ bcnt_s,
    uint* __restrict__ start_r, uint* __restrict__ start_s,
    uint* __restrict__ cur_r, uint* __restrict__ cur_s, int E, int NB) {
  __shared__ uint ts[256];
  int t = threadIdx.x;
  #pragma unroll
  for (int pass = 0; pass < 2; ++pass) {
    const uint* cnt = pass ? bcnt_s : bcnt_r;
    uint* start = pass ? start_s : start_r;
    uint* cur = pass ? cur_s : cur_r;
    uint loc[4]; uint tsum = 0;
    #pragma unroll
    for (int q = 0; q < 4; ++q) {
      int i = t * 4 + q;
      loc[q] = (i < NB) ? cnt[i] : 0;
      tsum += loc[q];
    }
    ts[t] = tsum;
    __syncthreads();
    for (int off = 1; off < 256; off <<= 1) {
      uint a = (t >= off) ? ts[t - off] : 0;
      __syncthreads();
      ts[t] += a;
      __syncthreads();
    }
    uint run = ts[t] - tsum;
    #pragma unroll
    for (int q = 0; q < 4; ++q) {
      int i = t * 4 + q;
      if (i < NB) { start[i] = run; cur[i] = run; run += loc[q]; }
    }
    if (t == 0) start[NB] = (uint)E;
    __syncthreads();
  }
}

// ---- bucket-sort edge ids, both directions in one launch.
__global__ __launch_bounds__(256) void distribute_kernel(
    const int* __restrict__ receivers, const int* __restrict__ senders,
    uint* __restrict__ gcur_r, uint* __restrict__ gcur_s,
    uint* __restrict__ tmp_r, uint* __restrict__ tmp_s, int E, int NB) {
  __shared__ uint hist[NBMAX], lstart[NBMAX], cur[NBMAX], gbase[NBMAX];
  __shared__ uint ids[DC];
  __shared__ ushort idsB[DC];
  __shared__ uint ts[256];
  int dir = blockIdx.x & 1;
  const int* key = dir ? senders : receivers;
  uint* g_cursor = dir ? gcur_s : gcur_r;
  uint* tmp = dir ? tmp_s : tmp_r;
  int t = threadIdx.x;
  int base = (blockIdx.x >> 1) * DC;
  int cact = min(DC, E - base);
  for (int i = t; i < NB; i += 256) hist[i] = 0;
  __syncthreads();
  for (int k = 0; k < DC / 256; ++k) {
    int j = k * 256 + t;
    if (j < cact) atomicAdd(&hist[key[base + j] >> BSHIFT], 1u);
  }
  __syncthreads();
  {
    uint loc[4]; uint tsum = 0;
    #pragma unroll
    for (int q = 0; q < 4; ++q) {
      int i = t * 4 + q;
      loc[q] = (i < NB) ? hist[i] : 0;
      tsum += loc[q];
    }
    ts[t] = tsum;
    __syncthreads();
    for (int off = 1; off < 256; off <<= 1) {
      uint a = (t >= off) ? ts[t - off] : 0;
      __syncthreads();
      ts[t] += a;
      __syncthreads();
    }
    uint run = ts[t] - tsum;
    #pragma unroll
    for (int q = 0; q < 4; ++q) {
      int i = t * 4 + q;
      if (i < NB) { lstart[i] = run; cur[i] = run; run += loc[q]; }
    }
  }
  __syncthreads();
  for (int i = t; i < NB; i += 256)
    if (hist[i]) gbase[i] = atomicAdd(&g_cursor[i], hist[i]);
  for (int k = 0; k < DC / 256; ++k) {
    int j = k * 256 + t;
    if (j < cact) {
      int e = base + j;
      int kk = key[e];
      uint b = (uint)(kk >> BSHIFT);
      uint slot = atomicAdd(&cur[b], 1u);
      ids[slot] = ((uint)(kk & (BW - 1)) << 21) | (uint)e;
      idsB[slot] = (ushort)b;
    }
  }
  __syncthreads();
  for (int j = t; j < cact; j += 256) {
    uint b2 = idsB[j];
    tmp[gbase[b2] + ((uint)j - lstart[b2])] = ids[j];
  }
}

// ---- per-bucket counting sort to full per-node order.
__global__ __launch_bounds__(256) void bucketsort_kernel(
    const uint* __restrict__ tmp_r, const uint* __restrict__ tmp_s,
    const uint* __restrict__ start_r, const uint* __restrict__ start_s,
    uint* __restrict__ eidx_r, uint* __restrict__ eidx_s,
    uint* __restrict__ row_ptr_r, uint* __restrict__ row_ptr_s,
    uint* __restrict__ cnt_r, uint* __restrict__ cnt_s, int N) {
  __shared__ uint hist[BW], pfx[BW], cur[BW];
  int d = blockIdx.x & 1;
  int b = blockIdx.x >> 1;
  const uint* tmp = d ? tmp_s : tmp_r;
  const uint* start = d ? start_s : start_r;
  uint* eidx = d ? eidx_s : eidx_r;
  uint* row_ptr = d ? row_ptr_s : row_ptr_r;
  uint* cnt = d ? cnt_s : cnt_r;
  int t = threadIdx.x;
  if (t < BW) hist[t] = 0;
  __syncthreads();
  int beg = (int)start[b], end = (int)start[b + 1];
  for (int i = beg + t; i < end; i += 256) atomicAdd(&hist[tmp[i] >> 21], 1u);
  __syncthreads();
  if (t < BW) pfx[t] = hist[t];
  __syncthreads();
  for (int off = 1; off < BW; off <<= 1) {
    uint a = 0;
    if (t < BW && t >= off) a = pfx[t - off];
    __syncthreads();
    if (t < BW) pfx[t] += a;
    __syncthreads();
  }
  if (t < BW) cur[t] = pfx[t] - hist[t];
  __syncthreads();
  for (int i = beg + t; i < end; i += 256) {
    uint v = tmp[i];
    uint nl = v >> 21;
    uint p = atomicAdd(&cur[nl], 1u);
    eidx[beg + p] = v & EMASK;
  }
  int nbase = b * BW;
  if (t < BW && nbase + t < N) {
    cnt[nbase + t] = hist[t];
    row_ptr[nbase + t] = (uint)beg + pfx[t] - hist[t];
  }
}

// ---- edge MLP: e_h = relu([ea, x_r, x_s]@W[0:48] + eb_init) -> bf16.
// All input loads up front (named values), one 64-wide acc pass.
__global__ __launch_bounds__(256, 2) void edge_kernel(
    const float* __restrict__ edge_attr, const ushort* __restrict__ xb,
    const int* __restrict__ senders, const int* __restrict__ receivers,
    const float* __restrict__ W_eb, const float* __restrict__ eb_init,
    ushort* __restrict__ e_h, int E) {
  int e = blockIdx.x * 256 + threadIdx.x;
  if (e >= E) return;
  int r = receivers[e];
  int s = senders[e];
  const float* ea_p = edge_attr + (size_t)e * 16;
  float4 a0 = LDF4(ea_p), a1 = LDF4(ea_p + 4), a2 = LDF4(ea_p + 8),
         a3 = LDF4(ea_p + 12);
  const uint4* xrp = reinterpret_cast<const uint4*>(xb + (size_t)r * 16);
  const uint4* xsp = reinterpret_cast<const uint4*>(xb + (size_t)s * 16);
  uint4 xr0 = xrp[0], xr1 = xrp[1];
  uint4 xs0 = xsp[0], xs1 = xsp[1];

  float acc[64];
  #pragma unroll
  for (int j = 0; j < 64; ++j) acc[j] = eb_init[j];

  float ea[16] = {a0.x, a0.y, a0.z, a0.w, a1.x, a1.y, a1.z, a1.w,
                  a2.x, a2.y, a2.z, a2.w, a3.x, a3.y, a3.z, a3.w};
  #pragma unroll
  for (int i = 0; i < 16; ++i) {
    const float* Wr = W_eb + i * 64;
    #pragma unroll
    for (int j = 0; j < 64; ++j) acc[j] = fmaf(ea[i], Wr[j], acc[j]);
  }
  uint xru[8] = {xr0.x, xr0.y, xr0.z, xr0.w, xr1.x, xr1.y, xr1.z, xr1.w};
  #pragma unroll
  for (int k = 0; k < 8; ++k) {
    float v0 = __uint_as_float(xru[k] << 16);
    float v1 = __uint_as_float(xru[k] & 0xFFFF0000u);
    const float* Wr = W_eb + (16 + 2 * k) * 64;
    #pragma unroll
    for (int j = 0; j < 64; ++j) acc[j] = fmaf(v0, Wr[j], acc[j]);
    #pragma unroll
    for (int j = 0; j < 64; ++j) acc[j] = fmaf(v1, Wr[64 + j], acc[j]);
  }
  uint xsu[8] = {xs0.x, xs0.y, xs0.z, xs0.w, xs1.x, xs1.y, xs1.z, xs1.w};
  #pragma unroll
  for (int k = 0; k < 8; ++k) {
    float v0 = __uint_as_float(xsu[k] << 16);
    float v1 = __uint_as_float(xsu[k] & 0xFFFF0000u);
    const float* Wr = W_eb + (32 + 2 * k) * 64;
    #pragma unroll
    for (int j = 0; j < 64; ++j) acc[j] = fmaf(v0, Wr[j], acc[j]);
    #pragma unroll
    for (int j = 0; j < 64; ++j) acc[j] = fmaf(v1, Wr[64 + j], acc[j]);
  }

  union { ushort hh[64]; uint4 q[8]; } pk;
  #pragma unroll
  for (int j = 0; j < 64; ++j) pk.hh[j] = f2bf(fmaxf(acc[j], 0.f));
  uint4* dst = reinterpret_cast<uint4*>(e_h + (size_t)e * 64);
  #pragma unroll
  for (int q2 = 0; q2 < 8; ++q2) dst[q2] = pk.q[q2];
}

// ---- gather: wave per node; half-waves take alternating edges; uint loads
// (2 cols/lane); combine via shfl_xor(32); float2 store from lanes 0-31.
__global__ __launch_bounds__(256, 4) void gather_kernel(
    const ushort* __restrict__ e_h, const uint* __restrict__ row_ptr,
    const uint* __restrict__ cnt, const uint* __restrict__ eidx,
    float* __restrict__ out, int N) {
  int n = blockIdx.x * 4 + (threadIdx.x >> 6);
  if (n >= N) return;
  const uint* eh32 = reinterpret_cast<const uint*>(e_h);
  int lane = threadIdx.x & 63;
  int half = lane >> 5;
  int l = lane & 31;
  int beg = (int)row_ptr[n], end = beg + (int)cnt[n];
  float a0 = 0, a1 = 0, b0 = 0, b1 = 0;
  int i = beg + half;
  for (; i + 2 < end; i += 4) {
    uint e0 = eidx[i], e1 = eidx[i + 2];
    uint w0 = eh32[(size_t)e0 * 32 + l];
    uint w1 = eh32[(size_t)e1 * 32 + l];
    a0 += __uint_as_float(w0 << 16);
    a1 += __uint_as_float(w0 & 0xFFFF0000u);
    b0 += __uint_as_float(w1 << 16);
    b1 += __uint_as_float(w1 & 0xFFFF0000u);
  }
  for (; i < end; i += 2) {
    uint w0 = eh32[(size_t)eidx[i] * 32 + l];
    a0 += __uint_as_float(w0 << 16);
    a1 += __uint_as_float(w0 & 0xFFFF0000u);
  }
  a0 += b0; a1 += b1;
  a0 += __shfl_xor(a0, 32);
  a1 += __shfl_xor(a1, 32);
  if (half == 0) {
    float2 t = {a0, a1};
    *reinterpret_cast<float2*>(out + (size_t)n * 64 + 2 * l) = t;
  }
}

// ---- node block: n_h = relu([sum_recv, x]@W_nb[0:80] + nb_init)
__global__ __launch_bounds__(256, 2) void node_kernel(
    const float* __restrict__ x, const float* __restrict__ sum_recv,
    const float* __restrict__ W_nb, const float* __restrict__ nb_init,
    float* __restrict__ n_h, int N) {
  int n = blockIdx.x * 256 + threadIdx.x;
  if (n >= N) return;
  float v[80];
  const float* ar = sum_recv + (size_t)n * 64;
  load16(ar, v); load16(ar + 16, v + 16); load16(ar + 32, v + 32);
  load16(ar + 48, v + 48);
  load16(x + (size_t)n * 16, v + 64);
  float* out = n_h + (size_t)n * 64;
  #pragma unroll
  for (int c = 0; c < 2; ++c) {
    float acc[32];
    #pragma unroll
    for (int j = 0; j < 32; ++j) acc[j] = nb_init[c * 32 + j];
    #pragma unroll
    for (int i = 0; i < 80; ++i) {
      const float* Wrow = W_nb + i * 64 + c * 32;
      #pragma unroll
      for (int j = 0; j < 32; ++j) acc[j] = fmaf(v[i], Wrow[j], acc[j]);
    }
    #pragma unroll
    for (int j = 0; j < 32; j += 4) {
      float4 tq = {fmaxf(acc[j], 0.f), fmaxf(acc[j + 1], 0.f),
                   fmaxf(acc[j + 2], 0.f), fmaxf(acc[j + 3], 0.f)};
      *reinterpret_cast<float4*>(out + c * 32 + j) = tq;
    }
  }
}

// ---- column sums of sum_recv (= sum of all e_h) and n_h
__global__ __launch_bounds__(256) void reduce_kernel(
    const float* __restrict__ sum_recv, const float* __restrict__ n_h,
    float* __restrict__ e_sum, float* __restrict__ n_sum, int N) {
  __shared__ float ls[128];
  if (threadIdx.x < 128) ls[threadIdx.x] = 0.f;
  __syncthreads();
  int g = threadIdx.x & 15;
  int tid = blockIdx.x * blockDim.x + threadIdx.x;
  int row0 = tid >> 4;
  int rstride = (gridDim.x * blockDim.x) >> 4;
  float pe[4] = {0, 0, 0, 0}, pn[4] = {0, 0, 0, 0};
  for (int r = row0; r < N; r += rstride) {
    float4 a = LDF4(sum_recv + (size_t)r * 64 + g * 4);
    float4 b = LDF4(n_h + (size_t)r * 64 + g * 4);
    pe[0] += a.x; pe[1] += a.y; pe[2] += a.z; pe[3] += a.w;
    pn[0] += b.x; pn[1] += b.y; pn[2] += b.z; pn[3] += b.w;
  }
  #pragma unroll
  for (int i = 0; i < 4; ++i) {
    atomicAdd(&ls[g * 4 + i], pe[i]);
    atomicAdd(&ls[64 + g * 4 + i], pn[i]);
  }
  __syncthreads();
  if (threadIdx.x < 64) {
    atomicAdd(&e_sum[threadIdx.x], ls[threadIdx.x]);
    atomicAdd(&n_sum[threadIdx.x], ls[64 + threadIdx.x]);
  }
}

// ---- global block + fold u2 into d1_init
__global__ void global_kernel(const float* __restrict__ u,
                              const float* __restrict__ e_sum,
                              const float* __restrict__ n_sum,
                              const float* __restrict__ W_gb,
                              const float* __restrict__ b_gb,
                              const float* __restrict__ W_d1,
                              const float* __restrict__ b_d1,
                              float* __restrict__ d1_init, float Ef, float Nf) {
  __shared__ float gin[192];
  __shared__ float u2s[64];
  int j = threadIdx.x;  // 64 threads
  gin[j] = e_sum[j] / Ef;
  gin[64 + j] = n_sum[j] / Nf;
  gin[128 + j] = u[j];
  __syncthreads();
  float a = b_gb[j];
  for (int k = 0; k < 192; ++k) a = fmaf(gin[k], W_gb[k * 64 + j], a);
  u2s[j] = fmaxf(a, 0.f);
  __syncthreads();
  float d = b_d1[j];
  for (int k = 0; k < 64; ++k) d = fmaf(u2s[k], W_d1[(192 + k) * 64 + j], d);
  d1_init[j] = d;
}

// ---- decoder
__global__ __launch_bounds__(256, 2) void decoder_kernel(
    const float* __restrict__ sum_recv, const float* __restrict__ sum_sent,
    const uint* __restrict__ cnt_r, const uint* __restrict__ cnt_s,
    const float* __restrict__ n_h, const float* __restrict__ W_d1,
    const float* __restrict__ d1_init, const float* __restrict__ W_d2,
    const float* __restrict__ b_d2, float* __restrict__ out, int N) {
  int n = blockIdx.x * 256 + threadIdx.x;
  if (n >= N) return;
  float acc[64];
  #pragma unroll
  for (int j = 0; j < 64; ++j) acc[j] = d1_init[j];
  float v[16];
  float invr = 1.0f / fmaxf((float)cnt_r[n], 1.0f);
  const float* pr = sum_recv + (size_t)n * 64;
  #pragma unroll
  for (int c = 0; c < 4; ++c) {
    load16(pr + c * 16, v);
    #pragma unroll
    for (int i = 0; i < 16; ++i) v[i] *= invr;
    #pragma unroll
    for (int i = 0; i < 16; ++i) {
      const float* Wrow = W_d1 + (c * 16 + i) * 64;
      #pragma unroll
      for (int j = 0; j < 64; ++j) acc[j] = fmaf(v[i], Wrow[j], acc[j]);
    }
  }
  float invs = 1.0f / fmaxf((float)cnt_s[n], 1.0f);
  const float* ps = sum_sent + (size_t)n * 64;
  #pragma unroll
  for (int c = 0; c < 4; ++c) {
    load16(ps + c * 16, v);
    #pragma unroll
    for (int i = 0; i < 16; ++i) v[i] *= invs;
    #pragma unroll
    for (int i = 0; i < 16; ++i) {
      const float* Wrow = W_d1 + (64 + c * 16 + i) * 64;
      #pragma unroll
      for (int j = 0; j < 64; ++j) acc[j] = fmaf(v[i], Wrow[j], acc[j]);
    }
  }
  const float* pn = n_h + (size_t)n * 64;
  #pragma unroll
  for (int c = 0; c < 4; ++c) {
    load16(pn + c * 16, v);
    #pragma unroll
    for (int i = 0; i < 16; ++i) {
      const float* Wrow = W_d1 + (128 + c * 16 + i) * 64;
      #pragma unroll
      for (int j = 0; j < 64; ++j) acc[j] = fmaf(v[i], Wrow[j], acc[j]);
    }
  }
  #pragma unroll
  for (int j = 0; j < 64; ++j) acc[j] = fmaxf(acc[j], 0.f);
  float* po = out + (size_t)n * 16;
  #pragma unroll
  for (int o = 0; o < 16; o += 4) {
    float4 tq;
    float* tp = &tq.x;
    #pragma unroll
    for (int q = 0; q < 4; ++q) {
      float a = b_d2[o + q];
      #pragma unroll
      for (int j = 0; j < 64; ++j) a = fmaf(acc[j], W_d2[j * 16 + o + q], a);
      tp[q] = a;
    }
    *reinterpret_cast<float4*>(po + o) = tq;
  }
}

extern "C" void kernel_launch(void* const* d_in, const int* in_sizes, int n_in,
                              void* d_out, int out_size, void* d_ws,
                              size_t ws_size, hipStream_t stream) {
  const float* x         = (const float*)d_in[0];
  const float* edge_attr = (const float*)d_in[1];
  const float* u         = (const float*)d_in[2];
  const int*   senders   = (const int*)d_in[3];
  const int*   receivers = (const int*)d_in[4];
  const float* W_eb = (const float*)d_in[7];
  const float* b_eb = (const float*)d_in[8];
  const float* W_nb = (const float*)d_in[9];
  const float* b_nb = (const float*)d_in[10];
  const float* W_gb = (const float*)d_in[11];
  const float* b_gb = (const float*)d_in[12];
  const float* W_d1 = (const float*)d_in[13];
  const float* b_d1 = (const float*)d_in[14];
  const float* W_d2 = (const float*)d_in[15];
  const float* b_d2 = (const float*)d_in[16];

  int N = in_sizes[0] / 16;
  int E = in_sizes[1] / 16;
  int NB = (N + BW - 1) >> BSHIFT;  // 782 for N=100000
  int NDB = (E + DC - 1) / DC;      // distribute chunks per direction

  char* w = (char*)d_ws;
  ushort* e_h = (ushort*)w;          w += (size_t)E * 64 * 2;
  float* sum_recv = (float*)w;       w += (size_t)N * 64 * 4;
  float* sum_sent = (float*)w;       w += (size_t)N * 64 * 4;
  float* n_h = (float*)w;            w += (size_t)N * 64 * 4;
  uint* tmp_r = (uint*)w;            w += (size_t)E * 4;
  uint* tmp_s = (uint*)w;            w += (size_t)E * 4;
  uint* eidx_r = (uint*)w;           w += (size_t)E * 4;
  uint* eidx_s = (uint*)w;           w += (size_t)E * 4;
  uint* row_ptr_r = (uint*)w;        w += (size_t)N * 4;
  uint* row_ptr_s = (uint*)w;        w += (size_t)N * 4;
  uint* cnt_r = (uint*)w;            w += (size_t)N * 4;
  uint* cnt_s = (uint*)w;            w += (size_t)N * 4;
  ushort* xb = (ushort*)w;           w += (size_t)N * 16 * 2;
  uint* start_r = (uint*)w;          w += (size_t)(NB + 1) * 4;
  uint* start_s = (uint*)w;          w += (size_t)(NB + 1) * 4;
  uint* cur_r = (uint*)w;            w += (size_t)NB * 4;
  uint* cur_s = (uint*)w;            w += (size_t)NB * 4;
  // zeroed region
  uint* bcnt_r = (uint*)w;           w += (size_t)NBMAX * 4;
  uint* bcnt_s = (uint*)w;           w += (size_t)NBMAX * 4;
  float* e_sum = (float*)w;          w += 64 * 4;
  float* n_sum = (float*)w;          w += 64 * 4;
  // small non-zeroed
  float* eb_init = (float*)w;        w += 64 * 4;
  float* nb_init = (float*)w;        w += 64 * 4;
  float* d1_init = (float*)w;        w += 64 * 4;

  size_t zero_bytes = (size_t)(2 * NBMAX + 128) * 4;
  hipMemsetAsync(bcnt_r, 0, zero_bytes, stream);

  hipLaunchKernelGGL(xconvert_kernel, dim3((N * 16 / 4 + 255) / 256), dim3(256),
                     0, stream, x, xb, N * 16);
  hipLaunchKernelGGL(precompute_kernel, dim3(1), dim3(64), 0, stream, u, W_eb,
                     b_eb, W_nb, b_nb, eb_init, nb_init);
  hipLaunchKernelGGL(bcount_kernel, dim3(64), dim3(256), 0, stream, receivers,
                     senders, bcnt_r, bcnt_s, E, NB);
  hipLaunchKernelGGL(bscan_kernel, dim3(1), dim3(256), 0, stream, bcnt_r,
                     bcnt_s, start_r, start_s, cur_r, cur_s, E, NB);
  hipLaunchKernelGGL(distribute_kernel, dim3(2 * NDB), dim3(256), 0, stream,
                     receivers, senders, cur_r, cur_s, tmp_r, tmp_s, E, NB);
  hipLaunchKernelGGL(bucketsort_kernel, dim3(2 * NB), dim3(256), 0, stream,
                     tmp_r, tmp_s, start_r, start_s, eidx_r, eidx_s, row_ptr_r,
                     row_ptr_s, cnt_r, cnt_s, N);
  // edge kernel last before gathers: e_h stays L3-resident
  hipLaunchKernelGGL(edge_kernel, dim3((E + 255) / 256), dim3(256), 0, stream,
                     edge_attr, xb, senders, receivers, W_eb, eb_init, e_h, E);
  hipLaunchKernelGGL(gather_kernel, dim3((N + 3) / 4), dim3(256), 0, stream,
                     e_h, row_ptr_r, cnt_r, eidx_r, sum_recv, N);
  hipLaunchKernelGGL(gather_kernel, dim3((N + 3) / 4), dim3(256), 0, stream,
                     e_h, row_ptr_s, cnt_s, eidx_s, sum_sent, N);
  hipLaunchKernelGGL(node_kernel, dim3((N + 255) / 256), dim3(256), 0, stream,
                     x, sum_recv, W_nb, nb_init, n_h, N);
  hipLaunchKernelGGL(reduce_kernel, dim3(256), dim3(256), 0, stream, sum_recv,
                     n_h, e_sum, n_sum, N);
  hipLaunchKernelGGL(global_kernel, dim3(1), dim3(64), 0, stream, u, e_sum,
                     n_sum, W_gb, b_gb, W_d1, b_d1, d1_init, (float)E,
                     (float)N);
  hipLaunchKernelGGL(decoder_kernel, dim3((N + 255) / 256), dim3(256), 0,
                     stream, sum_recv, sum_sent, cnt_r, cnt_s, n_h, W_d1,
                     d1_init, W_d2, b_d2, (float*)d_out, N);
}

// Round 9
// 672.064 us; speedup vs baseline: 3.2125x; 1.0791x over previous
//
#include <hip/hip_runtime.h>

// GraphNet forward. Round 9: edge MLP -> bf16 MFMA.
// r7/r8 lesson: the VALU path for the [1.6M x 48]@[48 x 64] edge GEMM has a
// structural ~2.3x issue tax (allocator chunks acc[64], VALUBusy 75%,
// 192us vs 62us FMA floor). MFMA peak is 16x the vector FLOPs; kernel
// becomes memory-bound (~51us floor: 102MB attr read + 205MB e_h write).
// A tile [64 edges][64 K] bf16 in LDS, XOR-swizzled (G4); W transposed +
// pre-swizzled ONCE into an 8KB global image (precompute), copied linearly
// per block; 8x mfma_f32_16x16x32_bf16 per wave; C via LDS transpose bounce.

typedef unsigned int uint;
typedef unsigned short ushort;
typedef __attribute__((ext_vector_type(8))) short bf16x8;
typedef __attribute__((ext_vector_type(4))) float f32x4;

#define BW 128          // nodes per bucket (sort)
#define BSHIFT 7
#define NBMAX 784       // max buckets (N=100000 -> 782)
#define DC 8192         // edges per distribute block
#define EMASK 0x1FFFFFu // 21 bits of edge id

#define LDF4(p) (*reinterpret_cast<const float4*>(p))

__device__ __forceinline__ void load16(const float* __restrict__ p, float* v) {
  float4 a = LDF4(p), b = LDF4(p + 4), c = LDF4(p + 8), d = LDF4(p + 12);
  v[0]=a.x; v[1]=a.y; v[2]=a.z; v[3]=a.w;
  v[4]=b.x; v[5]=b.y; v[6]=b.z; v[7]=b.w;
  v[8]=c.x; v[9]=c.y; v[10]=c.z; v[11]=c.w;
  v[12]=d.x; v[13]=d.y; v[14]=d.z; v[15]=d.w;
}

__device__ __forceinline__ ushort f2bf(float f) {
  uint u = __float_as_uint(f);
  u += 0x7FFFu + ((u >> 16) & 1u);
  return (ushort)(u >> 16);
}

// swizzled ushort index of the 8-elem (16B) chunk (row, kb) in a [64][64]
// bf16 tile; XOR of kb with row&7 spreads the 128B-stride column walk.
__device__ __forceinline__ int aswz(int row, int kb) {
  return row * 64 + (((kb ^ (row & 7)) << 3));
}

// ---- x -> bf16 table (3.2MB, L2-resident)
__global__ __launch_bounds__(256) void xconvert_kernel(
    const float* __restrict__ x, ushort* __restrict__ xb, int n16) {
  int i = blockIdx.x * 256 + threadIdx.x;
  if (i * 4 >= n16) return;
  float4 a = LDF4(x + i * 4);
  ushort4 o = {f2bf(a.x), f2bf(a.y), f2bf(a.z), f2bf(a.w)};
  *reinterpret_cast<ushort4*>(xb + i * 4) = o;
}

// ---- fold uniform-u into init vectors + build swizzled bf16 W^T image
__global__ void precompute_kernel(const float* __restrict__ u,
                                  const float* __restrict__ W_eb,
                                  const float* __restrict__ b_eb,
                                  const float* __restrict__ W_nb,
                                  const float* __restrict__ b_nb,
                                  float* __restrict__ eb_init,
                                  float* __restrict__ nb_init,
                                  ushort* __restrict__ wt_img) {
  int j = threadIdx.x;  // 64 threads
  float ae = b_eb[j], an = b_nb[j];
  for (int k = 0; k < 64; ++k) {
    float uk = u[k];
    ae = fmaf(uk, W_eb[(48 + k) * 64 + j], ae);
    an = fmaf(uk, W_nb[(80 + k) * 64 + j], an);
  }
  eb_init[j] = ae;
  nb_init[j] = an;
  // Wt image: "row" = output n (=j), k runs 0..63 (48 real + 16 zero)
  for (int k = 0; k < 64; ++k) {
    ushort v = (k < 48) ? f2bf(W_eb[k * 64 + j]) : (ushort)0;
    wt_img[aswz(j, k >> 3) + (k & 7)] = v;
  }
}

// ---- bucket histogram for both directions
__global__ __launch_bounds__(256) void bcount_kernel(
    const int* __restrict__ receivers, const int* __restrict__ senders,
    uint* __restrict__ bcnt_r, uint* __restrict__ bcnt_s, int E, int NB) {
  __shared__ uint hr[NBMAX], hs[NBMAX];
  int t = threadIdx.x;
  for (int i = t; i < NB; i += 256) { hr[i] = 0; hs[i] = 0; }
  __syncthreads();
  int stride = gridDim.x * 256;
  for (int e = blockIdx.x * 256 + t; e < E; e += stride) {
    atomicAdd(&hr[receivers[e] >> BSHIFT], 1u);
    atomicAdd(&hs[senders[e] >> BSHIFT], 1u);
  }
  __syncthreads();
  for (int i = t; i < NB; i += 256) {
    if (hr[i]) atomicAdd(&bcnt_r[i], hr[i]);
    if (hs[i]) atomicAdd(&bcnt_s[i], hs[i]);
  }
}

// ---- exclusive scan of both bucket-count arrays (single block, 4/thread)
__global__ __launch_bounds__(256) void bscan_kernel(
    const uint* __restrict__ bcnt_r, const uint* __restrict__ bcnt_s,
    uint* __restrict__ start_r, uint* __restrict__ start_s,
    uint* __restrict__ cur_r, uint* __restrict__ cur_s, int E, int NB) {
  __shared__ uint ts[256];
  int t = threadIdx.x;
  #pragma unroll
  for (int pass = 0; pass < 2; ++pass) {
    const uint* cnt = pass ? bcnt_s : bcnt_r;
    uint* start = pass ? start_s : start_r;
    uint* cur = pass ? cur_s : cur_r;
    uint loc[4]; uint tsum = 0;
    #pragma unroll
    for (int q = 0; q < 4; ++q) {
      int i = t * 4 + q;
      loc[q] = (i < NB) ? cnt[i] : 0;
      tsum += loc[q];
    }
    ts[t] = tsum;
    __syncthreads();
    for (int off = 1; off < 256; off <<= 1) {
      uint a = (t >= off) ? ts[t - off] : 0;
      __syncthreads();
      ts[t] += a;
      __syncthreads();
    }
    uint run = ts[t] - tsum;
    #pragma unroll
    for (int q = 0; q < 4; ++q) {
      int i = t * 4 + q;
      if (i < NB) { start[i] = run; cur[i] = run; run += loc[q]; }
    }
    if (t == 0) start[NB] = (uint)E;
    __syncthreads();
  }
}

// ---- bucket-sort edge ids, both directions in one launch.
__global__ __launch_bounds__(256) void distribute_kernel(
    const int* __restrict__ receivers, const int* __restrict__ senders,
    uint* __restrict__ gcur_r, uint* __restrict__ gcur_s,
    uint* __restrict__ tmp_r, uint* __restrict__ tmp_s, int E, int NB) {
  __shared__ uint hist[NBMAX], lstart[NBMAX], cur[NBMAX], gbase[NBMAX];
  __shared__ uint ids[DC];
  __shared__ ushort idsB[DC];
  __shared__ uint ts[256];
  int dir = blockIdx.x & 1;
  const int* key = dir ? senders : receivers;
  uint* g_cursor = dir ? gcur_s : gcur_r;
  uint* tmp = dir ? tmp_s : tmp_r;
  int t = threadIdx.x;
  int base = (blockIdx.x >> 1) * DC;
  int cact = min(DC, E - base);
  for (int i = t; i < NB; i += 256) hist[i] = 0;
  __syncthreads();
  for (int k = 0; k < DC / 256; ++k) {
    int j = k * 256 + t;
    if (j < cact) atomicAdd(&hist[key[base + j] >> BSHIFT], 1u);
  }
  __syncthreads();
  {
    uint loc[4]; uint tsum = 0;
    #pragma unroll
    for (int q = 0; q < 4; ++q) {
      int i = t * 4 + q;
      loc[q] = (i < NB) ? hist[i] : 0;
      tsum += loc[q];
    }
    ts[t] = tsum;
    __syncthreads();
    for (int off = 1; off < 256; off <<= 1) {
      uint a = (t >= off) ? ts[t - off] : 0;
      __syncthreads();
      ts[t] += a;
      __syncthreads();
    }
    uint run = ts[t] - tsum;
    #pragma unroll
    for (int q = 0; q < 4; ++q) {
      int i = t * 4 + q;
      if (i < NB) { lstart[i] = run; cur[i] = run; run += loc[q]; }
    }
  }
  __syncthreads();
  for (int i = t; i < NB; i += 256)
    if (hist[i]) gbase[i] = atomicAdd(&g_cursor[i], hist[i]);
  for (int k = 0; k < DC / 256; ++k) {
    int j = k * 256 + t;
    if (j < cact) {
      int e = base + j;
      int kk = key[e];
      uint b = (uint)(kk >> BSHIFT);
      uint slot = atomicAdd(&cur[b], 1u);
      ids[slot] = ((uint)(kk & (BW - 1)) << 21) | (uint)e;
      idsB[slot] = (ushort)b;
    }
  }
  __syncthreads();
  for (int j = t; j < cact; j += 256) {
    uint b2 = idsB[j];
    tmp[gbase[b2] + ((uint)j - lstart[b2])] = ids[j];
  }
}

// ---- per-bucket counting sort to full per-node order.
__global__ __launch_bounds__(256) void bucketsort_kernel(
    const uint* __restrict__ tmp_r, const uint* __restrict__ tmp_s,
    const uint* __restrict__ start_r, const uint* __restrict__ start_s,
    uint* __restrict__ eidx_r, uint* __restrict__ eidx_s,
    uint* __restrict__ row_ptr_r, uint* __restrict__ row_ptr_s,
    uint* __restrict__ cnt_r, uint* __restrict__ cnt_s, int N) {
  __shared__ uint hist[BW], pfx[BW], cur[BW];
  int d = blockIdx.x & 1;
  int b = blockIdx.x >> 1;
  const uint* tmp = d ? tmp_s : tmp_r;
  const uint* start = d ? start_s : start_r;
  uint* eidx = d ? eidx_s : eidx_r;
  uint* row_ptr = d ? row_ptr_s : row_ptr_r;
  uint* cnt = d ? cnt_s : cnt_r;
  int t = threadIdx.x;
  if (t < BW) hist[t] = 0;
  __syncthreads();
  int beg = (int)start[b], end = (int)start[b + 1];
  for (int i = beg + t; i < end; i += 256) atomicAdd(&hist[tmp[i] >> 21], 1u);
  __syncthreads();
  if (t < BW) pfx[t] = hist[t];
  __syncthreads();
  for (int off = 1; off < BW; off <<= 1) {
    uint a = 0;
    if (t < BW && t >= off) a = pfx[t - off];
    __syncthreads();
    if (t < BW) pfx[t] += a;
    __syncthreads();
  }
  if (t < BW) cur[t] = pfx[t] - hist[t];
  __syncthreads();
  for (int i = beg + t; i < end; i += 256) {
    uint v = tmp[i];
    uint nl = v >> 21;
    uint p = atomicAdd(&cur[nl], 1u);
    eidx[beg + p] = v & EMASK;
  }
  int nbase = b * BW;
  if (t < BW && nbase + t < N) {
    cnt[nbase + t] = hist[t];
    row_ptr[nbase + t] = (uint)beg + pfx[t] - hist[t];
  }
}

// ---- edge MLP via MFMA: e_h = relu([ea, x_r, x_s]@W + eb_init) -> bf16.
// Block = 4 waves = 64 edges. A[64m][64k] bf16 LDS (swizzled), Wt[64n][64k]
// copied pre-swizzled, 8 mfma_f32_16x16x32_bf16 per wave, C via LDS bounce.
__global__ __launch_bounds__(256, 2) void edge_mfma_kernel(
    const float* __restrict__ edge_attr, const ushort* __restrict__ xb,
    const int* __restrict__ senders, const int* __restrict__ receivers,
    const ushort* __restrict__ wt_img, const float* __restrict__ eb_init,
    ushort* __restrict__ e_h, int E) {
  __shared__ ushort Alds[64 * 64];       // 8 KB
  __shared__ ushort Wlds[64 * 64];       // 8 KB
  __shared__ ushort Clds[4][16 * 72];    // 9 KB (pitch 72)
  int t = threadIdx.x;
  int base = blockIdx.x * 64;

  // -- stage Wt (linear copy of pre-swizzled image): 16 ushorts/thread
  {
    const uint4* src = reinterpret_cast<const uint4*>(wt_img);
    uint4* dst = reinterpret_cast<uint4*>(Wlds);
    dst[t * 2] = src[t * 2];
    dst[t * 2 + 1] = src[t * 2 + 1];
  }
  // -- stage A: 4 threads per edge
  {
    int m = t >> 2, part = t & 3;
    int e = base + m;
    bool val = e < E;
    if (part < 2) {
      union { ushort h[8]; uint4 q; } pk;
      if (val) {
        const float* ap = edge_attr + (size_t)e * 16 + part * 8;
        float4 f0 = LDF4(ap), f1 = LDF4(ap + 4);
        pk.h[0] = f2bf(f0.x); pk.h[1] = f2bf(f0.y);
        pk.h[2] = f2bf(f0.z); pk.h[3] = f2bf(f0.w);
        pk.h[4] = f2bf(f1.x); pk.h[5] = f2bf(f1.y);
        pk.h[6] = f2bf(f1.z); pk.h[7] = f2bf(f1.w);
      } else {
        pk.q = uint4{0, 0, 0, 0};
      }
      *reinterpret_cast<uint4*>(&Alds[aswz(m, part)]) = pk.q;
    } else {
      uint4 w0 = {0, 0, 0, 0}, w1 = {0, 0, 0, 0};
      if (val) {
        int node = (part == 2) ? receivers[e] : senders[e];
        const uint4* xp = reinterpret_cast<const uint4*>(xb + (size_t)node * 16);
        w0 = xp[0]; w1 = xp[1];
      }
      int kb = (part == 2) ? 2 : 4;
      *reinterpret_cast<uint4*>(&Alds[aswz(m, kb)]) = w0;
      *reinterpret_cast<uint4*>(&Alds[aswz(m, kb + 1)]) = w1;
    }
    // zero-pad kb 6,7 (k=48..63)
    if (t < 128) {
      int zr = t >> 1, zkb = 6 + (t & 1);
      *reinterpret_cast<uint4*>(&Alds[aswz(zr, zkb)]) = uint4{0, 0, 0, 0};
    }
  }
  __syncthreads();

  // -- MFMA: wave wid owns rows [wid*16, wid*16+16)
  int wid = t >> 6, l = t & 63;
  int lrow = l & 15, lk = l >> 4;  // k-group 0..3
  int arow = wid * 16 + lrow;
  bf16x8 a0 = *reinterpret_cast<const bf16x8*>(&Alds[aswz(arow, lk)]);
  bf16x8 a1 = *reinterpret_cast<const bf16x8*>(&Alds[aswz(arow, 4 + lk)]);
  f32x4 acc[4];
  #pragma unroll
  for (int nt = 0; nt < 4; ++nt) {
    float ebi = eb_init[nt * 16 + lrow];
    acc[nt] = f32x4{ebi, ebi, ebi, ebi};
    bf16x8 b0 =
        *reinterpret_cast<const bf16x8*>(&Wlds[aswz(nt * 16 + lrow, lk)]);
    bf16x8 b1 =
        *reinterpret_cast<const bf16x8*>(&Wlds[aswz(nt * 16 + lrow, 4 + lk)]);
    acc[nt] = __builtin_amdgcn_mfma_f32_16x16x32_bf16(a0, b0, acc[nt], 0, 0, 0);
    acc[nt] = __builtin_amdgcn_mfma_f32_16x16x32_bf16(a1, b1, acc[nt], 0, 0, 0);
  }
  // -- relu + cvt + LDS transpose bounce
  int m0 = (l >> 4) * 4;
  #pragma unroll
  for (int nt = 0; nt < 4; ++nt) {
    #pragma unroll
    for (int reg = 0; reg < 4; ++reg) {
      Clds[wid][(m0 + reg) * 72 + nt * 16 + lrow] =
          f2bf(fmaxf(acc[nt][reg], 0.f));
    }
  }
  __syncthreads();
  // -- coalesced store: lane l -> row l>>2, 32B chunk l&3
  int sm = l >> 2, ch = l & 3;
  int ge = base + wid * 16 + sm;
  uint4 c0 = *reinterpret_cast<const uint4*>(&Clds[wid][sm * 72 + ch * 16]);
  uint4 c1 = *reinterpret_cast<const uint4*>(&Clds[wid][sm * 72 + ch * 16 + 8]);
  if (ge < E) {
    uint4* dst = reinterpret_cast<uint4*>(e_h + (size_t)ge * 64 + ch * 16);
    dst[0] = c0;
    dst[1] = c1;
  }
}

// ---- gather: wave per node; half-waves take alternating edges; uint loads
__global__ __launch_bounds__(256, 4) void gather_kernel(
    const ushort* __restrict__ e_h, const uint* __restrict__ row_ptr,
    const uint* __restrict__ cnt, const uint* __restrict__ eidx,
    float* __restrict__ out, int N) {
  int n = blockIdx.x * 4 + (threadIdx.x >> 6);
  if (n >= N) return;
  const uint* eh32 = reinterpret_cast<const uint*>(e_h);
  int lane = threadIdx.x & 63;
  int half = lane >> 5;
  int l = lane & 31;
  int beg = (int)row_ptr[n], end = beg + (int)cnt[n];
  float a0 = 0, a1 = 0, b0 = 0, b1 = 0;
  int i = beg + half;
  for (; i + 2 < end; i += 4) {
    uint e0 = eidx[i], e1 = eidx[i + 2];
    uint w0 = eh32[(size_t)e0 * 32 + l];
    uint w1 = eh32[(size_t)e1 * 32 + l];
    a0 += __uint_as_float(w0 << 16);
    a1 += __uint_as_float(w0 & 0xFFFF0000u);
    b0 += __uint_as_float(w1 << 16);
    b1 += __uint_as_float(w1 & 0xFFFF0000u);
  }
  for (; i < end; i += 2) {
    uint w0 = eh32[(size_t)eidx[i] * 32 + l];
    a0 += __uint_as_float(w0 << 16);
    a1 += __uint_as_float(w0 & 0xFFFF0000u);
  }
  a0 += b0; a1 += b1;
  a0 += __shfl_xor(a0, 32);
  a1 += __shfl_xor(a1, 32);
  if (half == 0) {
    float2 t = {a0, a1};
    *reinterpret_cast<float2*>(out + (size_t)n * 64 + 2 * l) = t;
  }
}

// ---- node block: n_h = relu([sum_recv, x]@W_nb[0:80] + nb_init)
__global__ __launch_bounds__(256, 2) void node_kernel(
    const float* __restrict__ x, const float* __restrict__ sum_recv,
    const float* __restrict__ W_nb, const float* __restrict__ nb_init,
    float* __restrict__ n_h, int N) {
  int n = blockIdx.x * 256 + threadIdx.x;
  if (n >= N) return;
  float v[80];
  const float* ar = sum_recv + (size_t)n * 64;
  load16(ar, v); load16(ar + 16, v + 16); load16(ar + 32, v + 32);
  load16(ar + 48, v + 48);
  load16(x + (size_t)n * 16, v + 64);
  float* out = n_h + (size_t)n * 64;
  #pragma unroll
  for (int c = 0; c < 2; ++c) {
    float acc[32];
    #pragma unroll
    for (int j = 0; j < 32; ++j) acc[j] = nb_init[c * 32 + j];
    #pragma unroll
    for (int i = 0; i < 80; ++i) {
      const float* Wrow = W_nb + i * 64 + c * 32;
      #pragma unroll
      for (int j = 0; j < 32; ++j) acc[j] = fmaf(v[i], Wrow[j], acc[j]);
    }
    #pragma unroll
    for (int j = 0; j < 32; j += 4) {
      float4 tq = {fmaxf(acc[j], 0.f), fmaxf(acc[j + 1], 0.f),
                   fmaxf(acc[j + 2], 0.f), fmaxf(acc[j + 3], 0.f)};
      *reinterpret_cast<float4*>(out + c * 32 + j) = tq;
    }
  }
}

// ---- column sums of sum_recv (= sum of all e_h) and n_h
__global__ __launch_bounds__(256) void reduce_kernel(
    const float* __restrict__ sum_recv, const float* __restrict__ n_h,
    float* __restrict__ e_sum, float* __restrict__ n_sum, int N) {
  __shared__ float ls[128];
  if (threadIdx.x < 128) ls[threadIdx.x] = 0.f;
  __syncthreads();
  int g = threadIdx.x & 15;
  int tid = blockIdx.x * blockDim.x + threadIdx.x;
  int row0 = tid >> 4;
  int rstride = (gridDim.x * blockDim.x) >> 4;
  float pe[4] = {0, 0, 0, 0}, pn[4] = {0, 0, 0, 0};
  for (int r = row0; r < N; r += rstride) {
    float4 a = LDF4(sum_recv + (size_t)r * 64 + g * 4);
    float4 b = LDF4(n_h + (size_t)r * 64 + g * 4);
    pe[0] += a.x; pe[1] += a.y; pe[2] += a.z; pe[3] += a.w;
    pn[0] += b.x; pn[1] += b.y; pn[2] += b.z; pn[3] += b.w;
  }
  #pragma unroll
  for (int i = 0; i < 4; ++i) {
    atomicAdd(&ls[g * 4 + i], pe[i]);
    atomicAdd(&ls[64 + g * 4 + i], pn[i]);
  }
  __syncthreads();
  if (threadIdx.x < 64) {
    atomicAdd(&e_sum[threadIdx.x], ls[threadIdx.x]);
    atomicAdd(&n_sum[threadIdx.x], ls[64 + threadIdx.x]);
  }
}

// ---- global block + fold u2 into d1_init
__global__ void global_kernel(const float* __restrict__ u,
                              const float* __restrict__ e_sum,
                              const float* __restrict__ n_sum,
                              const float* __restrict__ W_gb,
                              const float* __restrict__ b_gb,
                              const float* __restrict__ W_d1,
                              const float* __restrict__ b_d1,
                              float* __restrict__ d1_init, float Ef, float Nf) {
  __shared__ float gin[192];
  __shared__ float u2s[64];
  int j = threadIdx.x;  // 64 threads
  gin[j] = e_sum[j] / Ef;
  gin[64 + j] = n_sum[j] / Nf;
  gin[128 + j] = u[j];
  __syncthreads();
  float a = b_gb[j];
  for (int k = 0; k < 192; ++k) a = fmaf(gin[k], W_gb[k * 64 + j], a);
  u2s[j] = fmaxf(a, 0.f);
  __syncthreads();
  float d = b_d1[j];
  for (int k = 0; k < 64; ++k) d = fmaf(u2s[k], W_d1[(192 + k) * 64 + j], d);
  d1_init[j] = d;
}

// ---- decoder
__global__ __launch_bounds__(256, 2) void decoder_kernel(
    const float* __restrict__ sum_recv, const float* __restrict__ sum_sent,
    const uint* __restrict__ cnt_r, const uint* __restrict__ cnt_s,
    const float* __restrict__ n_h, const float* __restrict__ W_d1,
    const float* __restrict__ d1_init, const float* __restrict__ W_d2,
    const float* __restrict__ b_d2, float* __restrict__ out, int N) {
  int n = blockIdx.x * 256 + threadIdx.x;
  if (n >= N) return;
  float acc[64];
  #pragma unroll
  for (int j = 0; j < 64; ++j) acc[j] = d1_init[j];
  float v[16];
  float invr = 1.0f / fmaxf((float)cnt_r[n], 1.0f);
  const float* pr = sum_recv + (size_t)n * 64;
  #pragma unroll
  for (int c = 0; c < 4; ++c) {
    load16(pr + c * 16, v);
    #pragma unroll
    for (int i = 0; i < 16; ++i) v[i] *= invr;
    #pragma unroll
    for (int i = 0; i < 16; ++i) {
      const float* Wrow = W_d1 + (c * 16 + i) * 64;
      #pragma unroll
      for (int j = 0; j < 64; ++j) acc[j] = fmaf(v[i], Wrow[j], acc[j]);
    }
  }
  float invs = 1.0f / fmaxf((float)cnt_s[n], 1.0f);
  const float* ps = sum_sent + (size_t)n * 64;
  #pragma unroll
  for (int c = 0; c < 4; ++c) {
    load16(ps + c * 16, v);
    #pragma unroll
    for (int i = 0; i < 16; ++i) v[i] *= invs;
    #pragma unroll
    for (int i = 0; i < 16; ++i) {
      const float* Wrow = W_d1 + (64 + c * 16 + i) * 64;
      #pragma unroll
      for (int j = 0; j < 64; ++j) acc[j] = fmaf(v[i], Wrow[j], acc[j]);
    }
  }
  const float* pn = n_h + (size_t)n * 64;
  #pragma unroll
  for (int c = 0; c < 4; ++c) {
    load16(pn + c * 16, v);
    #pragma unroll
    for (int i = 0; i < 16; ++i) {
      const float* Wrow = W_d1 + (128 + c * 16 + i) * 64;
      #pragma unroll
      for (int j = 0; j < 64; ++j) acc[j] = fmaf(v[i], Wrow[j], acc[j]);
    }
  }
  #pragma unroll
  for (int j = 0; j < 64; ++j) acc[j] = fmaxf(acc[j], 0.f);
  float* po = out + (size_t)n * 16;
  #pragma unroll
  for (int o = 0; o < 16; o += 4) {
    float4 tq;
    float* tp = &tq.x;
    #pragma unroll
    for (int q = 0; q < 4; ++q) {
      float a = b_d2[o + q];
      #pragma unroll
      for (int j = 0; j < 64; ++j) a = fmaf(acc[j], W_d2[j * 16 + o + q], a);
      tp[q] = a;
    }
    *reinterpret_cast<float4*>(po + o) = tq;
  }
}

extern "C" void kernel_launch(void* const* d_in, const int* in_sizes, int n_in,
                              void* d_out, int out_size, void* d_ws,
                              size_t ws_size, hipStream_t stream) {
  const float* x         = (const float*)d_in[0];
  const float* edge_attr = (const float*)d_in[1];
  const float* u         = (const float*)d_in[2];
  const int*   senders   = (const int*)d_in[3];
  const int*   receivers = (const int*)d_in[4];
  const float* W_eb = (const float*)d_in[7];
  const float* b_eb = (const float*)d_in[8];
  const float* W_nb = (const float*)d_in[9];
  const float* b_nb = (const float*)d_in[10];
  const float* W_gb = (const float*)d_in[11];
  const float* b_gb = (const float*)d_in[12];
  const float* W_d1 = (const float*)d_in[13];
  const float* b_d1 = (const float*)d_in[14];
  const float* W_d2 = (const float*)d_in[15];
  const float* b_d2 = (const float*)d_in[16];

  int N = in_sizes[0] / 16;
  int E = in_sizes[1] / 16;
  int NB = (N + BW - 1) >> BSHIFT;  // 782 for N=100000
  int NDB = (E + DC - 1) / DC;      // distribute chunks per direction

  char* w = (char*)d_ws;
  ushort* e_h = (ushort*)w;          w += (size_t)E * 64 * 2;
  float* sum_recv = (float*)w;       w += (size_t)N * 64 * 4;
  float* sum_sent = (float*)w;       w += (size_t)N * 64 * 4;
  float* n_h = (float*)w;            w += (size_t)N * 64 * 4;
  uint* tmp_r = (uint*)w;            w += (size_t)E * 4;
  uint* tmp_s = (uint*)w;            w += (size_t)E * 4;
  uint* eidx_r = (uint*)w;           w += (size_t)E * 4;
  uint* eidx_s = (uint*)w;           w += (size_t)E * 4;
  uint* row_ptr_r = (uint*)w;        w += (size_t)N * 4;
  uint* row_ptr_s = (uint*)w;        w += (size_t)N * 4;
  uint* cnt_r = (uint*)w;            w += (size_t)N * 4;
  uint* cnt_s = (uint*)w;            w += (size_t)N * 4;
  ushort* xb = (ushort*)w;           w += (size_t)N * 16 * 2;
  ushort* wt_img = (ushort*)w;       w += (size_t)64 * 64 * 2;
  uint* start_r = (uint*)w;          w += (size_t)(NB + 1) * 4;
  uint* start_s = (uint*)w;          w += (size_t)(NB + 1) * 4;
  uint* cur_r = (uint*)w;            w += (size_t)NB * 4;
  uint* cur_s = (uint*)w;            w += (size_t)NB * 4;
  // zeroed region
  uint* bcnt_r = (uint*)w;           w += (size_t)NBMAX * 4;
  uint* bcnt_s = (uint*)w;           w += (size_t)NBMAX * 4;
  float* e_sum = (float*)w;          w += 64 * 4;
  float* n_sum = (float*)w;          w += 64 * 4;
  // small non-zeroed
  float* eb_init = (float*)w;        w += 64 * 4;
  float* nb_init = (float*)w;        w += 64 * 4;
  float* d1_init = (float*)w;        w += 64 * 4;

  size_t zero_bytes = (size_t)(2 * NBMAX + 128) * 4;
  hipMemsetAsync(bcnt_r, 0, zero_bytes, stream);

  hipLaunchKernelGGL(xconvert_kernel, dim3((N * 16 / 4 + 255) / 256), dim3(256),
                     0, stream, x, xb, N * 16);
  hipLaunchKernelGGL(precompute_kernel, dim3(1), dim3(64), 0, stream, u, W_eb,
                     b_eb, W_nb, b_nb, eb_init, nb_init, wt_img);
  hipLaunchKernelGGL(bcount_kernel, dim3(64), dim3(256), 0, stream, receivers,
                     senders, bcnt_r, bcnt_s, E, NB);
  hipLaunchKernelGGL(bscan_kernel, dim3(1), dim3(256), 0, stream, bcnt_r,
                     bcnt_s, start_r, start_s, cur_r, cur_s, E, NB);
  hipLaunchKernelGGL(distribute_kernel, dim3(2 * NDB), dim3(256), 0, stream,
                     receivers, senders, cur_r, cur_s, tmp_r, tmp_s, E, NB);
  hipLaunchKernelGGL(bucketsort_kernel, dim3(2 * NB), dim3(256), 0, stream,
                     tmp_r, tmp_s, start_r, start_s, eidx_r, eidx_s, row_ptr_r,
                     row_ptr_s, cnt_r, cnt_s, N);
  // edge MFMA kernel right before gathers: e_h stays L3-resident
  hipLaunchKernelGGL(edge_mfma_kernel, dim3((E + 63) / 64), dim3(256), 0,
                     stream, edge_attr, xb, senders, receivers, wt_img,
                     eb_init, e_h, E);
  hipLaunchKernelGGL(gather_kernel, dim3((N + 3) / 4), dim3(256), 0, stream,
                     e_h, row_ptr_r, cnt_r, eidx_r, sum_recv, N);
  hipLaunchKernelGGL(gather_kernel, dim3((N + 3) / 4), dim3(256), 0, stream,
                     e_h, row_ptr_s, cnt_s, eidx_s, sum_sent, N);
  hipLaunchKernelGGL(node_kernel, dim3((N + 255) / 256), dim3(256), 0, stream,
                     x, sum_recv, W_nb, nb_init, n_h, N);
  hipLaunchKernelGGL(reduce_kernel, dim3(256), dim3(256), 0, stream, sum_recv,
                     n_h, e_sum, n_sum, N);
  hipLaunchKernelGGL(global_kernel, dim3(1), dim3(64), 0, stream, u, e_sum,
                     n_sum, W_gb, b_gb, W_d1, b_d1, d1_init, (float)E,
                     (float)N);
  hipLaunchKernelGGL(decoder_kernel, dim3((N + 255) / 256), dim3(256), 0,
                     stream, sum_recv, sum_sent, cnt_r, cnt_s, n_h, W_d1,
                     d1_init, W_d2, b_d2, (float*)d_out, N);
}

// Round 11
// 576.223 us; speedup vs baseline: 3.7468x; 1.1663x over previous
//
#include <hip/hip_runtime.h>

// GraphNet forward. Round 11: r10 decoder-MFMA with the W2 staging bug
// fixed (w2_img is 128 uint4 = 16 rows x 64 k; r10 copied only 64 -> rows
// 8-15 of W2lds were garbage -> absmax 9.7e19). Everything else unchanged.

typedef unsigned int uint;
typedef unsigned short ushort;
typedef __attribute__((ext_vector_type(8))) short bf16x8;
typedef __attribute__((ext_vector_type(4))) float f32x4;

#define BW 128          // nodes per bucket (sort)
#define BSHIFT 7
#define NBMAX 784       // max buckets (N=100000 -> 782)
#define DC 8192         // edges per distribute block
#define EMASK 0x1FFFFFu // 21 bits of edge id

#define LDF4(p) (*reinterpret_cast<const float4*>(p))

__device__ __forceinline__ void load16(const float* __restrict__ p, float* v) {
  float4 a = LDF4(p), b = LDF4(p + 4), c = LDF4(p + 8), d = LDF4(p + 12);
  v[0]=a.x; v[1]=a.y; v[2]=a.z; v[3]=a.w;
  v[4]=b.x; v[5]=b.y; v[6]=b.z; v[7]=b.w;
  v[8]=c.x; v[9]=c.y; v[10]=c.z; v[11]=c.w;
  v[12]=d.x; v[13]=d.y; v[14]=d.z; v[15]=d.w;
}

__device__ __forceinline__ ushort f2bf(float f) {
  uint u = __float_as_uint(f);
  u += 0x7FFFu + ((u >> 16) & 1u);
  return (ushort)(u >> 16);
}

// swizzled ushort index of 16B chunk (row, kb) in a [row][64] bf16 tile
__device__ __forceinline__ int aswz(int row, int kb) {
  return row * 64 + ((kb ^ (row & 7)) << 3);
}
// same for a [row][192] tile (kb 0..23; XOR stays within aligned-8 groups)
__device__ __forceinline__ int aswz192(int row, int kb) {
  return row * 192 + (((kb & 24) | ((kb ^ row) & 7)) << 3);
}

// ---- x -> bf16 table (3.2MB, L2-resident)
__global__ __launch_bounds__(256) void xconvert_kernel(
    const float* __restrict__ x, ushort* __restrict__ xb, int n16) {
  int i = blockIdx.x * 256 + threadIdx.x;
  if (i * 4 >= n16) return;
  float4 a = LDF4(x + i * 4);
  ushort4 o = {f2bf(a.x), f2bf(a.y), f2bf(a.z), f2bf(a.w)};
  *reinterpret_cast<ushort4*>(xb + i * 4) = o;
}

// ---- fold uniform-u into init vectors + build swizzled bf16 W images
__global__ void precompute_kernel(const float* __restrict__ u,
                                  const float* __restrict__ W_eb,
                                  const float* __restrict__ b_eb,
                                  const float* __restrict__ W_nb,
                                  const float* __restrict__ b_nb,
                                  const float* __restrict__ W_d1,
                                  const float* __restrict__ W_d2,
                                  float* __restrict__ eb_init,
                                  float* __restrict__ nb_init,
                                  ushort* __restrict__ wt_img,
                                  ushort* __restrict__ wtd1_img,
                                  ushort* __restrict__ w2_img) {
  int j = threadIdx.x;  // 64 threads
  float ae = b_eb[j], an = b_nb[j];
  for (int k = 0; k < 64; ++k) {
    float uk = u[k];
    ae = fmaf(uk, W_eb[(48 + k) * 64 + j], ae);
    an = fmaf(uk, W_nb[(80 + k) * 64 + j], an);
  }
  eb_init[j] = ae;
  nb_init[j] = an;
  // edge Wt image: row = output n (=j), k 0..63 (48 real + 16 zero)
  for (int k = 0; k < 64; ++k) {
    ushort v = (k < 48) ? f2bf(W_eb[k * 64 + j]) : (ushort)0;
    wt_img[aswz(j, k >> 3) + (k & 7)] = v;
  }
  // decoder layer-1 Wt image: row = output n (=j), k 0..191
  for (int k = 0; k < 192; ++k)
    wtd1_img[aswz192(j, k >> 3) + (k & 7)] = f2bf(W_d1[k * 64 + j]);
  // decoder layer-2 Wt image: row = output o (<16), k 0..63
  if (j < 16)
    for (int k = 0; k < 64; ++k)
      w2_img[aswz(j, k >> 3) + (k & 7)] = f2bf(W_d2[k * 16 + j]);
}

// ---- bucket histogram for both directions
__global__ __launch_bounds__(256) void bcount_kernel(
    const int* __restrict__ receivers, const int* __restrict__ senders,
    uint* __restrict__ bcnt_r, uint* __restrict__ bcnt_s, int E, int NB) {
  __shared__ uint hr[NBMAX], hs[NBMAX];
  int t = threadIdx.x;
  for (int i = t; i < NB; i += 256) { hr[i] = 0; hs[i] = 0; }
  __syncthreads();
  int stride = gridDim.x * 256;
  for (int e = blockIdx.x * 256 + t; e < E; e += stride) {
    atomicAdd(&hr[receivers[e] >> BSHIFT], 1u);
    atomicAdd(&hs[senders[e] >> BSHIFT], 1u);
  }
  __syncthreads();
  for (int i = t; i < NB; i += 256) {
    if (hr[i]) atomicAdd(&bcnt_r[i], hr[i]);
    if (hs[i]) atomicAdd(&bcnt_s[i], hs[i]);
  }
}

// ---- exclusive scan of both bucket-count arrays (single block, 4/thread)
__global__ __launch_bounds__(256) void bscan_kernel(
    const uint* __restrict__ bcnt_r, const uint* __restrict__ bcnt_s,
    uint* __restrict__ start_r, uint* __restrict__ start_s,
    uint* __restrict__ cur_r, uint* __restrict__ cur_s, int E, int NB) {
  __shared__ uint ts[256];
  int t = threadIdx.x;
  #pragma unroll
  for (int pass = 0; pass < 2; ++pass) {
    const uint* cnt = pass ? bcnt_s : bcnt_r;
    uint* start = pass ? start_s : start_r;
    uint* cur = pass ? cur_s : cur_r;
    uint loc[4]; uint tsum = 0;
    #pragma unroll
    for (int q = 0; q < 4; ++q) {
      int i = t * 4 + q;
      loc[q] = (i < NB) ? cnt[i] : 0;
      tsum += loc[q];
    }
    ts[t] = tsum;
    __syncthreads();
    for (int off = 1; off < 256; off <<= 1) {
      uint a = (t >= off) ? ts[t - off] : 0;
      __syncthreads();
      ts[t] += a;
      __syncthreads();
    }
    uint run = ts[t] - tsum;
    #pragma unroll
    for (int q = 0; q < 4; ++q) {
      int i = t * 4 + q;
      if (i < NB) { start[i] = run; cur[i] = run; run += loc[q]; }
    }
    if (t == 0) start[NB] = (uint)E;
    __syncthreads();
  }
}

// ---- bucket-sort edge ids, both directions in one launch.
__global__ __launch_bounds__(256) void distribute_kernel(
    const int* __restrict__ receivers, const int* __restrict__ senders,
    uint* __restrict__ gcur_r, uint* __restrict__ gcur_s,
    uint* __restrict__ tmp_r, uint* __restrict__ tmp_s, int E, int NB) {
  __shared__ uint hist[NBMAX], lstart[NBMAX], cur[NBMAX], gbase[NBMAX];
  __shared__ uint ids[DC];
  __shared__ ushort idsB[DC];
  __shared__ uint ts[256];
  int dir = blockIdx.x & 1;
  const int* key = dir ? senders : receivers;
  uint* g_cursor = dir ? gcur_s : gcur_r;
  uint* tmp = dir ? tmp_s : tmp_r;
  int t = threadIdx.x;
  int base = (blockIdx.x >> 1) * DC;
  int cact = min(DC, E - base);
  for (int i = t; i < NB; i += 256) hist[i] = 0;
  __syncthreads();
  for (int k = 0; k < DC / 256; ++k) {
    int j = k * 256 + t;
    if (j < cact) atomicAdd(&hist[key[base + j] >> BSHIFT], 1u);
  }
  __syncthreads();
  {
    uint loc[4]; uint tsum = 0;
    #pragma unroll
    for (int q = 0; q < 4; ++q) {
      int i = t * 4 + q;
      loc[q] = (i < NB) ? hist[i] : 0;
      tsum += loc[q];
    }
    ts[t] = tsum;
    __syncthreads();
    for (int off = 1; off < 256; off <<= 1) {
      uint a = (t >= off) ? ts[t - off] : 0;
      __syncthreads();
      ts[t] += a;
      __syncthreads();
    }
    uint run = ts[t] - tsum;
    #pragma unroll
    for (int q = 0; q < 4; ++q) {
      int i = t * 4 + q;
      if (i < NB) { lstart[i] = run; cur[i] = run; run += loc[q]; }
    }
  }
  __syncthreads();
  for (int i = t; i < NB; i += 256)
    if (hist[i]) gbase[i] = atomicAdd(&g_cursor[i], hist[i]);
  for (int k = 0; k < DC / 256; ++k) {
    int j = k * 256 + t;
    if (j < cact) {
      int e = base + j;
      int kk = key[e];
      uint b = (uint)(kk >> BSHIFT);
      uint slot = atomicAdd(&cur[b], 1u);
      ids[slot] = ((uint)(kk & (BW - 1)) << 21) | (uint)e;
      idsB[slot] = (ushort)b;
    }
  }
  __syncthreads();
  for (int j = t; j < cact; j += 256) {
    uint b2 = idsB[j];
    tmp[gbase[b2] + ((uint)j - lstart[b2])] = ids[j];
  }
}

// ---- per-bucket counting sort to full per-node order.
__global__ __launch_bounds__(256) void bucketsort_kernel(
    const uint* __restrict__ tmp_r, const uint* __restrict__ tmp_s,
    const uint* __restrict__ start_r, const uint* __restrict__ start_s,
    uint* __restrict__ eidx_r, uint* __restrict__ eidx_s,
    uint* __restrict__ row_ptr_r, uint* __restrict__ row_ptr_s,
    uint* __restrict__ cnt_r, uint* __restrict__ cnt_s, int N) {
  __shared__ uint hist[BW], pfx[BW], cur[BW];
  int d = blockIdx.x & 1;
  int b = blockIdx.x >> 1;
  const uint* tmp = d ? tmp_s : tmp_r;
  const uint* start = d ? start_s : start_r;
  uint* eidx = d ? eidx_s : eidx_r;
  uint* row_ptr = d ? row_ptr_s : row_ptr_r;
  uint* cnt = d ? cnt_s : cnt_r;
  int t = threadIdx.x;
  if (t < BW) hist[t] = 0;
  __syncthreads();
  int beg = (int)start[b], end = (int)start[b + 1];
  for (int i = beg + t; i < end; i += 256) atomicAdd(&hist[tmp[i] >> 21], 1u);
  __syncthreads();
  if (t < BW) pfx[t] = hist[t];
  __syncthreads();
  for (int off = 1; off < BW; off <<= 1) {
    uint a = 0;
    if (t < BW && t >= off) a = pfx[t - off];
    __syncthreads();
    if (t < BW) pfx[t] += a;
    __syncthreads();
  }
  if (t < BW) cur[t] = pfx[t] - hist[t];
  __syncthreads();
  for (int i = beg + t; i < end; i += 256) {
    uint v = tmp[i];
    uint nl = v >> 21;
    uint p = atomicAdd(&cur[nl], 1u);
    eidx[beg + p] = v & EMASK;
  }
  int nbase = b * BW;
  if (t < BW && nbase + t < N) {
    cnt[nbase + t] = hist[t];
    row_ptr[nbase + t] = (uint)beg + pfx[t] - hist[t];
  }
}

// ---- edge MLP via MFMA (r9, refcheck-proven)
__global__ __launch_bounds__(256, 2) void edge_mfma_kernel(
    const float* __restrict__ edge_attr, const ushort* __restrict__ xb,
    const int* __restrict__ senders, const int* __restrict__ receivers,
    const ushort* __restrict__ wt_img, const float* __restrict__ eb_init,
    ushort* __restrict__ e_h, int E) {
  __shared__ ushort Alds[64 * 64];       // 8 KB
  __shared__ ushort Wlds[64 * 64];       // 8 KB
  __shared__ ushort Clds[4][16 * 72];    // 9 KB (pitch 72)
  int t = threadIdx.x;
  int base = blockIdx.x * 64;
  {
    const uint4* src = reinterpret_cast<const uint4*>(wt_img);
    uint4* dst = reinterpret_cast<uint4*>(Wlds);
    dst[t * 2] = src[t * 2];
    dst[t * 2 + 1] = src[t * 2 + 1];
  }
  {
    int m = t >> 2, part = t & 3;
    int e = base + m;
    bool val = e < E;
    if (part < 2) {
      union { ushort h[8]; uint4 q; } pk;
      if (val) {
        const float* ap = edge_attr + (size_t)e * 16 + part * 8;
        float4 f0 = LDF4(ap), f1 = LDF4(ap + 4);
        pk.h[0] = f2bf(f0.x); pk.h[1] = f2bf(f0.y);
        pk.h[2] = f2bf(f0.z); pk.h[3] = f2bf(f0.w);
        pk.h[4] = f2bf(f1.x); pk.h[5] = f2bf(f1.y);
        pk.h[6] = f2bf(f1.z); pk.h[7] = f2bf(f1.w);
      } else {
        pk.q = uint4{0, 0, 0, 0};
      }
      *reinterpret_cast<uint4*>(&Alds[aswz(m, part)]) = pk.q;
    } else {
      uint4 w0 = {0, 0, 0, 0}, w1 = {0, 0, 0, 0};
      if (val) {
        int node = (part == 2) ? receivers[e] : senders[e];
        const uint4* xp = reinterpret_cast<const uint4*>(xb + (size_t)node * 16);
        w0 = xp[0]; w1 = xp[1];
      }
      int kb = (part == 2) ? 2 : 4;
      *reinterpret_cast<uint4*>(&Alds[aswz(m, kb)]) = w0;
      *reinterpret_cast<uint4*>(&Alds[aswz(m, kb + 1)]) = w1;
    }
    if (t < 128) {
      int zr = t >> 1, zkb = 6 + (t & 1);
      *reinterpret_cast<uint4*>(&Alds[aswz(zr, zkb)]) = uint4{0, 0, 0, 0};
    }
  }
  __syncthreads();
  int wid = t >> 6, l = t & 63;
  int lrow = l & 15, lk = l >> 4;
  int arow = wid * 16 + lrow;
  bf16x8 a0 = *reinterpret_cast<const bf16x8*>(&Alds[aswz(arow, lk)]);
  bf16x8 a1 = *reinterpret_cast<const bf16x8*>(&Alds[aswz(arow, 4 + lk)]);
  f32x4 acc[4];
  #pragma unroll
  for (int nt = 0; nt < 4; ++nt) {
    float ebi = eb_init[nt * 16 + lrow];
    acc[nt] = f32x4{ebi, ebi, ebi, ebi};
    bf16x8 b0 =
        *reinterpret_cast<const bf16x8*>(&Wlds[aswz(nt * 16 + lrow, lk)]);
    bf16x8 b1 =
        *reinterpret_cast<const bf16x8*>(&Wlds[aswz(nt * 16 + lrow, 4 + lk)]);
    acc[nt] = __builtin_amdgcn_mfma_f32_16x16x32_bf16(a0, b0, acc[nt], 0, 0, 0);
    acc[nt] = __builtin_amdgcn_mfma_f32_16x16x32_bf16(a1, b1, acc[nt], 0, 0, 0);
  }
  int m0 = (l >> 4) * 4;
  #pragma unroll
  for (int nt = 0; nt < 4; ++nt) {
    #pragma unroll
    for (int reg = 0; reg < 4; ++reg) {
      Clds[wid][(m0 + reg) * 72 + nt * 16 + lrow] =
          f2bf(fmaxf(acc[nt][reg], 0.f));
    }
  }
  __syncthreads();
  int sm = l >> 2, ch = l & 3;
  int ge = base + wid * 16 + sm;
  uint4 c0 = *reinterpret_cast<const uint4*>(&Clds[wid][sm * 72 + ch * 16]);
  uint4 c1 = *reinterpret_cast<const uint4*>(&Clds[wid][sm * 72 + ch * 16 + 8]);
  if (ge < E) {
    uint4* dst = reinterpret_cast<uint4*>(e_h + (size_t)ge * 64 + ch * 16);
    dst[0] = c0;
    dst[1] = c1;
  }
}

// ---- gather: wave per node; half-waves take alternating edges; uint loads
__global__ __launch_bounds__(256, 4) void gather_kernel(
    const ushort* __restrict__ e_h, const uint* __restrict__ row_ptr,
    const uint* __restrict__ cnt, const uint* __restrict__ eidx,
    float* __restrict__ out, int N) {
  int n = blockIdx.x * 4 + (threadIdx.x >> 6);
  if (n >= N) return;
  const uint* eh32 = reinterpret_cast<const uint*>(e_h);
  int lane = threadIdx.x & 63;
  int half = lane >> 5;
  int l = lane & 31;
  int beg = (int)row_ptr[n], end = beg + (int)cnt[n];
  float a0 = 0, a1 = 0, b0 = 0, b1 = 0;
  int i = beg + half;
  for (; i + 2 < end; i += 4) {
    uint e0 = eidx[i], e1 = eidx[i + 2];
    uint w0 = eh32[(size_t)e0 * 32 + l];
    uint w1 = eh32[(size_t)e1 * 32 + l];
    a0 += __uint_as_float(w0 << 16);
    a1 += __uint_as_float(w0 & 0xFFFF0000u);
    b0 += __uint_as_float(w1 << 16);
    b1 += __uint_as_float(w1 & 0xFFFF0000u);
  }
  for (; i < end; i += 2) {
    uint w0 = eh32[(size_t)eidx[i] * 32 + l];
    a0 += __uint_as_float(w0 << 16);
    a1 += __uint_as_float(w0 & 0xFFFF0000u);
  }
  a0 += b0; a1 += b1;
  a0 += __shfl_xor(a0, 32);
  a1 += __shfl_xor(a1, 32);
  if (half == 0) {
    float2 t = {a0, a1};
    *reinterpret_cast<float2*>(out + (size_t)n * 64 + 2 * l) = t;
  }
}

// ---- node block: n_h = relu([sum_recv, x]@W_nb[0:80] + nb_init)
__global__ __launch_bounds__(256, 2) void node_kernel(
    const float* __restrict__ x, const float* __restrict__ sum_recv,
    const float* __restrict__ W_nb, const float* __restrict__ nb_init,
    float* __restrict__ n_h, int N) {
  int n = blockIdx.x * 256 + threadIdx.x;
  if (n >= N) return;
  float v[80];
  const float* ar = sum_recv + (size_t)n * 64;
  load16(ar, v); load16(ar + 16, v + 16); load16(ar + 32, v + 32);
  load16(ar + 48, v + 48);
  load16(x + (size_t)n * 16, v + 64);
  float* out = n_h + (size_t)n * 64;
  #pragma unroll
  for (int c = 0; c < 2; ++c) {
    float acc[32];
    #pragma unroll
    for (int j = 0; j < 32; ++j) acc[j] = nb_init[c * 32 + j];
    #pragma unroll
    for (int i = 0; i < 80; ++i) {
      const float* Wrow = W_nb + i * 64 + c * 32;
      #pragma unroll
      for (int j = 0; j < 32; ++j) acc[j] = fmaf(v[i], Wrow[j], acc[j]);
    }
    #pragma unroll
    for (int j = 0; j < 32; j += 4) {
      float4 tq = {fmaxf(acc[j], 0.f), fmaxf(acc[j + 1], 0.f),
                   fmaxf(acc[j + 2], 0.f), fmaxf(acc[j + 3], 0.f)};
      *reinterpret_cast<float4*>(out + c * 32 + j) = tq;
    }
  }
}

// ---- column sums of sum_recv (= sum of all e_h) and n_h
__global__ __launch_bounds__(256) void reduce_kernel(
    const float* __restrict__ sum_recv, const float* __restrict__ n_h,
    float* __restrict__ e_sum, float* __restrict__ n_sum, int N) {
  __shared__ float ls[128];
  if (threadIdx.x < 128) ls[threadIdx.x] = 0.f;
  __syncthreads();
  int g = threadIdx.x & 15;
  int tid = blockIdx.x * blockDim.x + threadIdx.x;
  int row0 = tid >> 4;
  int rstride = (gridDim.x * blockDim.x) >> 4;
  float pe[4] = {0, 0, 0, 0}, pn[4] = {0, 0, 0, 0};
  for (int r = row0; r < N; r += rstride) {
    float4 a = LDF4(sum_recv + (size_t)r * 64 + g * 4);
    float4 b = LDF4(n_h + (size_t)r * 64 + g * 4);
    pe[0] += a.x; pe[1] += a.y; pe[2] += a.z; pe[3] += a.w;
    pn[0] += b.x; pn[1] += b.y; pn[2] += b.z; pn[3] += b.w;
  }
  #pragma unroll
  for (int i = 0; i < 4; ++i) {
    atomicAdd(&ls[g * 4 + i], pe[i]);
    atomicAdd(&ls[64 + g * 4 + i], pn[i]);
  }
  __syncthreads();
  if (threadIdx.x < 64) {
    atomicAdd(&e_sum[threadIdx.x], ls[threadIdx.x]);
    atomicAdd(&n_sum[threadIdx.x], ls[64 + threadIdx.x]);
  }
}

// ---- global block + fold u2 into d1_init
__global__ void global_kernel(const float* __restrict__ u,
                              const float* __restrict__ e_sum,
                              const float* __restrict__ n_sum,
                              const float* __restrict__ W_gb,
                              const float* __restrict__ b_gb,
                              const float* __restrict__ W_d1,
                              const float* __restrict__ b_d1,
                              float* __restrict__ d1_init, float Ef, float Nf) {
  __shared__ float gin[192];
  __shared__ float u2s[64];
  int j = threadIdx.x;  // 64 threads
  gin[j] = e_sum[j] / Ef;
  gin[64 + j] = n_sum[j] / Nf;
  gin[128 + j] = u[j];
  __syncthreads();
  float a = b_gb[j];
  for (int k = 0; k < 192; ++k) a = fmaf(gin[k], W_gb[k * 64 + j], a);
  u2s[j] = fmaxf(a, 0.f);
  __syncthreads();
  float d = b_d1[j];
  for (int k = 0; k < 64; ++k) d = fmaf(u2s[k], W_d1[(192 + k) * 64 + j], d);
  d1_init[j] = d;
}

// ---- decoder via MFMA: out = relu(A@W_d1 + d1_init) @ W_d2 + b_d2
__global__ __launch_bounds__(256, 2) void decoder_mfma_kernel(
    const float* __restrict__ sum_recv, const float* __restrict__ sum_sent,
    const uint* __restrict__ cnt_r, const uint* __restrict__ cnt_s,
    const float* __restrict__ n_h, const ushort* __restrict__ wtd1_img,
    const float* __restrict__ d1_init, const ushort* __restrict__ w2_img,
    const float* __restrict__ b_d2, float* __restrict__ out, int N) {
  __shared__ ushort Alds[64 * 192];   // 24 KB
  __shared__ ushort Wlds[64 * 192];   // 24 KB
  __shared__ ushort Hlds[64 * 64];    // 8 KB
  __shared__ ushort W2lds[16 * 64];   // 2 KB
  int t = threadIdx.x;
  int base = blockIdx.x * 64;
  // stage W_d1^T (pre-swizzled image, linear copy: 1536 uint4)
  {
    const uint4* src = reinterpret_cast<const uint4*>(wtd1_img);
    uint4* dst = reinterpret_cast<uint4*>(Wlds);
    #pragma unroll
    for (int i = 0; i < 6; ++i) dst[t + 256 * i] = src[t + 256 * i];
    if (t < 128)  // FIX: w2_img is 128 uint4 (16 rows x 64 k x 2B)
      reinterpret_cast<uint4*>(W2lds)[t] =
          reinterpret_cast<const uint4*>(w2_img)[t];
  }
  // stage A: 4 threads per node, 6 chunks-of-8 each (24 chunks = 192 k)
  {
    int m = t >> 2;
    int n = base + m;
    bool val = n < N;
    float invr = 0.f, invs = 0.f;
    if (val) {
      invr = 1.f / fmaxf((float)cnt_r[n], 1.f);
      invs = 1.f / fmaxf((float)cnt_s[n], 1.f);
    }
    int c0 = (t & 3) * 6;
    for (int c = c0; c < c0 + 6; ++c) {
      union { ushort h[8]; uint4 q; } pk;
      if (val) {
        const float* src;
        float scl;
        if (c < 8)      { src = sum_recv + (size_t)n * 64 + c * 8;        scl = invr; }
        else if (c < 16){ src = sum_sent + (size_t)n * 64 + (c - 8) * 8;  scl = invs; }
        else            { src = n_h      + (size_t)n * 64 + (c - 16) * 8; scl = 1.f; }
        float4 f0 = LDF4(src), f1 = LDF4(src + 4);
        pk.h[0] = f2bf(f0.x * scl); pk.h[1] = f2bf(f0.y * scl);
        pk.h[2] = f2bf(f0.z * scl); pk.h[3] = f2bf(f0.w * scl);
        pk.h[4] = f2bf(f1.x * scl); pk.h[5] = f2bf(f1.y * scl);
        pk.h[6] = f2bf(f1.z * scl); pk.h[7] = f2bf(f1.w * scl);
      } else {
        pk.q = uint4{0, 0, 0, 0};
      }
      *reinterpret_cast<uint4*>(&Alds[aswz192(m, c)]) = pk.q;
    }
  }
  __syncthreads();
  int wid = t >> 6, l = t & 63;
  int lrow = l & 15, lk = l >> 4;
  int arow = wid * 16 + lrow;
  // layer 1: h[16 m][64 n] per wave, K=192 (6 mfma per 16-col tile)
  bf16x8 afr[6];
  #pragma unroll
  for (int g = 0; g < 6; ++g)
    afr[g] = *reinterpret_cast<const bf16x8*>(&Alds[aswz192(arow, g * 4 + lk)]);
  f32x4 acc[4];
  #pragma unroll
  for (int nt = 0; nt < 4; ++nt) {
    float di = d1_init[nt * 16 + lrow];
    acc[nt] = f32x4{di, di, di, di};
    #pragma unroll
    for (int g = 0; g < 6; ++g) {
      bf16x8 b = *reinterpret_cast<const bf16x8*>(
          &Wlds[aswz192(nt * 16 + lrow, g * 4 + lk)]);
      acc[nt] =
          __builtin_amdgcn_mfma_f32_16x16x32_bf16(afr[g], b, acc[nt], 0, 0, 0);
    }
  }
  // relu -> Hlds (swizzled [64][64] bf16); wave writes only its own 16 rows
  int m0 = (l >> 4) * 4;
  #pragma unroll
  for (int nt = 0; nt < 4; ++nt) {
    #pragma unroll
    for (int reg = 0; reg < 4; ++reg) {
      int hm = wid * 16 + m0 + reg;
      int hn = nt * 16 + lrow;
      Hlds[hm * 64 + (((hn >> 3) ^ (hm & 7)) << 3) + (hn & 7)] =
          f2bf(fmaxf(acc[nt][reg], 0.f));
    }
  }
  __syncthreads();
  // layer 2: out[16 m][16 o] per wave, K=64 (2 mfma)
  bf16x8 a20 = *reinterpret_cast<const bf16x8*>(&Hlds[aswz(arow, lk)]);
  bf16x8 a21 = *reinterpret_cast<const bf16x8*>(&Hlds[aswz(arow, 4 + lk)]);
  bf16x8 b20 = *reinterpret_cast<const bf16x8*>(&W2lds[aswz(lrow, lk)]);
  bf16x8 b21 = *reinterpret_cast<const bf16x8*>(&W2lds[aswz(lrow, 4 + lk)]);
  float bi = b_d2[lrow];
  f32x4 o = f32x4{bi, bi, bi, bi};
  o = __builtin_amdgcn_mfma_f32_16x16x32_bf16(a20, b20, o, 0, 0, 0);
  o = __builtin_amdgcn_mfma_f32_16x16x32_bf16(a21, b21, o, 0, 0, 0);
  #pragma unroll
  for (int reg = 0; reg < 4; ++reg) {
    int ge = base + wid * 16 + m0 + reg;
    if (ge < N) out[(size_t)ge * 16 + lrow] = o[reg];
  }
}

extern "C" void kernel_launch(void* const* d_in, const int* in_sizes, int n_in,
                              void* d_out, int out_size, void* d_ws,
                              size_t ws_size, hipStream_t stream) {
  const float* x         = (const float*)d_in[0];
  const float* edge_attr = (const float*)d_in[1];
  const float* u         = (const float*)d_in[2];
  const int*   senders   = (const int*)d_in[3];
  const int*   receivers = (const int*)d_in[4];
  const float* W_eb = (const float*)d_in[7];
  const float* b_eb = (const float*)d_in[8];
  const float* W_nb = (const float*)d_in[9];
  const float* b_nb = (const float*)d_in[10];
  const float* W_gb = (const float*)d_in[11];
  const float* b_gb = (const float*)d_in[12];
  const float* W_d1 = (const float*)d_in[13];
  const float* b_d1 = (const float*)d_in[14];
  const float* W_d2 = (const float*)d_in[15];
  const float* b_d2 = (const float*)d_in[16];

  int N = in_sizes[0] / 16;
  int E = in_sizes[1] / 16;
  int NB = (N + BW - 1) >> BSHIFT;  // 782 for N=100000
  int NDB = (E + DC - 1) / DC;      // distribute chunks per direction

  char* w = (char*)d_ws;
  ushort* e_h = (ushort*)w;          w += (size_t)E * 64 * 2;
  float* sum_recv = (float*)w;       w += (size_t)N * 64 * 4;
  float* sum_sent = (float*)w;       w += (size_t)N * 64 * 4;
  float* n_h = (float*)w;            w += (size_t)N * 64 * 4;
  uint* tmp_r = (uint*)w;            w += (size_t)E * 4;
  uint* tmp_s = (uint*)w;            w += (size_t)E * 4;
  uint* eidx_r = (uint*)w;           w += (size_t)E * 4;
  uint* eidx_s = (uint*)w;           w += (size_t)E * 4;
  uint* row_ptr_r = (uint*)w;        w += (size_t)N * 4;
  uint* row_ptr_s = (uint*)w;        w += (size_t)N * 4;
  uint* cnt_r = (uint*)w;            w += (size_t)N * 4;
  uint* cnt_s = (uint*)w;            w += (size_t)N * 4;
  ushort* xb = (ushort*)w;           w += (size_t)N * 16 * 2;
  ushort* wt_img = (ushort*)w;       w += (size_t)64 * 64 * 2;
  ushort* wtd1_img = (ushort*)w;     w += (size_t)64 * 192 * 2;
  ushort* w2_img = (ushort*)w;       w += (size_t)16 * 64 * 2;
  uint* start_r = (uint*)w;          w += (size_t)(NB + 1) * 4;
  uint* start_s = (uint*)w;          w += (size_t)(NB + 1) * 4;
  uint* cur_r = (uint*)w;            w += (size_t)NB * 4;
  uint* cur_s = (uint*)w;            w += (size_t)NB * 4;
  // zeroed region
  uint* bcnt_r = (uint*)w;           w += (size_t)NBMAX * 4;
  uint* bcnt_s = (uint*)w;           w += (size_t)NBMAX * 4;
  float* e_sum = (float*)w;          w += 64 * 4;
  float* n_sum = (float*)w;          w += 64 * 4;
  // small non-zeroed
  float* eb_init = (float*)w;        w += 64 * 4;
  float* nb_init = (float*)w;        w += 64 * 4;
  float* d1_init = (float*)w;        w += 64 * 4;

  size_t zero_bytes = (size_t)(2 * NBMAX + 128) * 4;
  hipMemsetAsync(bcnt_r, 0, zero_bytes, stream);

  hipLaunchKernelGGL(xconvert_kernel, dim3((N * 16 / 4 + 255) / 256), dim3(256),
                     0, stream, x, xb, N * 16);
  hipLaunchKernelGGL(precompute_kernel, dim3(1), dim3(64), 0, stream, u, W_eb,
                     b_eb, W_nb, b_nb, W_d1, W_d2, eb_init, nb_init, wt_img,
                     wtd1_img, w2_img);
  hipLaunchKernelGGL(bcount_kernel, dim3(64), dim3(256), 0, stream, receivers,
                     senders, bcnt_r, bcnt_s, E, NB);
  hipLaunchKernelGGL(bscan_kernel, dim3(1), dim3(256), 0, stream, bcnt_r,
                     bcnt_s, start_r, start_s, cur_r, cur_s, E, NB);
  hipLaunchKernelGGL(distribute_kernel, dim3(2 * NDB), dim3(256), 0, stream,
                     receivers, senders, cur_r, cur_s, tmp_r, tmp_s, E, NB);
  hipLaunchKernelGGL(bucketsort_kernel, dim3(2 * NB), dim3(256), 0, stream,
                     tmp_r, tmp_s, start_r, start_s, eidx_r, eidx_s, row_ptr_r,
                     row_ptr_s, cnt_r, cnt_s, N);
  // edge MFMA kernel right before gathers: e_h stays L3-resident
  hipLaunchKernelGGL(edge_mfma_kernel, dim3((E + 63) / 64), dim3(256), 0,
                     stream, edge_attr, xb, senders, receivers, wt_img,
                     eb_init, e_h, E);
  hipLaunchKernelGGL(gather_kernel, dim3((N + 3) / 4), dim3(256), 0, stream,
                     e_h, row_ptr_r, cnt_r, eidx_r, sum_recv, N);
  hipLaunchKernelGGL(gather_kernel, dim3((N + 3) / 4), dim3(256), 0, stream,
                     e_h, row_ptr_s, cnt_s, eidx_s, sum_sent, N);
  hipLaunchKernelGGL(node_kernel, dim3((N + 255) / 256), dim3(256), 0, stream,
                     x, sum_recv, W_nb, nb_init, n_h, N);
  hipLaunchKernelGGL(reduce_kernel, dim3(256), dim3(256), 0, stream, sum_recv,
                     n_h, e_sum, n_sum, N);
  hipLaunchKernelGGL(global_kernel, dim3(1), dim3(64), 0, stream, u, e_sum,
                     n_sum, W_gb, b_gb, W_d1, b_d1, d1_init, (float)E,
                     (float)N);
  hipLaunchKernelGGL(decoder_mfma_kernel, dim3((N + 63) / 64), dim3(256), 0,
                     stream, sum_recv, sum_sent, cnt_r, cnt_s, n_h, wtd1_img,
                     d1_init, w2_img, b_d2, (float*)d_out, N);
}

// Round 12
// 549.997 us; speedup vs baseline: 3.9255x; 1.0477x over previous
//
#include <hip/hip_runtime.h>

// GraphNet forward. Round 12: (1) node block -> MFMA (3rd use of the proven
// template), n_h stored bf16 (halves traffic, decoder copies it raw);
// (2) gather unroll 2->4 (latency-limited on L3-resident e_h: more rows in
// flight); (3) both gather directions in one launch.

typedef unsigned int uint;
typedef unsigned short ushort;
typedef __attribute__((ext_vector_type(8))) short bf16x8;
typedef __attribute__((ext_vector_type(4))) float f32x4;

#define BW 128          // nodes per bucket (sort)
#define BSHIFT 7
#define NBMAX 784       // max buckets (N=100000 -> 782)
#define DC 8192         // edges per distribute block
#define EMASK 0x1FFFFFu // 21 bits of edge id

#define LDF4(p) (*reinterpret_cast<const float4*>(p))

__device__ __forceinline__ ushort f2bf(float f) {
  uint u = __float_as_uint(f);
  u += 0x7FFFu + ((u >> 16) & 1u);
  return (ushort)(u >> 16);
}

// swizzled ushort index of 16B chunk (row, kb) in [row][64] bf16 tile
__device__ __forceinline__ int aswz(int row, int kb) {
  return row * 64 + ((kb ^ (row & 7)) << 3);
}
// [row][128] tile (kb 0..15)
__device__ __forceinline__ int nswz(int row, int kb) {
  return row * 128 + (((kb & 8) | ((kb ^ row) & 7)) << 3);
}
// [row][192] tile (kb 0..23)
__device__ __forceinline__ int aswz192(int row, int kb) {
  return row * 192 + (((kb & 24) | ((kb ^ row) & 7)) << 3);
}

// ---- x -> bf16 table (3.2MB, L2-resident)
__global__ __launch_bounds__(256) void xconvert_kernel(
    const float* __restrict__ x, ushort* __restrict__ xb, int n16) {
  int i = blockIdx.x * 256 + threadIdx.x;
  if (i * 4 >= n16) return;
  float4 a = LDF4(x + i * 4);
  ushort4 o = {f2bf(a.x), f2bf(a.y), f2bf(a.z), f2bf(a.w)};
  *reinterpret_cast<ushort4*>(xb + i * 4) = o;
}

// ---- fold uniform-u into init vectors + build swizzled bf16 W images
__global__ void precompute_kernel(const float* __restrict__ u,
                                  const float* __restrict__ W_eb,
                                  const float* __restrict__ b_eb,
                                  const float* __restrict__ W_nb,
                                  const float* __restrict__ b_nb,
                                  const float* __restrict__ W_d1,
                                  const float* __restrict__ W_d2,
                                  float* __restrict__ eb_init,
                                  float* __restrict__ nb_init,
                                  ushort* __restrict__ wt_img,
                                  ushort* __restrict__ wnb_img,
                                  ushort* __restrict__ wtd1_img,
                                  ushort* __restrict__ w2_img) {
  int j = threadIdx.x;  // 64 threads
  float ae = b_eb[j], an = b_nb[j];
  for (int k = 0; k < 64; ++k) {
    float uk = u[k];
    ae = fmaf(uk, W_eb[(48 + k) * 64 + j], ae);
    an = fmaf(uk, W_nb[(80 + k) * 64 + j], an);
  }
  eb_init[j] = ae;
  nb_init[j] = an;
  // edge Wt image: row = output n (=j), k 0..63 (48 real + 16 zero)
  for (int k = 0; k < 64; ++k) {
    ushort v = (k < 48) ? f2bf(W_eb[k * 64 + j]) : (ushort)0;
    wt_img[aswz(j, k >> 3) + (k & 7)] = v;
  }
  // node Wt image: row = output j, k 0..127 (80 real + 48 zero)
  for (int k = 0; k < 128; ++k) {
    ushort v = (k < 80) ? f2bf(W_nb[k * 64 + j]) : (ushort)0;
    wnb_img[nswz(j, k >> 3) + (k & 7)] = v;
  }
  // decoder layer-1 Wt image: row = output n (=j), k 0..191
  for (int k = 0; k < 192; ++k)
    wtd1_img[aswz192(j, k >> 3) + (k & 7)] = f2bf(W_d1[k * 64 + j]);
  // decoder layer-2 Wt image: row = output o (<16), k 0..63
  if (j < 16)
    for (int k = 0; k < 64; ++k)
      w2_img[aswz(j, k >> 3) + (k & 7)] = f2bf(W_d2[k * 16 + j]);
}

// ---- bucket histogram for both directions
__global__ __launch_bounds__(256) void bcount_kernel(
    const int* __restrict__ receivers, const int* __restrict__ senders,
    uint* __restrict__ bcnt_r, uint* __restrict__ bcnt_s, int E, int NB) {
  __shared__ uint hr[NBMAX], hs[NBMAX];
  int t = threadIdx.x;
  for (int i = t; i < NB; i += 256) { hr[i] = 0; hs[i] = 0; }
  __syncthreads();
  int stride = gridDim.x * 256;
  for (int e = blockIdx.x * 256 + t; e < E; e += stride) {
    atomicAdd(&hr[receivers[e] >> BSHIFT], 1u);
    atomicAdd(&hs[senders[e] >> BSHIFT], 1u);
  }
  __syncthreads();
  for (int i = t; i < NB; i += 256) {
    if (hr[i]) atomicAdd(&bcnt_r[i], hr[i]);
    if (hs[i]) atomicAdd(&bcnt_s[i], hs[i]);
  }
}

// ---- exclusive scan of both bucket-count arrays (single block, 4/thread)
__global__ __launch_bounds__(256) void bscan_kernel(
    const uint* __restrict__ bcnt_r, const uint* __restrict__ bcnt_s,
    uint* __restrict__ start_r, uint* __restrict__ start_s,
    uint* __restrict__ cur_r, uint* __restrict__ cur_s, int E, int NB) {
  __shared__ uint ts[256];
  int t = threadIdx.x;
  #pragma unroll
  for (int pass = 0; pass < 2; ++pass) {
    const uint* cnt = pass ? bcnt_s : bcnt_r;
    uint* start = pass ? start_s : start_r;
    uint* cur = pass ? cur_s : cur_r;
    uint loc[4]; uint tsum = 0;
    #pragma unroll
    for (int q = 0; q < 4; ++q) {
      int i = t * 4 + q;
      loc[q] = (i < NB) ? cnt[i] : 0;
      tsum += loc[q];
    }
    ts[t] = tsum;
    __syncthreads();
    for (int off = 1; off < 256; off <<= 1) {
      uint a = (t >= off) ? ts[t - off] : 0;
      __syncthreads();
      ts[t] += a;
      __syncthreads();
    }
    uint run = ts[t] - tsum;
    #pragma unroll
    for (int q = 0; q < 4; ++q) {
      int i = t * 4 + q;
      if (i < NB) { start[i] = run; cur[i] = run; run += loc[q]; }
    }
    if (t == 0) start[NB] = (uint)E;
    __syncthreads();
  }
}

// ---- bucket-sort edge ids, both directions in one launch.
__global__ __launch_bounds__(256) void distribute_kernel(
    const int* __restrict__ receivers, const int* __restrict__ senders,
    uint* __restrict__ gcur_r, uint* __restrict__ gcur_s,
    uint* __restrict__ tmp_r, uint* __restrict__ tmp_s, int E, int NB) {
  __shared__ uint hist[NBMAX], lstart[NBMAX], cur[NBMAX], gbase[NBMAX];
  __shared__ uint ids[DC];
  __shared__ ushort idsB[DC];
  __shared__ uint ts[256];
  int dir = blockIdx.x & 1;
  const int* key = dir ? senders : receivers;
  uint* g_cursor = dir ? gcur_s : gcur_r;
  uint* tmp = dir ? tmp_s : tmp_r;
  int t = threadIdx.x;
  int base = (blockIdx.x >> 1) * DC;
  int cact = min(DC, E - base);
  for (int i = t; i < NB; i += 256) hist[i] = 0;
  __syncthreads();
  for (int k = 0; k < DC / 256; ++k) {
    int j = k * 256 + t;
    if (j < cact) atomicAdd(&hist[key[base + j] >> BSHIFT], 1u);
  }
  __syncthreads();
  {
    uint loc[4]; uint tsum = 0;
    #pragma unroll
    for (int q = 0; q < 4; ++q) {
      int i = t * 4 + q;
      loc[q] = (i < NB) ? hist[i] : 0;
      tsum += loc[q];
    }
    ts[t] = tsum;
    __syncthreads();
    for (int off = 1; off < 256; off <<= 1) {
      uint a = (t >= off) ? ts[t - off] : 0;
      __syncthreads();
      ts[t] += a;
      __syncthreads();
    }
    uint run = ts[t] - tsum;
    #pragma unroll
    for (int q = 0; q < 4; ++q) {
      int i = t * 4 + q;
      if (i < NB) { lstart[i] = run; cur[i] = run; run += loc[q]; }
    }
  }
  __syncthreads();
  for (int i = t; i < NB; i += 256)
    if (hist[i]) gbase[i] = atomicAdd(&g_cursor[i], hist[i]);
  for (int k = 0; k < DC / 256; ++k) {
    int j = k * 256 + t;
    if (j < cact) {
      int e = base + j;
      int kk = key[e];
      uint b = (uint)(kk >> BSHIFT);
      uint slot = atomicAdd(&cur[b], 1u);
      ids[slot] = ((uint)(kk & (BW - 1)) << 21) | (uint)e;
      idsB[slot] = (ushort)b;
    }
  }
  __syncthreads();
  for (int j = t; j < cact; j += 256) {
    uint b2 = idsB[j];
    tmp[gbase[b2] + ((uint)j - lstart[b2])] = ids[j];
  }
}

// ---- per-bucket counting sort to full per-node order.
__global__ __launch_bounds__(256) void bucketsort_kernel(
    const uint* __restrict__ tmp_r, const uint* __restrict__ tmp_s,
    const uint* __restrict__ start_r, const uint* __restrict__ start_s,
    uint* __restrict__ eidx_r, uint* __restrict__ eidx_s,
    uint* __restrict__ row_ptr_r, uint* __restrict__ row_ptr_s,
    uint* __restrict__ cnt_r, uint* __restrict__ cnt_s, int N) {
  __shared__ uint hist[BW], pfx[BW], cur[BW];
  int d = blockIdx.x & 1;
  int b = blockIdx.x >> 1;
  const uint* tmp = d ? tmp_s : tmp_r;
  const uint* start = d ? start_s : start_r;
  uint* eidx = d ? eidx_s : eidx_r;
  uint* row_ptr = d ? row_ptr_s : row_ptr_r;
  uint* cnt = d ? cnt_s : cnt_r;
  int t = threadIdx.x;
  if (t < BW) hist[t] = 0;
  __syncthreads();
  int beg = (int)start[b], end = (int)start[b + 1];
  for (int i = beg + t; i < end; i += 256) atomicAdd(&hist[tmp[i] >> 21], 1u);
  __syncthreads();
  if (t < BW) pfx[t] = hist[t];
  __syncthreads();
  for (int off = 1; off < BW; off <<= 1) {
    uint a = 0;
    if (t < BW && t >= off) a = pfx[t - off];
    __syncthreads();
    if (t < BW) pfx[t] += a;
    __syncthreads();
  }
  if (t < BW) cur[t] = pfx[t] - hist[t];
  __syncthreads();
  for (int i = beg + t; i < end; i += 256) {
    uint v = tmp[i];
    uint nl = v >> 21;
    uint p = atomicAdd(&cur[nl], 1u);
    eidx[beg + p] = v & EMASK;
  }
  int nbase = b * BW;
  if (t < BW && nbase + t < N) {
    cnt[nbase + t] = hist[t];
    row_ptr[nbase + t] = (uint)beg + pfx[t] - hist[t];
  }
}

// ---- edge MLP via MFMA (refcheck-proven)
__global__ __launch_bounds__(256, 2) void edge_mfma_kernel(
    const float* __restrict__ edge_attr, const ushort* __restrict__ xb,
    const int* __restrict__ senders, const int* __restrict__ receivers,
    const ushort* __restrict__ wt_img, const float* __restrict__ eb_init,
    ushort* __restrict__ e_h, int E) {
  __shared__ ushort Alds[64 * 64];       // 8 KB
  __shared__ ushort Wlds[64 * 64];       // 8 KB
  __shared__ ushort Clds[4][16 * 72];    // 9 KB (pitch 72)
  int t = threadIdx.x;
  int base = blockIdx.x * 64;
  {
    const uint4* src = reinterpret_cast<const uint4*>(wt_img);
    uint4* dst = reinterpret_cast<uint4*>(Wlds);
    dst[t * 2] = src[t * 2];
    dst[t * 2 + 1] = src[t * 2 + 1];
  }
  {
    int m = t >> 2, part = t & 3;
    int e = base + m;
    bool val = e < E;
    if (part < 2) {
      union { ushort h[8]; uint4 q; } pk;
      if (val) {
        const float* ap = edge_attr + (size_t)e * 16 + part * 8;
        float4 f0 = LDF4(ap), f1 = LDF4(ap + 4);
        pk.h[0] = f2bf(f0.x); pk.h[1] = f2bf(f0.y);
        pk.h[2] = f2bf(f0.z); pk.h[3] = f2bf(f0.w);
        pk.h[4] = f2bf(f1.x); pk.h[5] = f2bf(f1.y);
        pk.h[6] = f2bf(f1.z); pk.h[7] = f2bf(f1.w);
      } else {
        pk.q = uint4{0, 0, 0, 0};
      }
      *reinterpret_cast<uint4*>(&Alds[aswz(m, part)]) = pk.q;
    } else {
      uint4 w0 = {0, 0, 0, 0}, w1 = {0, 0, 0, 0};
      if (val) {
        int node = (part == 2) ? receivers[e] : senders[e];
        const uint4* xp = reinterpret_cast<const uint4*>(xb + (size_t)node * 16);
        w0 = xp[0]; w1 = xp[1];
      }
      int kb = (part == 2) ? 2 : 4;
      *reinterpret_cast<uint4*>(&Alds[aswz(m, kb)]) = w0;
      *reinterpret_cast<uint4*>(&Alds[aswz(m, kb + 1)]) = w1;
    }
    if (t < 128) {
      int zr = t >> 1, zkb = 6 + (t & 1);
      *reinterpret_cast<uint4*>(&Alds[aswz(zr, zkb)]) = uint4{0, 0, 0, 0};
    }
  }
  __syncthreads();
  int wid = t >> 6, l = t & 63;
  int lrow = l & 15, lk = l >> 4;
  int arow = wid * 16 + lrow;
  bf16x8 a0 = *reinterpret_cast<const bf16x8*>(&Alds[aswz(arow, lk)]);
  bf16x8 a1 = *reinterpret_cast<const bf16x8*>(&Alds[aswz(arow, 4 + lk)]);
  f32x4 acc[4];
  #pragma unroll
  for (int nt = 0; nt < 4; ++nt) {
    float ebi = eb_init[nt * 16 + lrow];
    acc[nt] = f32x4{ebi, ebi, ebi, ebi};
    bf16x8 b0 =
        *reinterpret_cast<const bf16x8*>(&Wlds[aswz(nt * 16 + lrow, lk)]);
    bf16x8 b1 =
        *reinterpret_cast<const bf16x8*>(&Wlds[aswz(nt * 16 + lrow, 4 + lk)]);
    acc[nt] = __builtin_amdgcn_mfma_f32_16x16x32_bf16(a0, b0, acc[nt], 0, 0, 0);
    acc[nt] = __builtin_amdgcn_mfma_f32_16x16x32_bf16(a1, b1, acc[nt], 0, 0, 0);
  }
  int m0 = (l >> 4) * 4;
  #pragma unroll
  for (int nt = 0; nt < 4; ++nt) {
    #pragma unroll
    for (int reg = 0; reg < 4; ++reg) {
      Clds[wid][(m0 + reg) * 72 + nt * 16 + lrow] =
          f2bf(fmaxf(acc[nt][reg], 0.f));
    }
  }
  __syncthreads();
  int sm = l >> 2, ch = l & 3;
  int ge = base + wid * 16 + sm;
  uint4 c0 = *reinterpret_cast<const uint4*>(&Clds[wid][sm * 72 + ch * 16]);
  uint4 c1 = *reinterpret_cast<const uint4*>(&Clds[wid][sm * 72 + ch * 16 + 8]);
  if (ge < E) {
    uint4* dst = reinterpret_cast<uint4*>(e_h + (size_t)ge * 64 + ch * 16);
    dst[0] = c0;
    dst[1] = c1;
  }
}

// ---- gather, both directions in one launch; wave per node; unroll 4.
__global__ __launch_bounds__(256, 4) void gather_kernel(
    const ushort* __restrict__ e_h, const uint* __restrict__ row_ptr_r,
    const uint* __restrict__ cnt_r, const uint* __restrict__ eidx_r,
    const uint* __restrict__ row_ptr_s, const uint* __restrict__ cnt_s,
    const uint* __restrict__ eidx_s, float* __restrict__ sum_recv,
    float* __restrict__ sum_sent, int N) {
  int dir = blockIdx.x & 1;
  const uint* row_ptr = dir ? row_ptr_s : row_ptr_r;
  const uint* cnt = dir ? cnt_s : cnt_r;
  const uint* eidx = dir ? eidx_s : eidx_r;
  float* out = dir ? sum_sent : sum_recv;
  int n = (blockIdx.x >> 1) * 4 + (threadIdx.x >> 6);
  if (n >= N) return;
  const uint* eh32 = reinterpret_cast<const uint*>(e_h);
  int lane = threadIdx.x & 63;
  int half = lane >> 5;
  int l = lane & 31;
  int beg = (int)row_ptr[n], end = beg + (int)cnt[n];
  float a0 = 0, a1 = 0, b0 = 0, b1 = 0, c0 = 0, c1 = 0, d0 = 0, d1 = 0;
  int i = beg + half;
  for (; i + 6 < end; i += 8) {
    uint e0 = eidx[i], e1 = eidx[i + 2], e2 = eidx[i + 4], e3 = eidx[i + 6];
    uint w0 = eh32[(size_t)e0 * 32 + l];
    uint w1 = eh32[(size_t)e1 * 32 + l];
    uint w2 = eh32[(size_t)e2 * 32 + l];
    uint w3 = eh32[(size_t)e3 * 32 + l];
    a0 += __uint_as_float(w0 << 16);
    a1 += __uint_as_float(w0 & 0xFFFF0000u);
    b0 += __uint_as_float(w1 << 16);
    b1 += __uint_as_float(w1 & 0xFFFF0000u);
    c0 += __uint_as_float(w2 << 16);
    c1 += __uint_as_float(w2 & 0xFFFF0000u);
    d0 += __uint_as_float(w3 << 16);
    d1 += __uint_as_float(w3 & 0xFFFF0000u);
  }
  for (; i < end; i += 2) {
    uint w0 = eh32[(size_t)eidx[i] * 32 + l];
    a0 += __uint_as_float(w0 << 16);
    a1 += __uint_as_float(w0 & 0xFFFF0000u);
  }
  a0 = (a0 + b0) + (c0 + d0);
  a1 = (a1 + b1) + (c1 + d1);
  a0 += __shfl_xor(a0, 32);
  a1 += __shfl_xor(a1, 32);
  if (half == 0) {
    float2 t = {a0, a1};
    *reinterpret_cast<float2*>(out + (size_t)n * 64 + 2 * l) = t;
  }
}

// ---- node block via MFMA: n_h(bf16) = relu([sum_recv, x]@W_nb + nb_init)
__global__ __launch_bounds__(256, 2) void node_mfma_kernel(
    const float* __restrict__ sum_recv, const ushort* __restrict__ xb,
    const ushort* __restrict__ wnb_img, const float* __restrict__ nb_init,
    ushort* __restrict__ n_h, int N) {
  __shared__ ushort Alds[64 * 128];      // 16 KB
  __shared__ ushort Wlds[64 * 128];      // 16 KB
  __shared__ ushort Clds[4][16 * 72];    // 9 KB
  int t = threadIdx.x;
  int base = blockIdx.x * 64;
  // stage W image (1024 uint4)
  {
    const uint4* src = reinterpret_cast<const uint4*>(wnb_img);
    uint4* dst = reinterpret_cast<uint4*>(Wlds);
    #pragma unroll
    for (int i = 0; i < 4; ++i) dst[t + 256 * i] = src[t + 256 * i];
  }
  // stage A: 4 threads/node, 4 chunks each (16 chunks = 128 k)
  {
    int m = t >> 2, part = t & 3;
    int n = base + m;
    bool val = n < N;
    if (part < 2) {
      // chunks 0..7: sum_recv fp32 -> bf16
      #pragma unroll
      for (int q = 0; q < 4; ++q) {
        int c = part * 4 + q;
        union { ushort h[8]; uint4 qq; } pk;
        if (val) {
          const float* src = sum_recv + (size_t)n * 64 + c * 8;
          float4 f0 = LDF4(src), f1 = LDF4(src + 4);
          pk.h[0] = f2bf(f0.x); pk.h[1] = f2bf(f0.y);
          pk.h[2] = f2bf(f0.z); pk.h[3] = f2bf(f0.w);
          pk.h[4] = f2bf(f1.x); pk.h[5] = f2bf(f1.y);
          pk.h[6] = f2bf(f1.z); pk.h[7] = f2bf(f1.w);
        } else {
          pk.qq = uint4{0, 0, 0, 0};
        }
        *reinterpret_cast<uint4*>(&Alds[nswz(m, c)]) = pk.qq;
      }
    } else if (part == 2) {
      // chunks 8,9: xb row (bf16 direct); chunks 10,11: zero
      uint4 w0 = {0, 0, 0, 0}, w1 = {0, 0, 0, 0};
      if (val) {
        const uint4* xp = reinterpret_cast<const uint4*>(xb + (size_t)n * 16);
        w0 = xp[0]; w1 = xp[1];
      }
      *reinterpret_cast<uint4*>(&Alds[nswz(m, 8)]) = w0;
      *reinterpret_cast<uint4*>(&Alds[nswz(m, 9)]) = w1;
      *reinterpret_cast<uint4*>(&Alds[nswz(m, 10)]) = uint4{0, 0, 0, 0};
      *reinterpret_cast<uint4*>(&Alds[nswz(m, 11)]) = uint4{0, 0, 0, 0};
    } else {
      #pragma unroll
      for (int q = 0; q < 4; ++q)
        *reinterpret_cast<uint4*>(&Alds[nswz(m, 12 + q)]) = uint4{0, 0, 0, 0};
    }
  }
  __syncthreads();
  int wid = t >> 6, l = t & 63;
  int lrow = l & 15, lk = l >> 4;
  int arow = wid * 16 + lrow;
  bf16x8 afr[4];
  #pragma unroll
  for (int g = 0; g < 4; ++g)
    afr[g] = *reinterpret_cast<const bf16x8*>(&Alds[nswz(arow, g * 4 + lk)]);
  f32x4 acc[4];
  #pragma unroll
  for (int nt = 0; nt < 4; ++nt) {
    float nbi = nb_init[nt * 16 + lrow];
    acc[nt] = f32x4{nbi, nbi, nbi, nbi};
    #pragma unroll
    for (int g = 0; g < 4; ++g) {
      bf16x8 b = *reinterpret_cast<const bf16x8*>(
          &Wlds[nswz(nt * 16 + lrow, g * 4 + lk)]);
      acc[nt] =
          __builtin_amdgcn_mfma_f32_16x16x32_bf16(afr[g], b, acc[nt], 0, 0, 0);
    }
  }
  int m0 = (l >> 4) * 4;
  #pragma unroll
  for (int nt = 0; nt < 4; ++nt) {
    #pragma unroll
    for (int reg = 0; reg < 4; ++reg) {
      Clds[wid][(m0 + reg) * 72 + nt * 16 + lrow] =
          f2bf(fmaxf(acc[nt][reg], 0.f));
    }
  }
  __syncthreads();
  int sm = l >> 2, ch = l & 3;
  int gn = base + wid * 16 + sm;
  uint4 c0 = *reinterpret_cast<const uint4*>(&Clds[wid][sm * 72 + ch * 16]);
  uint4 c1 = *reinterpret_cast<const uint4*>(&Clds[wid][sm * 72 + ch * 16 + 8]);
  if (gn < N) {
    uint4* dst = reinterpret_cast<uint4*>(n_h + (size_t)gn * 64 + ch * 16);
    dst[0] = c0;
    dst[1] = c1;
  }
}

// ---- column sums of sum_recv (fp32) and n_h (bf16)
__global__ __launch_bounds__(256) void reduce_kernel(
    const float* __restrict__ sum_recv, const ushort* __restrict__ n_h,
    float* __restrict__ e_sum, float* __restrict__ n_sum, int N) {
  __shared__ float ls[128];
  if (threadIdx.x < 128) ls[threadIdx.x] = 0.f;
  __syncthreads();
  int g = threadIdx.x & 15;
  int tid = blockIdx.x * blockDim.x + threadIdx.x;
  int row0 = tid >> 4;
  int rstride = (gridDim.x * blockDim.x) >> 4;
  float pe[4] = {0, 0, 0, 0}, pn[4] = {0, 0, 0, 0};
  for (int r = row0; r < N; r += rstride) {
    float4 a = LDF4(sum_recv + (size_t)r * 64 + g * 4);
    uint2 b = *reinterpret_cast<const uint2*>(n_h + (size_t)r * 64 + g * 4);
    pe[0] += a.x; pe[1] += a.y; pe[2] += a.z; pe[3] += a.w;
    pn[0] += __uint_as_float(b.x << 16);
    pn[1] += __uint_as_float(b.x & 0xFFFF0000u);
    pn[2] += __uint_as_float(b.y << 16);
    pn[3] += __uint_as_float(b.y & 0xFFFF0000u);
  }
  #pragma unroll
  for (int i = 0; i < 4; ++i) {
    atomicAdd(&ls[g * 4 + i], pe[i]);
    atomicAdd(&ls[64 + g * 4 + i], pn[i]);
  }
  __syncthreads();
  if (threadIdx.x < 64) {
    atomicAdd(&e_sum[threadIdx.x], ls[threadIdx.x]);
    atomicAdd(&n_sum[threadIdx.x], ls[64 + threadIdx.x]);
  }
}

// ---- global block + fold u2 into d1_init
__global__ void global_kernel(const float* __restrict__ u,
                              const float* __restrict__ e_sum,
                              const float* __restrict__ n_sum,
                              const float* __restrict__ W_gb,
                              const float* __restrict__ b_gb,
                              const float* __restrict__ W_d1,
                              const float* __restrict__ b_d1,
                              float* __restrict__ d1_init, float Ef, float Nf) {
  __shared__ float gin[192];
  __shared__ float u2s[64];
  int j = threadIdx.x;  // 64 threads
  gin[j] = e_sum[j] / Ef;
  gin[64 + j] = n_sum[j] / Nf;
  gin[128 + j] = u[j];
  __syncthreads();
  float a = b_gb[j];
  for (int k = 0; k < 192; ++k) a = fmaf(gin[k], W_gb[k * 64 + j], a);
  u2s[j] = fmaxf(a, 0.f);
  __syncthreads();
  float d = b_d1[j];
  for (int k = 0; k < 64; ++k) d = fmaf(u2s[k], W_d1[(192 + k) * 64 + j], d);
  d1_init[j] = d;
}

// ---- decoder via MFMA: out = relu(A@W_d1 + d1_init) @ W_d2 + b_d2
__global__ __launch_bounds__(256, 2) void decoder_mfma_kernel(
    const float* __restrict__ sum_recv, const float* __restrict__ sum_sent,
    const uint* __restrict__ cnt_r, const uint* __restrict__ cnt_s,
    const ushort* __restrict__ n_h, const ushort* __restrict__ wtd1_img,
    const float* __restrict__ d1_init, const ushort* __restrict__ w2_img,
    const float* __restrict__ b_d2, float* __restrict__ out, int N) {
  __shared__ ushort Alds[64 * 192];   // 24 KB
  __shared__ ushort Wlds[64 * 192];   // 24 KB
  __shared__ ushort Hlds[64 * 64];    // 8 KB
  __shared__ ushort W2lds[16 * 64];   // 2 KB
  int t = threadIdx.x;
  int base = blockIdx.x * 64;
  {
    const uint4* src = reinterpret_cast<const uint4*>(wtd1_img);
    uint4* dst = reinterpret_cast<uint4*>(Wlds);
    #pragma unroll
    for (int i = 0; i < 6; ++i) dst[t + 256 * i] = src[t + 256 * i];
    if (t < 128)
      reinterpret_cast<uint4*>(W2lds)[t] =
          reinterpret_cast<const uint4*>(w2_img)[t];
  }
  // stage A: 4 threads per node, 6 chunks-of-8 each (24 chunks = 192 k)
  {
    int m = t >> 2;
    int n = base + m;
    bool val = n < N;
    float invr = 0.f, invs = 0.f;
    if (val) {
      invr = 1.f / fmaxf((float)cnt_r[n], 1.f);
      invs = 1.f / fmaxf((float)cnt_s[n], 1.f);
    }
    int c0 = (t & 3) * 6;
    for (int c = c0; c < c0 + 6; ++c) {
      union { ushort h[8]; uint4 q; } pk;
      if (val) {
        if (c >= 16) {
          pk.q = *reinterpret_cast<const uint4*>(n_h + (size_t)n * 64 +
                                                 (c - 16) * 8);
        } else {
          const float* src;
          float scl;
          if (c < 8) { src = sum_recv + (size_t)n * 64 + c * 8; scl = invr; }
          else       { src = sum_sent + (size_t)n * 64 + (c - 8) * 8; scl = invs; }
          float4 f0 = LDF4(src), f1 = LDF4(src + 4);
          pk.h[0] = f2bf(f0.x * scl); pk.h[1] = f2bf(f0.y * scl);
          pk.h[2] = f2bf(f0.z * scl); pk.h[3] = f2bf(f0.w * scl);
          pk.h[4] = f2bf(f1.x * scl); pk.h[5] = f2bf(f1.y * scl);
          pk.h[6] = f2bf(f1.z * scl); pk.h[7] = f2bf(f1.w * scl);
        }
      } else {
        pk.q = uint4{0, 0, 0, 0};
      }
      *reinterpret_cast<uint4*>(&Alds[aswz192(m, c)]) = pk.q;
    }
  }
  __syncthreads();
  int wid = t >> 6, l = t & 63;
  int lrow = l & 15, lk = l >> 4;
  int arow = wid * 16 + lrow;
  bf16x8 afr[6];
  #pragma unroll
  for (int g = 0; g < 6; ++g)
    afr[g] = *reinterpret_cast<const bf16x8*>(&Alds[aswz192(arow, g * 4 + lk)]);
  f32x4 acc[4];
  #pragma unroll
  for (int nt = 0; nt < 4; ++nt) {
    float di = d1_init[nt * 16 + lrow];
    acc[nt] = f32x4{di, di, di, di};
    #pragma unroll
    for (int g = 0; g < 6; ++g) {
      bf16x8 b = *reinterpret_cast<const bf16x8*>(
          &Wlds[aswz192(nt * 16 + lrow, g * 4 + lk)]);
      acc[nt] =
          __builtin_amdgcn_mfma_f32_16x16x32_bf16(afr[g], b, acc[nt], 0, 0, 0);
    }
  }
  int m0 = (l >> 4) * 4;
  #pragma unroll
  for (int nt = 0; nt < 4; ++nt) {
    #pragma unroll
    for (int reg = 0; reg < 4; ++reg) {
      int hm = wid * 16 + m0 + reg;
      int hn = nt * 16 + lrow;
      Hlds[hm * 64 + (((hn >> 3) ^ (hm & 7)) << 3) + (hn & 7)] =
          f2bf(fmaxf(acc[nt][reg], 0.f));
    }
  }
  __syncthreads();
  bf16x8 a20 = *reinterpret_cast<const bf16x8*>(&Hlds[aswz(arow, lk)]);
  bf16x8 a21 = *reinterpret_cast<const bf16x8*>(&Hlds[aswz(arow, 4 + lk)]);
  bf16x8 b20 = *reinterpret_cast<const bf16x8*>(&W2lds[aswz(lrow, lk)]);
  bf16x8 b21 = *reinterpret_cast<const bf16x8*>(&W2lds[aswz(lrow, 4 + lk)]);
  float bi = b_d2[lrow];
  f32x4 o = f32x4{bi, bi, bi, bi};
  o = __builtin_amdgcn_mfma_f32_16x16x32_bf16(a20, b20, o, 0, 0, 0);
  o = __builtin_amdgcn_mfma_f32_16x16x32_bf16(a21, b21, o, 0, 0, 0);
  #pragma unroll
  for (int reg = 0; reg < 4; ++reg) {
    int ge = base + wid * 16 + m0 + reg;
    if (ge < N) out[(size_t)ge * 16 + lrow] = o[reg];
  }
}

extern "C" void kernel_launch(void* const* d_in, const int* in_sizes, int n_in,
                              void* d_out, int out_size, void* d_ws,
                              size_t ws_size, hipStream_t stream) {
  const float* x         = (const float*)d_in[0];
  const float* edge_attr = (const float*)d_in[1];
  const float* u         = (const float*)d_in[2];
  const int*   senders   = (const int*)d_in[3];
  const int*   receivers = (const int*)d_in[4];
  const float* W_eb = (const float*)d_in[7];
  const float* b_eb = (const float*)d_in[8];
  const float* W_nb = (const float*)d_in[9];
  const float* b_nb = (const float*)d_in[10];
  const float* W_gb = (const float*)d_in[11];
  const float* b_gb = (const float*)d_in[12];
  const float* W_d1 = (const float*)d_in[13];
  const float* b_d1 = (const float*)d_in[14];
  const float* W_d2 = (const float*)d_in[15];
  const float* b_d2 = (const float*)d_in[16];

  int N = in_sizes[0] / 16;
  int E = in_sizes[1] / 16;
  int NB = (N + BW - 1) >> BSHIFT;  // 782 for N=100000
  int NDB = (E + DC - 1) / DC;      // distribute chunks per direction

  char* w = (char*)d_ws;
  ushort* e_h = (ushort*)w;          w += (size_t)E * 64 * 2;
  float* sum_recv = (float*)w;       w += (size_t)N * 64 * 4;
  float* sum_sent = (float*)w;       w += (size_t)N * 64 * 4;
  ushort* n_h = (ushort*)w;          w += (size_t)N * 64 * 2;
  uint* tmp_r = (uint*)w;            w += (size_t)E * 4;
  uint* tmp_s = (uint*)w;            w += (size_t)E * 4;
  uint* eidx_r = (uint*)w;           w += (size_t)E * 4;
  uint* eidx_s = (uint*)w;           w += (size_t)E * 4;
  uint* row_ptr_r = (uint*)w;        w += (size_t)N * 4;
  uint* row_ptr_s = (uint*)w;        w += (size_t)N * 4;
  uint* cnt_r = (uint*)w;            w += (size_t)N * 4;
  uint* cnt_s = (uint*)w;            w += (size_t)N * 4;
  ushort* xb = (ushort*)w;           w += (size_t)N * 16 * 2;
  ushort* wt_img = (ushort*)w;       w += (size_t)64 * 64 * 2;
  ushort* wnb_img = (ushort*)w;      w += (size_t)64 * 128 * 2;
  ushort* wtd1_img = (ushort*)w;     w += (size_t)64 * 192 * 2;
  ushort* w2_img = (ushort*)w;       w += (size_t)16 * 64 * 2;
  uint* start_r = (uint*)w;          w += (size_t)(NB + 1) * 4;
  uint* start_s = (uint*)w;          w += (size_t)(NB + 1) * 4;
  uint* cur_r = (uint*)w;            w += (size_t)NB * 4;
  uint* cur_s = (uint*)w;            w += (size_t)NB * 4;
  // zeroed region
  uint* bcnt_r = (uint*)w;           w += (size_t)NBMAX * 4;
  uint* bcnt_s = (uint*)w;           w += (size_t)NBMAX * 4;
  float* e_sum = (float*)w;          w += 64 * 4;
  float* n_sum = (float*)w;          w += 64 * 4;
  // small non-zeroed
  float* eb_init = (float*)w;        w += 64 * 4;
  float* nb_init = (float*)w;        w += 64 * 4;
  float* d1_init = (float*)w;        w += 64 * 4;

  size_t zero_bytes = (size_t)(2 * NBMAX + 128) * 4;
  hipMemsetAsync(bcnt_r, 0, zero_bytes, stream);

  hipLaunchKernelGGL(xconvert_kernel, dim3((N * 16 / 4 + 255) / 256), dim3(256),
                     0, stream, x, xb, N * 16);
  hipLaunchKernelGGL(precompute_kernel, dim3(1), dim3(64), 0, stream, u, W_eb,
                     b_eb, W_nb, b_nb, W_d1, W_d2, eb_init, nb_init, wt_img,
                     wnb_img, wtd1_img, w2_img);
  hipLaunchKernelGGL(bcount_kernel, dim3(64), dim3(256), 0, stream, receivers,
                     senders, bcnt_r, bcnt_s, E, NB);
  hipLaunchKernelGGL(bscan_kernel, dim3(1), dim3(256), 0, stream, bcnt_r,
                     bcnt_s, start_r, start_s, cur_r, cur_s, E, NB);
  hipLaunchKernelGGL(distribute_kernel, dim3(2 * NDB), dim3(256), 0, stream,
                     receivers, senders, cur_r, cur_s, tmp_r, tmp_s, E, NB);
  hipLaunchKernelGGL(bucketsort_kernel, dim3(2 * NB), dim3(256), 0, stream,
                     tmp_r, tmp_s, start_r, start_s, eidx_r, eidx_s, row_ptr_r,
                     row_ptr_s, cnt_r, cnt_s, N);
  // edge MFMA kernel right before gathers: e_h stays L3-resident
  hipLaunchKernelGGL(edge_mfma_kernel, dim3((E + 63) / 64), dim3(256), 0,
                     stream, edge_attr, xb, senders, receivers, wt_img,
                     eb_init, e_h, E);
  hipLaunchKernelGGL(gather_kernel, dim3(2 * ((N + 3) / 4)), dim3(256), 0,
                     stream, e_h, row_ptr_r, cnt_r, eidx_r, row_ptr_s, cnt_s,
                     eidx_s, sum_recv, sum_sent, N);
  hipLaunchKernelGGL(node_mfma_kernel, dim3((N + 63) / 64), dim3(256), 0,
                     stream, sum_recv, xb, wnb_img, nb_init, n_h, N);
  hipLaunchKernelGGL(reduce_kernel, dim3(256), dim3(256), 0, stream, sum_recv,
                     n_h, e_sum, n_sum, N);
  hipLaunchKernelGGL(global_kernel, dim3(1), dim3(64), 0, stream, u, e_sum,
                     n_sum, W_gb, b_gb, W_d1, b_d1, d1_init, (float)E,
                     (float)N);
  hipLaunchKernelGGL(decoder_mfma_kernel, dim3((N + 63) / 64), dim3(256), 0,
                     stream, sum_recv, sum_sent, cnt_r, cnt_s, n_h, wtd1_img,
                     d1_init, w2_img, b_d2, (float*)d_out, N);
}

// Round 13
// 531.666 us; speedup vs baseline: 4.0609x; 1.0345x over previous
//
#include <hip/hip_runtime.h>

// GraphNet forward. Round 13: gather software-pipeline fix. r12 gather ran
// at VGPR=16 (loads serialized; occ 79%, VALU 25%, hbm 20% - nothing
// saturated; 2.9 TB/s delivered). Restructure: contiguous per-half edge
// ranges + index prefetch (next iter's eidx loaded before this iter's rows
// are consumed) + launch_bounds(256,2). Everything else unchanged (proven).

typedef unsigned int uint;
typedef unsigned short ushort;
typedef __attribute__((ext_vector_type(8))) short bf16x8;
typedef __attribute__((ext_vector_type(4))) float f32x4;

#define BW 128          // nodes per bucket (sort)
#define BSHIFT 7
#define NBMAX 784       // max buckets (N=100000 -> 782)
#define DC 8192         // edges per distribute block
#define EMASK 0x1FFFFFu // 21 bits of edge id

#define LDF4(p) (*reinterpret_cast<const float4*>(p))

__device__ __forceinline__ ushort f2bf(float f) {
  uint u = __float_as_uint(f);
  u += 0x7FFFu + ((u >> 16) & 1u);
  return (ushort)(u >> 16);
}

// swizzled ushort index of 16B chunk (row, kb) in [row][64] bf16 tile
__device__ __forceinline__ int aswz(int row, int kb) {
  return row * 64 + ((kb ^ (row & 7)) << 3);
}
// [row][128] tile (kb 0..15)
__device__ __forceinline__ int nswz(int row, int kb) {
  return row * 128 + (((kb & 8) | ((kb ^ row) & 7)) << 3);
}
// [row][192] tile (kb 0..23)
__device__ __forceinline__ int aswz192(int row, int kb) {
  return row * 192 + (((kb & 24) | ((kb ^ row) & 7)) << 3);
}

// ---- x -> bf16 table (3.2MB, L2-resident)
__global__ __launch_bounds__(256) void xconvert_kernel(
    const float* __restrict__ x, ushort* __restrict__ xb, int n16) {
  int i = blockIdx.x * 256 + threadIdx.x;
  if (i * 4 >= n16) return;
  float4 a = LDF4(x + i * 4);
  ushort4 o = {f2bf(a.x), f2bf(a.y), f2bf(a.z), f2bf(a.w)};
  *reinterpret_cast<ushort4*>(xb + i * 4) = o;
}

// ---- fold uniform-u into init vectors + build swizzled bf16 W images
__global__ void precompute_kernel(const float* __restrict__ u,
                                  const float* __restrict__ W_eb,
                                  const float* __restrict__ b_eb,
                                  const float* __restrict__ W_nb,
                                  const float* __restrict__ b_nb,
                                  const float* __restrict__ W_d1,
                                  const float* __restrict__ W_d2,
                                  float* __restrict__ eb_init,
                                  float* __restrict__ nb_init,
                                  ushort* __restrict__ wt_img,
                                  ushort* __restrict__ wnb_img,
                                  ushort* __restrict__ wtd1_img,
                                  ushort* __restrict__ w2_img) {
  int j = threadIdx.x;  // 64 threads
  float ae = b_eb[j], an = b_nb[j];
  for (int k = 0; k < 64; ++k) {
    float uk = u[k];
    ae = fmaf(uk, W_eb[(48 + k) * 64 + j], ae);
    an = fmaf(uk, W_nb[(80 + k) * 64 + j], an);
  }
  eb_init[j] = ae;
  nb_init[j] = an;
  for (int k = 0; k < 64; ++k) {
    ushort v = (k < 48) ? f2bf(W_eb[k * 64 + j]) : (ushort)0;
    wt_img[aswz(j, k >> 3) + (k & 7)] = v;
  }
  for (int k = 0; k < 128; ++k) {
    ushort v = (k < 80) ? f2bf(W_nb[k * 64 + j]) : (ushort)0;
    wnb_img[nswz(j, k >> 3) + (k & 7)] = v;
  }
  for (int k = 0; k < 192; ++k)
    wtd1_img[aswz192(j, k >> 3) + (k & 7)] = f2bf(W_d1[k * 64 + j]);
  if (j < 16)
    for (int k = 0; k < 64; ++k)
      w2_img[aswz(j, k >> 3) + (k & 7)] = f2bf(W_d2[k * 16 + j]);
}

// ---- bucket histogram for both directions
__global__ __launch_bounds__(256) void bcount_kernel(
    const int* __restrict__ receivers, const int* __restrict__ senders,
    uint* __restrict__ bcnt_r, uint* __restrict__ bcnt_s, int E, int NB) {
  __shared__ uint hr[NBMAX], hs[NBMAX];
  int t = threadIdx.x;
  for (int i = t; i < NB; i += 256) { hr[i] = 0; hs[i] = 0; }
  __syncthreads();
  int stride = gridDim.x * 256;
  for (int e = blockIdx.x * 256 + t; e < E; e += stride) {
    atomicAdd(&hr[receivers[e] >> BSHIFT], 1u);
    atomicAdd(&hs[senders[e] >> BSHIFT], 1u);
  }
  __syncthreads();
  for (int i = t; i < NB; i += 256) {
    if (hr[i]) atomicAdd(&bcnt_r[i], hr[i]);
    if (hs[i]) atomicAdd(&bcnt_s[i], hs[i]);
  }
}

// ---- exclusive scan of both bucket-count arrays (single block, 4/thread)
__global__ __launch_bounds__(256) void bscan_kernel(
    const uint* __restrict__ bcnt_r, const uint* __restrict__ bcnt_s,
    uint* __restrict__ start_r, uint* __restrict__ start_s,
    uint* __restrict__ cur_r, uint* __restrict__ cur_s, int E, int NB) {
  __shared__ uint ts[256];
  int t = threadIdx.x;
  #pragma unroll
  for (int pass = 0; pass < 2; ++pass) {
    const uint* cnt = pass ? bcnt_s : bcnt_r;
    uint* start = pass ? start_s : start_r;
    uint* cur = pass ? cur_s : cur_r;
    uint loc[4]; uint tsum = 0;
    #pragma unroll
    for (int q = 0; q < 4; ++q) {
      int i = t * 4 + q;
      loc[q] = (i < NB) ? cnt[i] : 0;
      tsum += loc[q];
    }
    ts[t] = tsum;
    __syncthreads();
    for (int off = 1; off < 256; off <<= 1) {
      uint a = (t >= off) ? ts[t - off] : 0;
      __syncthreads();
      ts[t] += a;
      __syncthreads();
    }
    uint run = ts[t] - tsum;
    #pragma unroll
    for (int q = 0; q < 4; ++q) {
      int i = t * 4 + q;
      if (i < NB) { start[i] = run; cur[i] = run; run += loc[q]; }
    }
    if (t == 0) start[NB] = (uint)E;
    __syncthreads();
  }
}

// ---- bucket-sort edge ids, both directions in one launch.
__global__ __launch_bounds__(256) void distribute_kernel(
    const int* __restrict__ receivers, const int* __restrict__ senders,
    uint* __restrict__ gcur_r, uint* __restrict__ gcur_s,
    uint* __restrict__ tmp_r, uint* __restrict__ tmp_s, int E, int NB) {
  __shared__ uint hist[NBMAX], lstart[NBMAX], cur[NBMAX], gbase[NBMAX];
  __shared__ uint ids[DC];
  __shared__ ushort idsB[DC];
  __shared__ uint ts[256];
  int dir = blockIdx.x & 1;
  const int* key = dir ? senders : receivers;
  uint* g_cursor = dir ? gcur_s : gcur_r;
  uint* tmp = dir ? tmp_s : tmp_r;
  int t = threadIdx.x;
  int base = (blockIdx.x >> 1) * DC;
  int cact = min(DC, E - base);
  for (int i = t; i < NB; i += 256) hist[i] = 0;
  __syncthreads();
  for (int k = 0; k < DC / 256; ++k) {
    int j = k * 256 + t;
    if (j < cact) atomicAdd(&hist[key[base + j] >> BSHIFT], 1u);
  }
  __syncthreads();
  {
    uint loc[4]; uint tsum = 0;
    #pragma unroll
    for (int q = 0; q < 4; ++q) {
      int i = t * 4 + q;
      loc[q] = (i < NB) ? hist[i] : 0;
      tsum += loc[q];
    }
    ts[t] = tsum;
    __syncthreads();
    for (int off = 1; off < 256; off <<= 1) {
      uint a = (t >= off) ? ts[t - off] : 0;
      __syncthreads();
      ts[t] += a;
      __syncthreads();
    }
    uint run = ts[t] - tsum;
    #pragma unroll
    for (int q = 0; q < 4; ++q) {
      int i = t * 4 + q;
      if (i < NB) { lstart[i] = run; cur[i] = run; run += loc[q]; }
    }
  }
  __syncthreads();
  for (int i = t; i < NB; i += 256)
    if (hist[i]) gbase[i] = atomicAdd(&g_cursor[i], hist[i]);
  for (int k = 0; k < DC / 256; ++k) {
    int j = k * 256 + t;
    if (j < cact) {
      int e = base + j;
      int kk = key[e];
      uint b = (uint)(kk >> BSHIFT);
      uint slot = atomicAdd(&cur[b], 1u);
      ids[slot] = ((uint)(kk & (BW - 1)) << 21) | (uint)e;
      idsB[slot] = (ushort)b;
    }
  }
  __syncthreads();
  for (int j = t; j < cact; j += 256) {
    uint b2 = idsB[j];
    tmp[gbase[b2] + ((uint)j - lstart[b2])] = ids[j];
  }
}

// ---- per-bucket counting sort to full per-node order.
__global__ __launch_bounds__(256) void bucketsort_kernel(
    const uint* __restrict__ tmp_r, const uint* __restrict__ tmp_s,
    const uint* __restrict__ start_r, const uint* __restrict__ start_s,
    uint* __restrict__ eidx_r, uint* __restrict__ eidx_s,
    uint* __restrict__ row_ptr_r, uint* __restrict__ row_ptr_s,
    uint* __restrict__ cnt_r, uint* __restrict__ cnt_s, int N) {
  __shared__ uint hist[BW], pfx[BW], cur[BW];
  int d = blockIdx.x & 1;
  int b = blockIdx.x >> 1;
  const uint* tmp = d ? tmp_s : tmp_r;
  const uint* start = d ? start_s : start_r;
  uint* eidx = d ? eidx_s : eidx_r;
  uint* row_ptr = d ? row_ptr_s : row_ptr_r;
  uint* cnt = d ? cnt_s : cnt_r;
  int t = threadIdx.x;
  if (t < BW) hist[t] = 0;
  __syncthreads();
  int beg = (int)start[b], end = (int)start[b + 1];
  for (int i = beg + t; i < end; i += 256) atomicAdd(&hist[tmp[i] >> 21], 1u);
  __syncthreads();
  if (t < BW) pfx[t] = hist[t];
  __syncthreads();
  for (int off = 1; off < BW; off <<= 1) {
    uint a = 0;
    if (t < BW && t >= off) a = pfx[t - off];
    __syncthreads();
    if (t < BW) pfx[t] += a;
    __syncthreads();
  }
  if (t < BW) cur[t] = pfx[t] - hist[t];
  __syncthreads();
  for (int i = beg + t; i < end; i += 256) {
    uint v = tmp[i];
    uint nl = v >> 21;
    uint p = atomicAdd(&cur[nl], 1u);
    eidx[beg + p] = v & EMASK;
  }
  int nbase = b * BW;
  if (t < BW && nbase + t < N) {
    cnt[nbase + t] = hist[t];
    row_ptr[nbase + t] = (uint)beg + pfx[t] - hist[t];
  }
}

// ---- edge MLP via MFMA (refcheck-proven)
__global__ __launch_bounds__(256, 2) void edge_mfma_kernel(
    const float* __restrict__ edge_attr, const ushort* __restrict__ xb,
    const int* __restrict__ senders, const int* __restrict__ receivers,
    const ushort* __restrict__ wt_img, const float* __restrict__ eb_init,
    ushort* __restrict__ e_h, int E) {
  __shared__ ushort Alds[64 * 64];       // 8 KB
  __shared__ ushort Wlds[64 * 64];       // 8 KB
  __shared__ ushort Clds[4][16 * 72];    // 9 KB (pitch 72)
  int t = threadIdx.x;
  int base = blockIdx.x * 64;
  {
    const uint4* src = reinterpret_cast<const uint4*>(wt_img);
    uint4* dst = reinterpret_cast<uint4*>(Wlds);
    dst[t * 2] = src[t * 2];
    dst[t * 2 + 1] = src[t * 2 + 1];
  }
  {
    int m = t >> 2, part = t & 3;
    int e = base + m;
    bool val = e < E;
    if (part < 2) {
      union { ushort h[8]; uint4 q; } pk;
      if (val) {
        const float* ap = edge_attr + (size_t)e * 16 + part * 8;
        float4 f0 = LDF4(ap), f1 = LDF4(ap + 4);
        pk.h[0] = f2bf(f0.x); pk.h[1] = f2bf(f0.y);
        pk.h[2] = f2bf(f0.z); pk.h[3] = f2bf(f0.w);
        pk.h[4] = f2bf(f1.x); pk.h[5] = f2bf(f1.y);
        pk.h[6] = f2bf(f1.z); pk.h[7] = f2bf(f1.w);
      } else {
        pk.q = uint4{0, 0, 0, 0};
      }
      *reinterpret_cast<uint4*>(&Alds[aswz(m, part)]) = pk.q;
    } else {
      uint4 w0 = {0, 0, 0, 0}, w1 = {0, 0, 0, 0};
      if (val) {
        int node = (part == 2) ? receivers[e] : senders[e];
        const uint4* xp = reinterpret_cast<const uint4*>(xb + (size_t)node * 16);
        w0 = xp[0]; w1 = xp[1];
      }
      int kb = (part == 2) ? 2 : 4;
      *reinterpret_cast<uint4*>(&Alds[aswz(m, kb)]) = w0;
      *reinterpret_cast<uint4*>(&Alds[aswz(m, kb + 1)]) = w1;
    }
    if (t < 128) {
      int zr = t >> 1, zkb = 6 + (t & 1);
      *reinterpret_cast<uint4*>(&Alds[aswz(zr, zkb)]) = uint4{0, 0, 0, 0};
    }
  }
  __syncthreads();
  int wid = t >> 6, l = t & 63;
  int lrow = l & 15, lk = l >> 4;
  int arow = wid * 16 + lrow;
  bf16x8 a0 = *reinterpret_cast<const bf16x8*>(&Alds[aswz(arow, lk)]);
  bf16x8 a1 = *reinterpret_cast<const bf16x8*>(&Alds[aswz(arow, 4 + lk)]);
  f32x4 acc[4];
  #pragma unroll
  for (int nt = 0; nt < 4; ++nt) {
    float ebi = eb_init[nt * 16 + lrow];
    acc[nt] = f32x4{ebi, ebi, ebi, ebi};
    bf16x8 b0 =
        *reinterpret_cast<const bf16x8*>(&Wlds[aswz(nt * 16 + lrow, lk)]);
    bf16x8 b1 =
        *reinterpret_cast<const bf16x8*>(&Wlds[aswz(nt * 16 + lrow, 4 + lk)]);
    acc[nt] = __builtin_amdgcn_mfma_f32_16x16x32_bf16(a0, b0, acc[nt], 0, 0, 0);
    acc[nt] = __builtin_amdgcn_mfma_f32_16x16x32_bf16(a1, b1, acc[nt], 0, 0, 0);
  }
  int m0 = (l >> 4) * 4;
  #pragma unroll
  for (int nt = 0; nt < 4; ++nt) {
    #pragma unroll
    for (int reg = 0; reg < 4; ++reg) {
      Clds[wid][(m0 + reg) * 72 + nt * 16 + lrow] =
          f2bf(fmaxf(acc[nt][reg], 0.f));
    }
  }
  __syncthreads();
  int sm = l >> 2, ch = l & 3;
  int ge = base + wid * 16 + sm;
  uint4 c0 = *reinterpret_cast<const uint4*>(&Clds[wid][sm * 72 + ch * 16]);
  uint4 c1 = *reinterpret_cast<const uint4*>(&Clds[wid][sm * 72 + ch * 16 + 8]);
  if (ge < E) {
    uint4* dst = reinterpret_cast<uint4*>(e_h + (size_t)ge * 64 + ch * 16);
    dst[0] = c0;
    dst[1] = c1;
  }
}

// ---- gather, both directions in one launch; wave per node.
// Each half-wave owns a CONTIGUOUS range of the node's edges; index
// prefetch overlaps the eidx->addr->row chain across iterations.
__global__ __launch_bounds__(256, 2) void gather_kernel(
    const ushort* __restrict__ e_h, const uint* __restrict__ row_ptr_r,
    const uint* __restrict__ cnt_r, const uint* __restrict__ eidx_r,
    const uint* __restrict__ row_ptr_s, const uint* __restrict__ cnt_s,
    const uint* __restrict__ eidx_s, float* __restrict__ sum_recv,
    float* __restrict__ sum_sent, int N) {
  int dir = blockIdx.x & 1;
  const uint* row_ptr = dir ? row_ptr_s : row_ptr_r;
  const uint* cnt = dir ? cnt_s : cnt_r;
  const uint* eidx = dir ? eidx_s : eidx_r;
  float* out = dir ? sum_sent : sum_recv;
  int n = (blockIdx.x >> 1) * 4 + (threadIdx.x >> 6);
  if (n >= N) return;
  const uint* eh32 = reinterpret_cast<const uint*>(e_h);
  int lane = threadIdx.x & 63;
  int half = lane >> 5;
  int l = lane & 31;
  int beg = (int)row_ptr[n];
  int c = (int)cnt[n];
  int c0 = (c + 1) >> 1;                  // half 0 count (ceil)
  int b0 = beg + (half ? c0 : 0);         // this half's base
  int cN = half ? (c - c0) : c0;          // this half's count
  float a0 = 0, a1 = 0, b0f = 0, b1f = 0, c0f = 0, c1f = 0, d0f = 0, d1f = 0;
  int i = 0;
  uint e0 = 0, e1 = 0, e2 = 0, e3 = 0;
  if (cN >= 4) {
    e0 = eidx[b0]; e1 = eidx[b0 + 1]; e2 = eidx[b0 + 2]; e3 = eidx[b0 + 3];
  }
  for (; i + 8 <= cN; i += 4) {
    uint w0 = eh32[(size_t)e0 * 32 + l];
    uint w1 = eh32[(size_t)e1 * 32 + l];
    uint w2 = eh32[(size_t)e2 * 32 + l];
    uint w3 = eh32[(size_t)e3 * 32 + l];
    e0 = eidx[b0 + i + 4]; e1 = eidx[b0 + i + 5];
    e2 = eidx[b0 + i + 6]; e3 = eidx[b0 + i + 7];
    a0 += __uint_as_float(w0 << 16);
    a1 += __uint_as_float(w0 & 0xFFFF0000u);
    b0f += __uint_as_float(w1 << 16);
    b1f += __uint_as_float(w1 & 0xFFFF0000u);
    c0f += __uint_as_float(w2 << 16);
    c1f += __uint_as_float(w2 & 0xFFFF0000u);
    d0f += __uint_as_float(w3 << 16);
    d1f += __uint_as_float(w3 & 0xFFFF0000u);
  }
  if (i + 4 <= cN) {
    uint w0 = eh32[(size_t)e0 * 32 + l];
    uint w1 = eh32[(size_t)e1 * 32 + l];
    uint w2 = eh32[(size_t)e2 * 32 + l];
    uint w3 = eh32[(size_t)e3 * 32 + l];
    a0 += __uint_as_float(w0 << 16);
    a1 += __uint_as_float(w0 & 0xFFFF0000u);
    b0f += __uint_as_float(w1 << 16);
    b1f += __uint_as_float(w1 & 0xFFFF0000u);
    c0f += __uint_as_float(w2 << 16);
    c1f += __uint_as_float(w2 & 0xFFFF0000u);
    d0f += __uint_as_float(w3 << 16);
    d1f += __uint_as_float(w3 & 0xFFFF0000u);
    i += 4;
  }
  for (; i < cN; ++i) {
    uint w0 = eh32[(size_t)eidx[b0 + i] * 32 + l];
    a0 += __uint_as_float(w0 << 16);
    a1 += __uint_as_float(w0 & 0xFFFF0000u);
  }
  a0 = (a0 + b0f) + (c0f + d0f);
  a1 = (a1 + b1f) + (c1f + d1f);
  a0 += __shfl_xor(a0, 32);
  a1 += __shfl_xor(a1, 32);
  if (half == 0) {
    float2 t = {a0, a1};
    *reinterpret_cast<float2*>(out + (size_t)n * 64 + 2 * l) = t;
  }
}

// ---- node block via MFMA: n_h(bf16) = relu([sum_recv, x]@W_nb + nb_init)
__global__ __launch_bounds__(256, 2) void node_mfma_kernel(
    const float* __restrict__ sum_recv, const ushort* __restrict__ xb,
    const ushort* __restrict__ wnb_img, const float* __restrict__ nb_init,
    ushort* __restrict__ n_h, int N) {
  __shared__ ushort Alds[64 * 128];      // 16 KB
  __shared__ ushort Wlds[64 * 128];      // 16 KB
  __shared__ ushort Clds[4][16 * 72];    // 9 KB
  int t = threadIdx.x;
  int base = blockIdx.x * 64;
  {
    const uint4* src = reinterpret_cast<const uint4*>(wnb_img);
    uint4* dst = reinterpret_cast<uint4*>(Wlds);
    #pragma unroll
    for (int i = 0; i < 4; ++i) dst[t + 256 * i] = src[t + 256 * i];
  }
  {
    int m = t >> 2, part = t & 3;
    int n = base + m;
    bool val = n < N;
    if (part < 2) {
      #pragma unroll
      for (int q = 0; q < 4; ++q) {
        int c = part * 4 + q;
        union { ushort h[8]; uint4 qq; } pk;
        if (val) {
          const float* src = sum_recv + (size_t)n * 64 + c * 8;
          float4 f0 = LDF4(src), f1 = LDF4(src + 4);
          pk.h[0] = f2bf(f0.x); pk.h[1] = f2bf(f0.y);
          pk.h[2] = f2bf(f0.z); pk.h[3] = f2bf(f0.w);
          pk.h[4] = f2bf(f1.x); pk.h[5] = f2bf(f1.y);
          pk.h[6] = f2bf(f1.z); pk.h[7] = f2bf(f1.w);
        } else {
          pk.qq = uint4{0, 0, 0, 0};
        }
        *reinterpret_cast<uint4*>(&Alds[nswz(m, c)]) = pk.qq;
      }
    } else if (part == 2) {
      uint4 w0 = {0, 0, 0, 0}, w1 = {0, 0, 0, 0};
      if (val) {
        const uint4* xp = reinterpret_cast<const uint4*>(xb + (size_t)n * 16);
        w0 = xp[0]; w1 = xp[1];
      }
      *reinterpret_cast<uint4*>(&Alds[nswz(m, 8)]) = w0;
      *reinterpret_cast<uint4*>(&Alds[nswz(m, 9)]) = w1;
      *reinterpret_cast<uint4*>(&Alds[nswz(m, 10)]) = uint4{0, 0, 0, 0};
      *reinterpret_cast<uint4*>(&Alds[nswz(m, 11)]) = uint4{0, 0, 0, 0};
    } else {
      #pragma unroll
      for (int q = 0; q < 4; ++q)
        *reinterpret_cast<uint4*>(&Alds[nswz(m, 12 + q)]) = uint4{0, 0, 0, 0};
    }
  }
  __syncthreads();
  int wid = t >> 6, l = t & 63;
  int lrow = l & 15, lk = l >> 4;
  int arow = wid * 16 + lrow;
  bf16x8 afr[4];
  #pragma unroll
  for (int g = 0; g < 4; ++g)
    afr[g] = *reinterpret_cast<const bf16x8*>(&Alds[nswz(arow, g * 4 + lk)]);
  f32x4 acc[4];
  #pragma unroll
  for (int nt = 0; nt < 4; ++nt) {
    float nbi = nb_init[nt * 16 + lrow];
    acc[nt] = f32x4{nbi, nbi, nbi, nbi};
    #pragma unroll
    for (int g = 0; g < 4; ++g) {
      bf16x8 b = *reinterpret_cast<const bf16x8*>(
          &Wlds[nswz(nt * 16 + lrow, g * 4 + lk)]);
      acc[nt] =
          __builtin_amdgcn_mfma_f32_16x16x32_bf16(afr[g], b, acc[nt], 0, 0, 0);
    }
  }
  int m0 = (l >> 4) * 4;
  #pragma unroll
  for (int nt = 0; nt < 4; ++nt) {
    #pragma unroll
    for (int reg = 0; reg < 4; ++reg) {
      Clds[wid][(m0 + reg) * 72 + nt * 16 + lrow] =
          f2bf(fmaxf(acc[nt][reg], 0.f));
    }
  }
  __syncthreads();
  int sm = l >> 2, ch = l & 3;
  int gn = base + wid * 16 + sm;
  uint4 c0 = *reinterpret_cast<const uint4*>(&Clds[wid][sm * 72 + ch * 16]);
  uint4 c1 = *reinterpret_cast<const uint4*>(&Clds[wid][sm * 72 + ch * 16 + 8]);
  if (gn < N) {
    uint4* dst = reinterpret_cast<uint4*>(n_h + (size_t)gn * 64 + ch * 16);
    dst[0] = c0;
    dst[1] = c1;
  }
}

// ---- column sums of sum_recv (fp32) and n_h (bf16)
__global__ __launch_bounds__(256) void reduce_kernel(
    const float* __restrict__ sum_recv, const ushort* __restrict__ n_h,
    float* __restrict__ e_sum, float* __restrict__ n_sum, int N) {
  __shared__ float ls[128];
  if (threadIdx.x < 128) ls[threadIdx.x] = 0.f;
  __syncthreads();
  int g = threadIdx.x & 15;
  int tid = blockIdx.x * blockDim.x + threadIdx.x;
  int row0 = tid >> 4;
  int rstride = (gridDim.x * blockDim.x) >> 4;
  float pe[4] = {0, 0, 0, 0}, pn[4] = {0, 0, 0, 0};
  for (int r = row0; r < N; r += rstride) {
    float4 a = LDF4(sum_recv + (size_t)r * 64 + g * 4);
    uint2 b = *reinterpret_cast<const uint2*>(n_h + (size_t)r * 64 + g * 4);
    pe[0] += a.x; pe[1] += a.y; pe[2] += a.z; pe[3] += a.w;
    pn[0] += __uint_as_float(b.x << 16);
    pn[1] += __uint_as_float(b.x & 0xFFFF0000u);
    pn[2] += __uint_as_float(b.y << 16);
    pn[3] += __uint_as_float(b.y & 0xFFFF0000u);
  }
  #pragma unroll
  for (int i = 0; i < 4; ++i) {
    atomicAdd(&ls[g * 4 + i], pe[i]);
    atomicAdd(&ls[64 + g * 4 + i], pn[i]);
  }
  __syncthreads();
  if (threadIdx.x < 64) {
    atomicAdd(&e_sum[threadIdx.x], ls[threadIdx.x]);
    atomicAdd(&n_sum[threadIdx.x], ls[64 + threadIdx.x]);
  }
}

// ---- global block + fold u2 into d1_init
__global__ void global_kernel(const float* __restrict__ u,
                              const float* __restrict__ e_sum,
                              const float* __restrict__ n_sum,
                              const float* __restrict__ W_gb,
                              const float* __restrict__ b_gb,
                              const float* __restrict__ W_d1,
                              const float* __restrict__ b_d1,
                              float* __restrict__ d1_init, float Ef, float Nf) {
  __shared__ float gin[192];
  __shared__ float u2s[64];
  int j = threadIdx.x;  // 64 threads
  gin[j] = e_sum[j] / Ef;
  gin[64 + j] = n_sum[j] / Nf;
  gin[128 + j] = u[j];
  __syncthreads();
  float a = b_gb[j];
  for (int k = 0; k < 192; ++k) a = fmaf(gin[k], W_gb[k * 64 + j], a);
  u2s[j] = fmaxf(a, 0.f);
  __syncthreads();
  float d = b_d1[j];
  for (int k = 0; k < 64; ++k) d = fmaf(u2s[k], W_d1[(192 + k) * 64 + j], d);
  d1_init[j] = d;
}

// ---- decoder via MFMA: out = relu(A@W_d1 + d1_init) @ W_d2 + b_d2
__global__ __launch_bounds__(256, 2) void decoder_mfma_kernel(
    const float* __restrict__ sum_recv, const float* __restrict__ sum_sent,
    const uint* __restrict__ cnt_r, const uint* __restrict__ cnt_s,
    const ushort* __restrict__ n_h, const ushort* __restrict__ wtd1_img,
    const float* __restrict__ d1_init, const ushort* __restrict__ w2_img,
    const float* __restrict__ b_d2, float* __restrict__ out, int N) {
  __shared__ ushort Alds[64 * 192];   // 24 KB
  __shared__ ushort Wlds[64 * 192];   // 24 KB
  __shared__ ushort Hlds[64 * 64];    // 8 KB
  __shared__ ushort W2lds[16 * 64];   // 2 KB
  int t = threadIdx.x;
  int base = blockIdx.x * 64;
  {
    const uint4* src = reinterpret_cast<const uint4*>(wtd1_img);
    uint4* dst = reinterpret_cast<uint4*>(Wlds);
    #pragma unroll
    for (int i = 0; i < 6; ++i) dst[t + 256 * i] = src[t + 256 * i];
    if (t < 128)
      reinterpret_cast<uint4*>(W2lds)[t] =
          reinterpret_cast<const uint4*>(w2_img)[t];
  }
  {
    int m = t >> 2;
    int n = base + m;
    bool val = n < N;
    float invr = 0.f, invs = 0.f;
    if (val) {
      invr = 1.f / fmaxf((float)cnt_r[n], 1.f);
      invs = 1.f / fmaxf((float)cnt_s[n], 1.f);
    }
    int c0 = (t & 3) * 6;
    for (int c = c0; c < c0 + 6; ++c) {
      union { ushort h[8]; uint4 q; } pk;
      if (val) {
        if (c >= 16) {
          pk.q = *reinterpret_cast<const uint4*>(n_h + (size_t)n * 64 +
                                                 (c - 16) * 8);
        } else {
          const float* src;
          float scl;
          if (c < 8) { src = sum_recv + (size_t)n * 64 + c * 8; scl = invr; }
          else       { src = sum_sent + (size_t)n * 64 + (c - 8) * 8; scl = invs; }
          float4 f0 = LDF4(src), f1 = LDF4(src + 4);
          pk.h[0] = f2bf(f0.x * scl); pk.h[1] = f2bf(f0.y * scl);
          pk.h[2] = f2bf(f0.z * scl); pk.h[3] = f2bf(f0.w * scl);
          pk.h[4] = f2bf(f1.x * scl); pk.h[5] = f2bf(f1.y * scl);
          pk.h[6] = f2bf(f1.z * scl); pk.h[7] = f2bf(f1.w * scl);
        }
      } else {
        pk.q = uint4{0, 0, 0, 0};
      }
      *reinterpret_cast<uint4*>(&Alds[aswz192(m, c)]) = pk.q;
    }
  }
  __syncthreads();
  int wid = t >> 6, l = t & 63;
  int lrow = l & 15, lk = l >> 4;
  int arow = wid * 16 + lrow;
  bf16x8 afr[6];
  #pragma unroll
  for (int g = 0; g < 6; ++g)
    afr[g] = *reinterpret_cast<const bf16x8*>(&Alds[aswz192(arow, g * 4 + lk)]);
  f32x4 acc[4];
  #pragma unroll
  for (int nt = 0; nt < 4; ++nt) {
    float di = d1_init[nt * 16 + lrow];
    acc[nt] = f32x4{di, di, di, di};
    #pragma unroll
    for (int g = 0; g < 6; ++g) {
      bf16x8 b = *reinterpret_cast<const bf16x8*>(
          &Wlds[aswz192(nt * 16 + lrow, g * 4 + lk)]);
      acc[nt] =
          __builtin_amdgcn_mfma_f32_16x16x32_bf16(afr[g], b, acc[nt], 0, 0, 0);
    }
  }
  int m0 = (l >> 4) * 4;
  #pragma unroll
  for (int nt = 0; nt < 4; ++nt) {
    #pragma unroll
    for (int reg = 0; reg < 4; ++reg) {
      int hm = wid * 16 + m0 + reg;
      int hn = nt * 16 + lrow;
      Hlds[hm * 64 + (((hn >> 3) ^ (hm & 7)) << 3) + (hn & 7)] =
          f2bf(fmaxf(acc[nt][reg], 0.f));
    }
  }
  __syncthreads();
  bf16x8 a20 = *reinterpret_cast<const bf16x8*>(&Hlds[aswz(arow, lk)]);
  bf16x8 a21 = *reinterpret_cast<const bf16x8*>(&Hlds[aswz(arow, 4 + lk)]);
  bf16x8 b20 = *reinterpret_cast<const bf16x8*>(&W2lds[aswz(lrow, lk)]);
  bf16x8 b21 = *reinterpret_cast<const bf16x8*>(&W2lds[aswz(lrow, 4 + lk)]);
  float bi = b_d2[lrow];
  f32x4 o = f32x4{bi, bi, bi, bi};
  o = __builtin_amdgcn_mfma_f32_16x16x32_bf16(a20, b20, o, 0, 0, 0);
  o = __builtin_amdgcn_mfma_f32_16x16x32_bf16(a21, b21, o, 0, 0, 0);
  #pragma unroll
  for (int reg = 0; reg < 4; ++reg) {
    int ge = base + wid * 16 + m0 + reg;
    if (ge < N) out[(size_t)ge * 16 + lrow] = o[reg];
  }
}

extern "C" void kernel_launch(void* const* d_in, const int* in_sizes, int n_in,
                              void* d_out, int out_size, void* d_ws,
                              size_t ws_size, hipStream_t stream) {
  const float* x         = (const float*)d_in[0];
  const float* edge_attr = (const float*)d_in[1];
  const float* u         = (const float*)d_in[2];
  const int*   senders   = (const int*)d_in[3];
  const int*   receivers = (const int*)d_in[4];
  const float* W_eb = (const float*)d_in[7];
  const float* b_eb = (const float*)d_in[8];
  const float* W_nb = (const float*)d_in[9];
  const float* b_nb = (const float*)d_in[10];
  const float* W_gb = (const float*)d_in[11];
  const float* b_gb = (const float*)d_in[12];
  const float* W_d1 = (const float*)d_in[13];
  const float* b_d1 = (const float*)d_in[14];
  const float* W_d2 = (const float*)d_in[15];
  const float* b_d2 = (const float*)d_in[16];

  int N = in_sizes[0] / 16;
  int E = in_sizes[1] / 16;
  int NB = (N + BW - 1) >> BSHIFT;  // 782 for N=100000
  int NDB = (E + DC - 1) / DC;      // distribute chunks per direction

  char* w = (char*)d_ws;
  ushort* e_h = (ushort*)w;          w += (size_t)E * 64 * 2;
  float* sum_recv = (float*)w;       w += (size_t)N * 64 * 4;
  float* sum_sent = (float*)w;       w += (size_t)N * 64 * 4;
  ushort* n_h = (ushort*)w;          w += (size_t)N * 64 * 2;
  uint* tmp_r = (uint*)w;            w += (size_t)E * 4;
  uint* tmp_s = (uint*)w;            w += (size_t)E * 4;
  uint* eidx_r = (uint*)w;           w += (size_t)E * 4;
  uint* eidx_s = (uint*)w;           w += (size_t)E * 4;
  uint* row_ptr_r = (uint*)w;        w += (size_t)N * 4;
  uint* row_ptr_s = (uint*)w;        w += (size_t)N * 4;
  uint* cnt_r = (uint*)w;            w += (size_t)N * 4;
  uint* cnt_s = (uint*)w;            w += (size_t)N * 4;
  ushort* xb = (ushort*)w;           w += (size_t)N * 16 * 2;
  ushort* wt_img = (ushort*)w;       w += (size_t)64 * 64 * 2;
  ushort* wnb_img = (ushort*)w;      w += (size_t)64 * 128 * 2;
  ushort* wtd1_img = (ushort*)w;     w += (size_t)64 * 192 * 2;
  ushort* w2_img = (ushort*)w;       w += (size_t)16 * 64 * 2;
  uint* start_r = (uint*)w;          w += (size_t)(NB + 1) * 4;
  uint* start_s = (uint*)w;          w += (size_t)(NB + 1) * 4;
  uint* cur_r = (uint*)w;            w += (size_t)NB * 4;
  uint* cur_s = (uint*)w;            w += (size_t)NB * 4;
  // zeroed region
  uint* bcnt_r = (uint*)w;           w += (size_t)NBMAX * 4;
  uint* bcnt_s = (uint*)w;           w += (size_t)NBMAX * 4;
  float* e_sum = (float*)w;          w += 64 * 4;
  float* n_sum = (float*)w;          w += 64 * 4;
  // small non-zeroed
  float* eb_init = (float*)w;        w += 64 * 4;
  float* nb_init = (float*)w;        w += 64 * 4;
  float* d1_init = (float*)w;        w += 64 * 4;

  size_t zero_bytes = (size_t)(2 * NBMAX + 128) * 4;
  hipMemsetAsync(bcnt_r, 0, zero_bytes, stream);

  hipLaunchKernelGGL(xconvert_kernel, dim3((N * 16 / 4 + 255) / 256), dim3(256),
                     0, stream, x, xb, N * 16);
  hipLaunchKernelGGL(precompute_kernel, dim3(1), dim3(64), 0, stream, u, W_eb,
                     b_eb, W_nb, b_nb, W_d1, W_d2, eb_init, nb_init, wt_img,
                     wnb_img, wtd1_img, w2_img);
  hipLaunchKernelGGL(bcount_kernel, dim3(64), dim3(256), 0, stream, receivers,
                     senders, bcnt_r, bcnt_s, E, NB);
  hipLaunchKernelGGL(bscan_kernel, dim3(1), dim3(256), 0, stream, bcnt_r,
                     bcnt_s, start_r, start_s, cur_r, cur_s, E, NB);
  hipLaunchKernelGGL(distribute_kernel, dim3(2 * NDB), dim3(256), 0, stream,
                     receivers, senders, cur_r, cur_s, tmp_r, tmp_s, E, NB);
  hipLaunchKernelGGL(bucketsort_kernel, dim3(2 * NB), dim3(256), 0, stream,
                     tmp_r, tmp_s, start_r, start_s, eidx_r, eidx_s, row_ptr_r,
                     row_ptr_s, cnt_r, cnt_s, N);
  // edge MFMA kernel right before gathers: e_h stays L3-resident
  hipLaunchKernelGGL(edge_mfma_kernel, dim3((E + 63) / 64), dim3(256), 0,
                     stream, edge_attr, xb, senders, receivers, wt_img,
                     eb_init, e_h, E);
  hipLaunchKernelGGL(gather_kernel, dim3(2 * ((N + 3) / 4)), dim3(256), 0,
                     stream, e_h, row_ptr_r, cnt_r, eidx_r, row_ptr_s, cnt_s,
                     eidx_s, sum_recv, sum_sent, N);
  hipLaunchKernelGGL(node_mfma_kernel, dim3((N + 63) / 64), dim3(256), 0,
                     stream, sum_recv, xb, wnb_img, nb_init, n_h, N);
  hipLaunchKernelGGL(reduce_kernel, dim3(256), dim3(256), 0, stream, sum_recv,
                     n_h, e_sum, n_sum, N);
  hipLaunchKernelGGL(global_kernel, dim3(1), dim3(64), 0, stream, u, e_sum,
                     n_sum, W_gb, b_gb, W_d1, b_d1, d1_init, (float)E,
                     (float)N);
  hipLaunchKernelGGL(decoder_mfma_kernel, dim3((N + 63) / 64), dim3(256), 0,
                     stream, sum_recv, sum_sent, cnt_r, cnt_s, n_h, wtd1_img,
                     d1_init, w2_img, b_d2, (float*)d_out, N);
}